// Round 1
// baseline (5425.262 us; speedup 1.0000x reference)
//
#include <hip/hip_runtime.h>
#include <math.h>

// ---------------------------------------------------------------------------
// HAGMoE — f32 correctness-first implementation with algebraic restructuring:
//  * K/V projections of h_sent folded into the (tiny) query side:
//      score = (Wk_h^T Q_h) . h_sent[b,s]   (cost B*T*H^2 instead of B*S*H^2)
//  * mean-pool commutes with linear maps: out-projections applied to pooled
//    vectors, never to [B,S,H] tensors.
//  * biases handled exactly via per-(b,h,t) scalar score offsets.
// Workspace: ~229 MB of f32 scratch in d_ws.
// ---------------------------------------------------------------------------

#define B_    256
#define S_    256
#define T_    16
#define H_    1024
#define NH_   8
#define DH_   128      // H/NH
#define M128_ 128      // NH*T
#define G_    3
#define E_    8
#define I_    4096
#define R_    256
#define L_    3
#define GE_   24       // G*E

// -------------------- wave helpers (wave64) --------------------
__device__ inline float wave_sum(float v) {
    for (int o = 32; o > 0; o >>= 1) v += __shfl_xor(v, o);
    return v;
}
__device__ inline float wave_max(float v) {
    for (int o = 32; o > 0; o >>= 1) v = fmaxf(v, __shfl_xor(v, o));
    return v;
}

// -------------------- generic tiled GEMM --------------------
// C[r, n] = act( scale * (sum_k A[r,k]*B[n_or_k] + rowoff[r]) + bias[n] )
// A row address: Ab + r1*sA1 + r2*sA2  (r = r1*M2 + r2), k contiguous.
// TRANSB=1: B is [N,K] row-major (ldb); TRANSB=0: B is [K,N] row-major (ldb).
// Batched over blockIdx.z with sAz/sBz/sBias/sCz/sRoff element strides.
// Requires K % 16 == 0 (all call sites satisfy this).
#define BM 64
#define BN 64
#define BK 16

template <int TRANSB, int ACT>
__global__ __launch_bounds__(256) void gemm_k(
    const float* __restrict__ Ap, const float* __restrict__ Bp,
    const float* __restrict__ biasp, const float* __restrict__ roffp,
    float* __restrict__ Cp,
    int M1, int M2, int N, int K,
    long sA1, long sA2, long sAz,
    long ldb, long sBz, long sBias,
    long sC1, long sC2, long sCz, long sRoff,
    float scale)
{
    const int z = blockIdx.z;
    const float* Ab = Ap + (long)z * sAz;
    const float* Bb = Bp + (long)z * sBz;
    const float* biasb = biasp ? biasp + (long)z * sBias : nullptr;
    const float* roffb = roffp ? roffp + (long)z * sRoff : nullptr;
    float* Cb = Cp + (long)z * sCz;
    const int M = M1 * M2;
    const int row0 = blockIdx.y * BM;
    const int col0 = blockIdx.x * BN;
    const int tid = threadIdx.x;

    __shared__ float As[BK][BM + 4];
    __shared__ float Bs[BK][BN + 4];

    float acc[4][4] = {};

    const int tm = (tid >> 4) << 2;  // 0..60
    const int tn = (tid & 15) << 2;  // 0..60

    for (int k0 = 0; k0 < K; k0 += BK) {
        // ---- stage A: thread loads float4 of one row ----
        {
            const int i  = tid << 2;
            const int m  = i >> 4;        // row in tile
            const int kk = i & 15;        // multiple of 4
            const int r  = row0 + m;
            float4 v = make_float4(0.f, 0.f, 0.f, 0.f);
            if (r < M) {
                const int r1 = r / M2, r2 = r - r1 * M2;
                v = *(const float4*)(Ab + (long)r1 * sA1 + (long)r2 * sA2 + k0 + kk);
            }
            As[kk + 0][m] = v.x; As[kk + 1][m] = v.y;
            As[kk + 2][m] = v.z; As[kk + 3][m] = v.w;
        }
        // ---- stage B ----
        if (TRANSB) {
            const int i  = tid << 2;
            const int n  = i >> 4;
            const int kk = i & 15;
            const int c  = col0 + n;
            float4 v = make_float4(0.f, 0.f, 0.f, 0.f);
            if (c < N) v = *(const float4*)(Bb + (long)c * ldb + k0 + kk);
            Bs[kk + 0][n] = v.x; Bs[kk + 1][n] = v.y;
            Bs[kk + 2][n] = v.z; Bs[kk + 3][n] = v.w;
        } else {
            const int i  = tid << 2;
            const int kk = i >> 6;
            const int n  = i & 63;
            const int c  = col0 + n;
            float4 v = make_float4(0.f, 0.f, 0.f, 0.f);
            if (c + 3 < N) {
                v = *(const float4*)(Bb + (long)(k0 + kk) * ldb + c);
            } else {
                float tmpv[4] = {0.f, 0.f, 0.f, 0.f};
                for (int j = 0; j < 4; ++j)
                    if (c + j < N) tmpv[j] = Bb[(long)(k0 + kk) * ldb + c + j];
                v = make_float4(tmpv[0], tmpv[1], tmpv[2], tmpv[3]);
            }
            *(float4*)&Bs[kk][n] = v;
        }
        __syncthreads();
#pragma unroll
        for (int kk = 0; kk < BK; ++kk) {
            const float4 av = *(const float4*)&As[kk][tm];
            const float4 bv = *(const float4*)&Bs[kk][tn];
            acc[0][0] += av.x * bv.x; acc[0][1] += av.x * bv.y;
            acc[0][2] += av.x * bv.z; acc[0][3] += av.x * bv.w;
            acc[1][0] += av.y * bv.x; acc[1][1] += av.y * bv.y;
            acc[1][2] += av.y * bv.z; acc[1][3] += av.y * bv.w;
            acc[2][0] += av.z * bv.x; acc[2][1] += av.z * bv.y;
            acc[2][2] += av.z * bv.z; acc[2][3] += av.z * bv.w;
            acc[3][0] += av.w * bv.x; acc[3][1] += av.w * bv.y;
            acc[3][2] += av.w * bv.z; acc[3][3] += av.w * bv.w;
        }
        __syncthreads();
    }

    // ---- epilogue ----
#pragma unroll
    for (int i2 = 0; i2 < 4; ++i2) {
        const int r = row0 + tm + i2;
        if (r >= M) continue;
        const int r1 = r / M2, r2 = r - r1 * M2;
        const float ro = roffb ? roffb[r] : 0.f;
        float* crow = Cb + (long)r1 * sC1 + (long)r2 * sC2;
#pragma unroll
        for (int j = 0; j < 4; ++j) {
            const int c = col0 + tn + j;
            if (c >= N) continue;
            float v = (acc[i2][j] + ro) * scale;
            if (biasb) v += biasb[c];
            if (ACT == 1) v = 0.5f * v * (1.0f + erff(v * 0.70710678118654752f)); // exact gelu
            else if (ACT == 2) v = 1.0f / (1.0f + expf(-v));                      // sigmoid
            crow[c] = v;
        }
    }
}

static void g_launch(hipStream_t s, int transB, int act,
                     const float* A, const float* Bw, const float* bias,
                     const float* roff, float* C,
                     int M1, int M2, int N, int K,
                     long sA1, long sA2, long sAz,
                     long ldb, long sBz, long sBias,
                     long sC1, long sC2, long sCz, long sRoff,
                     float scale, int Z)
{
    dim3 grid((N + BN - 1) / BN, (M1 * M2 + BM - 1) / BM, Z);
    dim3 blk(256);
#define GARGS A, Bw, bias, roff, C, M1, M2, N, K, sA1, sA2, sAz, ldb, sBz, sBias, sC1, sC2, sCz, sRoff, scale
    if (transB == 1 && act == 0)      gemm_k<1, 0><<<grid, blk, 0, s>>>(GARGS);
    else if (transB == 0 && act == 0) gemm_k<0, 0><<<grid, blk, 0, s>>>(GARGS);
    else if (transB == 1 && act == 1) gemm_k<1, 1><<<grid, blk, 0, s>>>(GARGS);
    else                              gemm_k<1, 2><<<grid, blk, 0, s>>>(GARGS);
#undef GARGS
}

// -------------------- glue kernels --------------------

// offs[b*128 + t*NH + h] = sum_k Q[(b*T+t)*H + h*DH + k] * bvec[h*DH + k]
__global__ void headdot_k(const float* __restrict__ Q, const float* __restrict__ bvec,
                          float* __restrict__ out)
{
    const int idx = blockIdx.x * blockDim.x + threadIdx.x;
    if (idx >= B_ * T_ * NH_) return;
    const int h = idx % NH_;
    const int t = (idx / NH_) % T_;
    const int b = idx / (NH_ * T_);
    const float* q  = Q + ((long)(b * T_ + t)) * H_ + h * DH_;
    const float* bb = bvec + h * DH_;
    float sum = 0.f;
    for (int k = 0; k < DH_; ++k) sum += q[k] * bb[k];
    out[idx] = sum;  // idx == b*128 + t*NH + h
}

// softmax over contiguous rows of length S_ (one 64-thread block per row)
__global__ void softmax_rows_k(float* __restrict__ x)
{
    const long row = blockIdx.x;
    float* p = x + row * S_;
    const int t = threadIdx.x;
    float v0 = p[t], v1 = p[t + 64], v2 = p[t + 128], v3 = p[t + 192];
    float m = wave_max(fmaxf(fmaxf(v0, v1), fmaxf(v2, v3)));
    v0 = expf(v0 - m); v1 = expf(v1 - m); v2 = expf(v2 - m); v3 = expf(v3 - m);
    const float inv = 1.f / wave_sum(v0 + v1 + v2 + v3);
    p[t] = v0 * inv; p[t + 64] = v1 * inv; p[t + 128] = v2 * inv; p[t + 192] = v3 * inv;
}

// st: softmax over t (stride NH*S) for each (b,h,s)
__global__ void softmax_t_k(float* __restrict__ sc)
{
    const int idx = blockIdx.x * blockDim.x + threadIdx.x;
    if (idx >= B_ * NH_ * S_) return;
    const int s = idx % S_;
    const int h = (idx / S_) % NH_;
    const int b = idx / (S_ * NH_);
    float* base = sc + (long)b * M128_ * S_ + (long)h * S_ + s;
    float v[T_];
    float mx = -1e30f;
#pragma unroll
    for (int t = 0; t < T_; ++t) { v[t] = base[(long)t * NH_ * S_]; mx = fmaxf(mx, v[t]); }
    float sum = 0.f;
#pragma unroll
    for (int t = 0; t < T_; ++t) { v[t] = expf(v[t] - mx); sum += v[t]; }
    const float inv = 1.f / sum;
#pragma unroll
    for (int t = 0; t < T_; ++t) base[(long)t * NH_ * S_] = v[t] * inv;
}

// out[row] = mean of contiguous row of length S_
__global__ void rowmean_k(const float* __restrict__ x, float* __restrict__ out)
{
    const int row = blockIdx.x;
    const float* p = x + (long)row * S_;
    float sv = 0.f;
    for (int i = threadIdx.x; i < S_; i += 64) sv += p[i];
    sv = wave_sum(sv);
    if (threadIdx.x == 0) out[row] = sv * (1.0f / S_);
}

// ctxbar[b,h,k] = mean_t ctx[b][(t*NH+h)][k]
__global__ void ctxbar_k(const float* __restrict__ ctx, float* __restrict__ out)
{
    const int idx = blockIdx.x * blockDim.x + threadIdx.x;
    if (idx >= B_ * NH_ * H_) return;
    const int k = idx % H_;
    const int h = (idx / H_) % NH_;
    const int b = idx / (H_ * NH_);
    const float* p = ctx + (long)b * M128_ * H_ + (long)h * H_ + k;
    float sv = 0.f;
#pragma unroll
    for (int t = 0; t < T_; ++t) sv += p[(long)t * NH_ * H_];
    out[(long)b * NH_ * H_ + (long)h * H_ + k] = sv * (1.0f / T_);
}

// obar[b,c] = sum_t attm[b*128 + t*NH + h(c)] * V[(b*T+t)*H + c]
__global__ void ohead2_k(const float* __restrict__ attm, const float* __restrict__ V,
                         float* __restrict__ outb)
{
    const int idx = blockIdx.x * blockDim.x + threadIdx.x;
    if (idx >= B_ * H_) return;
    const int c = idx & (H_ - 1);
    const int b = idx >> 10;
    const int h = c >> 7;
    float sv = 0.f;
#pragma unroll
    for (int t = 0; t < T_; ++t)
        sv += attm[b * M128_ + t * NH_ + h] * V[((long)(b * T_ + t)) * H_ + c];
    outb[idx] = sv;
}

__global__ void cat3_k(const float* __restrict__ vs, const float* __restrict__ vt,
                       const float* __restrict__ vo, float* __restrict__ out)
{
    const int idx = blockIdx.x * blockDim.x + threadIdx.x;
    if (idx >= B_ * 3 * H_) return;
    const int k = idx % (3 * H_);
    const int b = idx / (3 * H_);
    float v;
    if (k < H_)           v = vs[b * H_ + k];
    else if (k < 2 * H_)  v = vt[b * H_ + k - H_];
    else                  v = vo[b * H_ + k - 2 * H_];
    out[idx] = v;
}

__global__ void ln_k(const float* __restrict__ cat3, const float* __restrict__ g,
                     const float* __restrict__ bta, float* __restrict__ out)
{
    const int b = blockIdx.x;
    const int tid = threadIdx.x;
    __shared__ float buf[3 * H_];
    __shared__ float red[4];
    const float* src = cat3 + (long)b * 3 * H_;
    float sv = 0.f;
    for (int i = tid; i < 3 * H_; i += 256) { const float x = src[i]; buf[i] = x; sv += x; }
    sv = wave_sum(sv);
    if ((tid & 63) == 0) red[tid >> 6] = sv;
    __syncthreads();
    const float mu = (red[0] + red[1] + red[2] + red[3]) * (1.f / (3 * H_));
    __syncthreads();
    float s2 = 0.f;
    for (int i = tid; i < 3 * H_; i += 256) { const float d0 = buf[i] - mu; s2 += d0 * d0; }
    s2 = wave_sum(s2);
    if ((tid & 63) == 0) red[tid >> 6] = s2;
    __syncthreads();
    const float var = (red[0] + red[1] + red[2] + red[3]) * (1.f / (3 * H_));
    const float rstd = rsqrtf(var + 1e-5f);
    float* dst = out + (long)b * 3 * H_;
    for (int i = tid; i < 3 * H_; i += 256) dst[i] = (buf[i] - mu) * rstd * g[i] + bta[i];
}

__global__ void mul_k(float* __restrict__ a, const float* __restrict__ b2, int n)
{
    const int idx = blockIdx.x * blockDim.x + threadIdx.x;
    if (idx < n) a[idx] *= b2[idx];
}

__global__ void fuse_k(const float* __restrict__ g, const float* __restrict__ flin,
                       const float* __restrict__ bil, float* __restrict__ fused)
{
    const int idx = blockIdx.x * blockDim.x + threadIdx.x;
    if (idx >= B_ * H_) return;
    const float gg = g[idx];
    fused[idx] = gg * flin[idx] + (1.f - gg) * bil[idx];
}

__global__ void catfv_k(const float* __restrict__ fused, const float* __restrict__ vt,
                        float* __restrict__ out)
{
    const int idx = blockIdx.x * blockDim.x + threadIdx.x;
    if (idx >= B_ * 2 * H_) return;
    const int k = idx % (2 * H_);
    const int b = idx / (2 * H_);
    out[idx] = (k < H_) ? fused[b * H_ + k] : vt[b * H_ + k - H_];
}

__global__ void route_k(const float* __restrict__ glog, float* __restrict__ gp)
{
    const int b = blockIdx.x * blockDim.x + threadIdx.x;
    if (b >= B_) return;
    const float x0 = glog[b * 3], x1 = glog[b * 3 + 1], x2 = glog[b * 3 + 2];
    const float m1 = fmaxf(x0, fmaxf(x1, x2));
    float thr;
    if (x0 == m1)      thr = fmaxf(x1, x2);
    else if (x1 == m1) thr = fmaxf(x0, x2);
    else               thr = fmaxf(x0, x1);
    const float y0 = (x0 >= thr) ? x0 : -1e9f;
    const float y1 = (x1 >= thr) ? x1 : -1e9f;
    const float y2 = (x2 >= thr) ? x2 : -1e9f;
    const float mm = fmaxf(y0, fmaxf(y1, y2));
    const float e0 = expf(y0 - mm), e1 = expf(y1 - mm), e2 = expf(y2 - mm);
    const float inv = 1.f / (e0 + e1 + e2);
    gp[b * 3] = e0 * inv; gp[b * 3 + 1] = e1 * inv; gp[b * 3 + 2] = e2 * inv;
}

__global__ void epsm_k(float* __restrict__ elog)
{
    const int idx = blockIdx.x * blockDim.x + threadIdx.x;
    if (idx >= B_ * G_) return;
    float* p = elog + (long)idx * E_;
    float m = p[0];
#pragma unroll
    for (int e = 1; e < E_; ++e) m = fmaxf(m, p[e]);
    float sum = 0.f;
    float v[E_];
#pragma unroll
    for (int e = 0; e < E_; ++e) { v[e] = expf(p[e] - m); sum += v[e]; }
    const float inv = 1.f / sum;
#pragma unroll
    for (int e = 0; e < E_; ++e) p[e] = v[e] * inv;
}

__global__ void moe_k(const float* __restrict__ y, const float* __restrict__ gp,
                      const float* __restrict__ ep, const float* __restrict__ fused,
                      float* __restrict__ res)
{
    const int idx = blockIdx.x * blockDim.x + threadIdx.x;
    if (idx >= B_ * H_) return;
    const int hh = idx & (H_ - 1);
    const int b = idx >> 10;
    float acc = fused[idx];
#pragma unroll
    for (int ge = 0; ge < GE_; ++ge) {
        const float w = gp[b * G_ + (ge >> 3)] * ep[b * GE_ + ge];
        acc += w * y[(long)b * (GE_ * H_) + ge * H_ + hh];
    }
    res[idx] = acc;
}

// -------------------- attention module helper (t2s / ca pattern) --------------------
// Qsrc: [B*T, H] projected queries (bias included). Computes vout = [B,H].
static void attn_tq(hipStream_t s, const float* Qsrc,
                    const float* w_in, const float* b_in,
                    const float* w_out, const float* b_out,
                    const float* h_sent,
                    float* BIGp, float* SCp, float* OFFSp, float* CTXBp,
                    float* OBARp, float* vout)
{
    const float rscale = 0.08838834764831845f; // 1/sqrt(128)
    headdot_k<<<dim3(128), dim3(256), 0, s>>>(Qsrc, b_in + H_, OFFSp);
    // A[b, t*NH+h, :] = Q_h[b,t] @ Wk_h   (TRANSB=0, z = head)
    g_launch(s, 0, 0, Qsrc, w_in + (long)H_ * H_, nullptr, nullptr, BIGp,
             B_, T_, H_, DH_,
             (long)T_ * H_, H_, DH_,
             H_, (long)DH_ * H_, 0,
             (long)M128_ * H_, (long)NH_ * H_, H_, 0, 1.f, NH_);
    // scores[b, m, s] = scale*(A . h_sent + off)   (z = b)
    g_launch(s, 1, 0, BIGp, h_sent, nullptr, OFFSp, SCp,
             1, M128_, S_, H_,
             0, H_, (long)M128_ * H_,
             H_, (long)S_ * H_, 0,
             0, S_, (long)M128_ * S_, M128_, rscale, B_);
    softmax_rows_k<<<dim3(B_ * M128_), dim3(64), 0, s>>>(SCp);
    // ctx[b, m, :] = att @ h_sent   (z = b) — overwrites BIG (A no longer needed)
    g_launch(s, 0, 0, SCp, h_sent, nullptr, nullptr, BIGp,
             1, M128_, H_, S_,
             0, S_, (long)M128_ * S_,
             H_, (long)S_ * H_, 0,
             0, H_, (long)M128_ * H_, 0, 1.f, B_);
    ctxbar_k<<<dim3((B_ * NH_ * H_ + 255) / 256), dim3(256), 0, s>>>(BIGp, CTXBp);
    // obar[b, h*DH+j] = Wv_h ctxbar + bv  (z = head)
    g_launch(s, 1, 0, CTXBp, w_in + (long)2 * H_ * H_, b_in + 2 * H_, nullptr, OBARp,
             1, B_, DH_, H_,
             0, (long)NH_ * H_, H_,
             H_, (long)DH_ * H_, DH_,
             0, H_, DH_, 0, 1.f, NH_);
    // vout = obar @ w_out^T + b_out
    g_launch(s, 1, 0, OBARp, w_out, b_out, nullptr, vout,
             1, B_, H_, H_, 0, H_, 0, H_, 0, 0, 0, H_, 0, 0, 1.f, 1);
}

// -------------------- entry --------------------
extern "C" void kernel_launch(void* const* d_in, const int* in_sizes, int n_in,
                              void* d_out, int out_size, void* d_ws, size_t ws_size,
                              hipStream_t stream)
{
    const float* h_sent  = (const float*)d_in[0];
    const float* h_term  = (const float*)d_in[1];
    const float* ts_in_w = (const float*)d_in[2];
    const float* ts_out_w= (const float*)d_in[3];
    const float* st_in_w = (const float*)d_in[4];
    const float* st_out_w= (const float*)d_in[5];
    const float* ca_in_w = (const float*)d_in[6];
    const float* ca_out_w= (const float*)d_in[7];
    const float* opq_w   = (const float*)d_in[8];
    const float* fuse_w  = (const float*)d_in[9];
    const float* gate_w  = (const float*)d_in[10];
    const float* bs_w    = (const float*)d_in[11];
    const float* bt_w    = (const float*)d_in[12];
    const float* bo_w    = (const float*)d_in[13];
    const float* cond_w  = (const float*)d_in[14];
    const float* gr_w    = (const float*)d_in[15];
    const float* er_w    = (const float*)d_in[16];
    const float* e_w1    = (const float*)d_in[17];
    const float* e_w2    = (const float*)d_in[18];
    const float* cls_w   = (const float*)d_in[19];
    const float* ts_in_b = (const float*)d_in[20];
    const float* ts_out_b= (const float*)d_in[21];
    const float* st_in_b = (const float*)d_in[22];
    const float* st_out_b= (const float*)d_in[23];
    const float* ca_in_b = (const float*)d_in[24];
    const float* ca_out_b= (const float*)d_in[25];
    const float* fuse_b  = (const float*)d_in[26];
    const float* gate_b  = (const float*)d_in[27];
    const float* bs_b    = (const float*)d_in[28];
    const float* bt_b    = (const float*)d_in[29];
    const float* bo_b    = (const float*)d_in[30];
    const float* cond_b  = (const float*)d_in[31];
    const float* gr_b    = (const float*)d_in[32];
    const float* er_b    = (const float*)d_in[33];
    const float* e_b1    = (const float*)d_in[34];
    const float* e_b2    = (const float*)d_in[35];
    const float* cls_b   = (const float*)d_in[36];
    const float* ln_b    = (const float*)d_in[37];
    const float* ln_g    = (const float*)d_in[38];
    (void)in_sizes; (void)n_in; (void)out_size; (void)ws_size;

    float* ws = (float*)d_ws;
    size_t off = 0;
    auto alloc = [&](size_t n) { float* p = ws + off; off += (n + 63) & ~(size_t)63; return p; };
    float* BIG  = alloc(33554432); // [B][128][H] A/ctx; later h1 [B][24*I]
    float* SC   = alloc(8388608);  // [B][128][S] scores; later y [B][24*H]
    float* QB   = alloc(4194304);  // [B*T, H]
    float* QB2  = alloc(4194304);  // [B*T, H]
    float* OFFS = alloc(32768);    // [B][128]
    float* ATTM = alloc(32768);    // [B][128]
    float* CTXB = alloc(2097152);  // [B][NH][H]
    float* OBAR = alloc(262144);   // [B][H]
    float* VTERM= alloc(262144);
    float* VSENT= alloc(262144);
    float* VOP  = alloc(262144);
    float* CAT3 = alloc(786432);   // [B][3H]
    float* LNC  = alloc(786432);
    float* FLIN = alloc(262144);
    float* GATE = alloc(262144);
    float* BSV  = alloc(65536);    // [B][R]
    float* BTV  = alloc(65536);
    float* BIL  = alloc(262144);
    float* FUSED= alloc(262144);
    float* CATFV= alloc(524288);   // [B][2H]
    float* COND = alloc(262144);
    float* GLOG = alloc(1024);
    float* GP   = alloc(1024);
    float* ELOG = alloc(8192);     // [B][24], ep in place
    float* RES  = alloc(262144);
    // total ≈ 57.4M floats ≈ 229 MB

    hipStream_t s = stream;

    // ================= t2s (v_term) =================
    g_launch(s, 1, 0, h_term, ts_in_w, ts_in_b, nullptr, QB,
             1, B_ * T_, H_, H_, 0, H_, 0, H_, 0, 0, 0, H_, 0, 0, 1.f, 1);
    attn_tq(s, QB, ts_in_w, ts_in_b, ts_out_w, ts_out_b, h_sent,
            BIG, SC, OFFS, CTXB, OBAR, VTERM);

    // ================= ca (v_op) =================
    g_launch(s, 1, 0, h_term, opq_w, nullptr, nullptr, QB2,
             1, B_ * T_, H_, H_, 0, H_, 0, H_, 0, 0, 0, H_, 0, 0, 1.f, 1);
    g_launch(s, 1, 0, QB2, ca_in_w, ca_in_b, nullptr, QB,
             1, B_ * T_, H_, H_, 0, H_, 0, H_, 0, 0, 0, H_, 0, 0, 1.f, 1);
    attn_tq(s, QB, ca_in_w, ca_in_b, ca_out_w, ca_out_b, h_sent,
            BIG, SC, OFFS, CTXB, OBAR, VOP);

    // ================= s2t (v_sent) =================
    // K_st, V_st of h_term
    g_launch(s, 1, 0, h_term, st_in_w + (long)H_ * H_, st_in_b + H_, nullptr, QB,
             1, B_ * T_, H_, H_, 0, H_, 0, H_, 0, 0, 0, H_, 0, 0, 1.f, 1);
    g_launch(s, 1, 0, h_term, st_in_w + (long)2 * H_ * H_, st_in_b + 2 * H_, nullptr, QB2,
             1, B_ * T_, H_, H_, 0, H_, 0, H_, 0, 0, 0, H_, 0, 0, 1.f, 1);
    headdot_k<<<dim3(128), dim3(256), 0, s>>>(QB, st_in_b, OFFS); // K_h . bq_h
    // A2[b, t*NH+h, :] = K_h[b,t] @ Wq_h
    g_launch(s, 0, 0, QB, st_in_w, nullptr, nullptr, BIG,
             B_, T_, H_, DH_,
             (long)T_ * H_, H_, DH_,
             H_, (long)DH_ * H_, 0,
             (long)M128_ * H_, (long)NH_ * H_, H_, 0, 1.f, NH_);
    // scores2[b, t*NH+h, s]
    g_launch(s, 1, 0, BIG, h_sent, nullptr, OFFS, SC,
             1, M128_, S_, H_,
             0, H_, (long)M128_ * H_,
             H_, (long)S_ * H_, 0,
             0, S_, (long)M128_ * S_, M128_, 0.08838834764831845f, B_);
    softmax_t_k<<<dim3((B_ * NH_ * S_ + 255) / 256), dim3(256), 0, s>>>(SC);
    rowmean_k<<<dim3(B_ * M128_), dim3(64), 0, s>>>(SC, ATTM);
    ohead2_k<<<dim3((B_ * H_ + 255) / 256), dim3(256), 0, s>>>(ATTM, QB2, OBAR);
    g_launch(s, 1, 0, OBAR, st_out_w, st_out_b, nullptr, VSENT,
             1, B_, H_, H_, 0, H_, 0, H_, 0, 0, 0, H_, 0, 0, 1.f, 1);

    // ================= fusion head =================
    cat3_k<<<dim3((B_ * 3 * H_ + 255) / 256), dim3(256), 0, s>>>(VSENT, VTERM, VOP, CAT3);
    ln_k<<<dim3(B_), dim3(256), 0, s>>>(CAT3, ln_g, ln_b, LNC);
    g_launch(s, 1, 0, LNC, fuse_w, fuse_b, nullptr, FLIN,
             1, B_, H_, 3 * H_, 0, 3 * H_, 0, 3 * H_, 0, 0, 0, H_, 0, 0, 1.f, 1);
    g_launch(s, 1, 2, CAT3, gate_w, gate_b, nullptr, GATE,
             1, B_, H_, 3 * H_, 0, 3 * H_, 0, 3 * H_, 0, 0, 0, H_, 0, 0, 1.f, 1);
    g_launch(s, 1, 0, VSENT, bs_w, bs_b, nullptr, BSV,
             1, B_, R_, H_, 0, H_, 0, H_, 0, 0, 0, R_, 0, 0, 1.f, 1);
    g_launch(s, 1, 0, VTERM, bt_w, bt_b, nullptr, BTV,
             1, B_, R_, H_, 0, H_, 0, H_, 0, 0, 0, R_, 0, 0, 1.f, 1);
    mul_k<<<dim3((B_ * R_ + 255) / 256), dim3(256), 0, s>>>(BSV, BTV, B_ * R_);
    g_launch(s, 1, 0, BSV, bo_w, bo_b, nullptr, BIL,
             1, B_, H_, R_, 0, R_, 0, R_, 0, 0, 0, H_, 0, 0, 1.f, 1);
    fuse_k<<<dim3((B_ * H_ + 255) / 256), dim3(256), 0, s>>>(GATE, FLIN, BIL, FUSED);
    catfv_k<<<dim3((B_ * 2 * H_ + 255) / 256), dim3(256), 0, s>>>(FUSED, VTERM, CATFV);
    g_launch(s, 1, 0, CATFV, cond_w, cond_b, nullptr, COND,
             1, B_, H_, 2 * H_, 0, 2 * H_, 0, 2 * H_, 0, 0, 0, H_, 0, 0, 1.f, 1);

    // ================= routing =================
    g_launch(s, 1, 0, FUSED, gr_w, gr_b, nullptr, GLOG,
             1, B_, G_, H_, 0, H_, 0, H_, 0, 0, 0, G_, 0, 0, 1.f, 1);
    route_k<<<dim3(1), dim3(256), 0, s>>>(GLOG, GP);
    g_launch(s, 1, 0, COND, er_w, er_b, nullptr, ELOG,
             1, B_, GE_, H_, 0, H_, 0, H_, 0, 0, 0, GE_, 0, 0, 1.f, 1);
    epsm_k<<<dim3(3), dim3(256), 0, s>>>(ELOG);

    // ================= MoE =================
    // h1[b, z*I + i] = gelu(fused @ e_w1[z]^T + e_b1[z])   (z = g*E+e)
    g_launch(s, 1, 1, FUSED, e_w1, e_b1, nullptr, BIG,
             1, B_, I_, H_,
             0, H_, 0,
             H_, (long)I_ * H_, I_,
             0, (long)GE_ * I_, I_, 0, 1.f, GE_);
    // y[b, z*H + h] = h1[z] @ e_w2[z]^T + e_b2[z]
    g_launch(s, 1, 0, BIG, e_w2, e_b2, nullptr, SC,
             1, B_, H_, I_,
             0, (long)GE_ * I_, I_,
             I_, (long)H_ * I_, H_,
             0, (long)GE_ * H_, H_, 0, 1.f, GE_);
    moe_k<<<dim3((B_ * H_ + 255) / 256), dim3(256), 0, s>>>(SC, GP, ELOG, FUSED, RES);

    // ================= classifier =================
    g_launch(s, 1, 0, RES, cls_w, cls_b, nullptr, (float*)d_out,
             1, B_, L_, H_, 0, H_, 0, H_, 0, 0, 0, L_, 0, 0, 1.f, 1);
}

// Round 4
// 2828.097 us; speedup vs baseline: 1.9183x; 1.9183x over previous
//
#include <hip/hip_runtime.h>
#include <math.h>

// ---------------------------------------------------------------------------
// HAGMoE — round 4: ALL heavy GEMMs via split-bf16 (hi+lo, 3-MFMA) — f32-grade
// end-to-end (R1 numerics class, MFMA speed). No single-rounded bf16 tensor
// anywhere. ctx chain stays f32 VALU (ctxbar = (mean_t probs) @ h_sent).
// Workspace ~227.6 MB (<= R1's proven 229.6 MB envelope); CTXB aliases SC,
// H1 aliases BIG, y aliases SC, one shared wT buffer.
// ---------------------------------------------------------------------------

#define B_    256
#define S_    256
#define T_    16
#define H_    1024
#define NH_   8
#define DH_   128
#define M128_ 128
#define G_    3
#define E_    8
#define I_    4096
#define R_    256
#define L_    3
#define GE_   24

using bf16x8 = __attribute__((ext_vector_type(8))) __bf16;
using f32x4  = __attribute__((ext_vector_type(4))) float;

// -------------------- wave helpers --------------------
__device__ inline float wave_sum(float v) {
    for (int o = 32; o > 0; o >>= 1) v += __shfl_xor(v, o);
    return v;
}
__device__ inline float wave_max(float v) {
    for (int o = 32; o > 0; o >>= 1) v = fmaxf(v, __shfl_xor(v, o));
    return v;
}

// ===================== split-bf16 (hi+lo) MFMA GEMM =====================
// C[r,n] = act( scale*(sum_k A[r,k]*Bt[n,k] + roff[r]) + bias[n] )
// A,B read as f32, split x = hi + lo (bf16 each); acc += ah*bh + ah*bl + al*bh
// -> ~2^-16 relative error (f32-grade). 128x128 tile, 4 waves, BK=32.
// Row decode: r1 = r >> m2shift, r2 = r & m2mask.
template <int ACT>
__global__ __launch_bounds__(256) void sgemm_k(
    const float* __restrict__ Ap, const float* __restrict__ Bp,
    const float* __restrict__ biasp, const float* __restrict__ roffp,
    float* __restrict__ Cf,
    int K, int m2shift, int m2mask,
    long sA1, long sA2, long sAz,
    long ldb, long sBz, long sBias,
    long sC1, long sC2, long sCz, long sRoff,
    float scale)
{
    const int z    = blockIdx.z;
    const int row0 = blockIdx.y * 128;
    const int col0 = blockIdx.x * 128;
    const float* Ab = Ap + (long)z * sAz;
    const float* Bb = Bp + (long)z * sBz;
    const float* biasb = biasp ? biasp + (long)z * sBias : nullptr;
    const float* roffb = roffp ? roffp + (long)z * sRoff : nullptr;

    __shared__ __bf16 Ahs[128 * 40];
    __shared__ __bf16 Als[128 * 40];
    __shared__ __bf16 Bhs[128 * 40];
    __shared__ __bf16 Bls[128 * 40];

    const int tid  = threadIdx.x;
    const int lane = tid & 63;
    const int wid  = tid >> 6;
    const int wm = (wid >> 1) * 64;
    const int wn = (wid & 1) * 64;
    const int fr  = lane & 15;
    const int fkb = (lane >> 4) * 16;   // byte offset of the 8-bf16 k-group
    const int qrow = tid >> 2;
    const int c4   = tid & 3;

    f32x4 acc[4][4] = {};

    for (int k0 = 0; k0 < K; k0 += 32) {
        __syncthreads();
#pragma unroll
        for (int rep = 0; rep < 2; ++rep) {
            const int row = qrow + rep * 64;
            {   // stage A (split)
                const int r = row0 + row;
                const int r1 = r >> m2shift, r2 = r & m2mask;
                const float* src = Ab + (long)r1 * sA1 + (long)r2 * sA2 + k0 + c4 * 8;
                float4 f0 = *(const float4*)src;
                float4 f1 = *(const float4*)(src + 4);
                const float fv[8] = {f0.x, f0.y, f0.z, f0.w, f1.x, f1.y, f1.z, f1.w};
                bf16x8 hi, lo;
#pragma unroll
                for (int j = 0; j < 8; ++j) {
                    const __bf16 h = (__bf16)fv[j];
                    hi[j] = h; lo[j] = (__bf16)(fv[j] - (float)h);
                }
                *(bf16x8*)&Ahs[row * 40 + c4 * 8] = hi;
                *(bf16x8*)&Als[row * 40 + c4 * 8] = lo;
            }
            {   // stage B (split); Bt rows = output cols
                const float* src = Bb + (long)(col0 + row) * ldb + k0 + c4 * 8;
                float4 f0 = *(const float4*)src;
                float4 f1 = *(const float4*)(src + 4);
                const float fv[8] = {f0.x, f0.y, f0.z, f0.w, f1.x, f1.y, f1.z, f1.w};
                bf16x8 hi, lo;
#pragma unroll
                for (int j = 0; j < 8; ++j) {
                    const __bf16 h = (__bf16)fv[j];
                    hi[j] = h; lo[j] = (__bf16)(fv[j] - (float)h);
                }
                *(bf16x8*)&Bhs[row * 40 + c4 * 8] = hi;
                *(bf16x8*)&Bls[row * 40 + c4 * 8] = lo;
            }
        }
        __syncthreads();
        bf16x8 bh4[4], bl4[4];
#pragma unroll
        for (int n = 0; n < 4; ++n) {
            bh4[n] = *(const bf16x8*)((const char*)&Bhs[(wn + n * 16 + fr) * 40] + fkb);
            bl4[n] = *(const bf16x8*)((const char*)&Bls[(wn + n * 16 + fr) * 40] + fkb);
        }
#pragma unroll
        for (int m = 0; m < 4; ++m) {
            const bf16x8 ah = *(const bf16x8*)((const char*)&Ahs[(wm + m * 16 + fr) * 40] + fkb);
            const bf16x8 al = *(const bf16x8*)((const char*)&Als[(wm + m * 16 + fr) * 40] + fkb);
#pragma unroll
            for (int n = 0; n < 4; ++n) {
                acc[m][n] = __builtin_amdgcn_mfma_f32_16x16x32_bf16(ah, bh4[n], acc[m][n], 0, 0, 0);
                acc[m][n] = __builtin_amdgcn_mfma_f32_16x16x32_bf16(ah, bl4[n], acc[m][n], 0, 0, 0);
                acc[m][n] = __builtin_amdgcn_mfma_f32_16x16x32_bf16(al, bh4[n], acc[m][n], 0, 0, 0);
            }
        }
    }

    // epilogue: C/D mapping col = lane&15, row = (lane>>4)*4 + reg
    float* Cfb = Cf + (long)z * sCz;
    const int lr4 = (lane >> 4) * 4;
#pragma unroll
    for (int m = 0; m < 4; ++m) {
#pragma unroll
        for (int r = 0; r < 4; ++r) {
            const int rr = row0 + wm + m * 16 + lr4 + r;
            const int r1 = rr >> m2shift, r2 = rr & m2mask;
            const float ro = roffp ? roffb[rr] : 0.f;
            const long cb = (long)r1 * sC1 + (long)r2 * sC2;
#pragma unroll
            for (int n = 0; n < 4; ++n) {
                const int cc = col0 + wn + n * 16 + fr;
                float v = (acc[m][n][r] + ro) * scale;
                if (biasp) v += biasb[cc];
                if (ACT == 1) v = 0.5f * v * (1.0f + erff(v * 0.70710678118654752f)); // exact gelu
                else if (ACT == 2) v = 1.0f / (1.0f + expf(-v));                      // sigmoid
                Cfb[cb + cc] = v;
            }
        }
    }
}

static void sg(hipStream_t s, int act,
               const float* A, const float* B, const float* bias, const float* roff,
               float* Cf, int M, int N, int K, int m2shift,
               long sA1, long sA2, long sAz, long ldb, long sBz, long sBias,
               long sC1, long sC2, long sCz, long sRoff, float scale, int Z)
{
    dim3 g(N / 128, M / 128, Z), b(256);
    const int m2mask = (1 << m2shift) - 1;
#define SARGS A, B, bias, roff, Cf, K, m2shift, m2mask, sA1, sA2, sAz, ldb, sBz, sBias, sC1, sC2, sCz, sRoff, scale
    if (act == 1)      sgemm_k<1><<<g, b, 0, s>>>(SARGS);
    else if (act == 2) sgemm_k<2><<<g, b, 0, s>>>(SARGS);
    else               sgemm_k<0><<<g, b, 0, s>>>(SARGS);
#undef SARGS
}

// ===================== f32 VALU GEMM (small N only) =====================
#define BM 64
#define BN 64
#define BK 16
__global__ __launch_bounds__(256) void gemm_k(
    const float* __restrict__ Ap, const float* __restrict__ Bp,
    const float* __restrict__ biasp, float* __restrict__ Cp,
    int M, int N, int K, long sA1, long ldb, long sC1)
{
    const int row0 = blockIdx.y * BM;
    const int col0 = blockIdx.x * BN;
    const int tid = threadIdx.x;
    __shared__ float As[BK][BM + 4];
    __shared__ float Bs[BK][BN + 4];
    float acc[4][4] = {};
    const int tm = (tid >> 4) << 2;
    const int tn = (tid & 15) << 2;
    for (int k0 = 0; k0 < K; k0 += BK) {
        {
            const int i = tid << 2;
            const int m = i >> 4, kk = i & 15;
            const int r = row0 + m;
            float4 v = make_float4(0.f, 0.f, 0.f, 0.f);
            if (r < M) v = *(const float4*)(Ap + (long)r * sA1 + k0 + kk);
            As[kk + 0][m] = v.x; As[kk + 1][m] = v.y;
            As[kk + 2][m] = v.z; As[kk + 3][m] = v.w;
        }
        {
            const int i = tid << 2;
            const int n = i >> 4, kk = i & 15;
            const int c = col0 + n;
            float4 v = make_float4(0.f, 0.f, 0.f, 0.f);
            if (c < N) v = *(const float4*)(Bp + (long)c * ldb + k0 + kk);
            Bs[kk + 0][n] = v.x; Bs[kk + 1][n] = v.y;
            Bs[kk + 2][n] = v.z; Bs[kk + 3][n] = v.w;
        }
        __syncthreads();
#pragma unroll
        for (int kk = 0; kk < BK; ++kk) {
            const float4 av = *(const float4*)&As[kk][tm];
            const float4 bv = *(const float4*)&Bs[kk][tn];
            acc[0][0] += av.x * bv.x; acc[0][1] += av.x * bv.y;
            acc[0][2] += av.x * bv.z; acc[0][3] += av.x * bv.w;
            acc[1][0] += av.y * bv.x; acc[1][1] += av.y * bv.y;
            acc[1][2] += av.y * bv.z; acc[1][3] += av.y * bv.w;
            acc[2][0] += av.z * bv.x; acc[2][1] += av.z * bv.y;
            acc[2][2] += av.z * bv.z; acc[2][3] += av.z * bv.w;
            acc[3][0] += av.w * bv.x; acc[3][1] += av.w * bv.y;
            acc[3][2] += av.w * bv.z; acc[3][3] += av.w * bv.w;
        }
        __syncthreads();
    }
#pragma unroll
    for (int i2 = 0; i2 < 4; ++i2) {
        const int r = row0 + tm + i2;
        if (r >= M) continue;
        float* crow = Cp + (long)r * sC1;
#pragma unroll
        for (int j = 0; j < 4; ++j) {
            const int c = col0 + tn + j;
            if (c >= N) continue;
            float v = acc[i2][j];
            if (biasp) v += biasp[c];
            crow[c] = v;
        }
    }
}

static void g_launch(hipStream_t s, const float* A, const float* Bw, const float* bias,
                     float* C, int M, int N, int K, long sA1, long ldb, long sC1)
{
    dim3 grid((N + BN - 1) / BN, (M + BM - 1) / BM, 1);
    gemm_k<<<grid, dim3(256), 0, s>>>(A, Bw, bias, C, M, N, K, sA1, ldb, sC1);
}

// ===================== transpose (f32 -> f32) =====================
__global__ void tT_k(const float* __restrict__ src, float* __restrict__ dst, int R, int C)
{
    __shared__ float t[32][33];
    const int c0 = blockIdx.x * 32, r0 = blockIdx.y * 32;
    const int tx = threadIdx.x & 31, ty = threadIdx.x >> 5;
#pragma unroll
    for (int i = 0; i < 4; ++i) {
        const int r = ty + i * 8;
        t[r][tx] = src[(long)(r0 + r) * C + c0 + tx];
    }
    __syncthreads();
#pragma unroll
    for (int i = 0; i < 4; ++i) {
        const int r = ty + i * 8;
        dst[(long)(c0 + r) * R + r0 + tx] = t[tx][r];
    }
}

// ===================== glue kernels (all f32, R1-proven) =====================
__global__ void headdot_k(const float* __restrict__ Q, const float* __restrict__ bvec,
                          float* __restrict__ out)
{
    const int idx = blockIdx.x * blockDim.x + threadIdx.x;
    if (idx >= B_ * T_ * NH_) return;
    const int h = idx % NH_;
    const int t = (idx / NH_) % T_;
    const int b = idx / (NH_ * T_);
    const float* q = Q + ((long)(b * T_ + t)) * H_ + h * DH_;
    const float* bb = bvec + h * DH_;
    float sum = 0.f;
    for (int k = 0; k < DH_; ++k) sum += q[k] * bb[k];
    out[idx] = sum;
}

__global__ void softmax_rows_k(float* __restrict__ x)
{
    const long row = blockIdx.x;
    float* p = x + row * S_;
    const int t = threadIdx.x;
    float v0 = p[t], v1 = p[t + 64], v2 = p[t + 128], v3 = p[t + 192];
    float m = wave_max(fmaxf(fmaxf(v0, v1), fmaxf(v2, v3)));
    v0 = expf(v0 - m); v1 = expf(v1 - m); v2 = expf(v2 - m); v3 = expf(v3 - m);
    const float inv = 1.f / wave_sum(v0 + v1 + v2 + v3);
    p[t] = v0 * inv; p[t + 64] = v1 * inv; p[t + 128] = v2 * inv; p[t + 192] = v3 * inv;
}

__global__ void softmax_t_k(float* __restrict__ sc)
{
    const int idx = blockIdx.x * blockDim.x + threadIdx.x;
    if (idx >= B_ * NH_ * S_) return;
    const int s = idx % S_;
    const int h = (idx / S_) % NH_;
    const int b = idx / (S_ * NH_);
    float* base = sc + (long)b * M128_ * S_ + (long)h * S_ + s;
    float v[T_];
    float mx = -1e30f;
#pragma unroll
    for (int t = 0; t < T_; ++t) { v[t] = base[(long)t * NH_ * S_]; mx = fmaxf(mx, v[t]); }
    float sum = 0.f;
#pragma unroll
    for (int t = 0; t < T_; ++t) { v[t] = expf(v[t] - mx); sum += v[t]; }
    const float inv = 1.f / sum;
#pragma unroll
    for (int t = 0; t < T_; ++t) base[(long)t * NH_ * S_] = v[t] * inv;
}

__global__ void rowmean_k(const float* __restrict__ x, float* __restrict__ out)
{
    const int row = blockIdx.x;
    const float* p = x + (long)row * S_;
    float sv = 0.f;
    for (int i = threadIdx.x; i < S_; i += 64) sv += p[i];
    sv = wave_sum(sv);
    if (threadIdx.x == 0) out[row] = sv * (1.0f / S_);
}

// pbar[b][h][s] = mean_t probs[b][t*NH+h][s]
__global__ void pbar_k(const float* __restrict__ sc, float* __restrict__ pb)
{
    const int idx = blockIdx.x * blockDim.x + threadIdx.x;
    if (idx >= B_ * NH_ * S_) return;
    const int s = idx & 255;
    const int h = (idx >> 8) & 7;
    const int b = idx >> 11;
    const float* base = sc + (long)b * M128_ * S_ + (long)h * S_ + s;
    float sum = 0.f;
#pragma unroll
    for (int t = 0; t < T_; ++t) sum += base[(long)t * NH_ * S_];
    pb[idx] = sum * (1.0f / T_);
}

// ctxbar[b][h][k] = sum_s pbar[b][h][s] * h_sent[b][s][k]   (pure f32)
__global__ __launch_bounds__(256) void ctxw_k(const float* __restrict__ pbar,
                                              const float* __restrict__ hs,
                                              float* __restrict__ out)
{
    const int b = blockIdx.x;
    __shared__ float pl[NH_][S_];
    const int tid = threadIdx.x;
    for (int i = tid; i < NH_ * S_; i += 256) pl[i >> 8][i & 255] = pbar[(long)b * NH_ * S_ + i];
    __syncthreads();
    const int k0 = tid * 4;
    float4 acc[NH_] = {};
    const float* hb = hs + (long)b * S_ * H_;
    for (int s = 0; s < S_; ++s) {
        const float4 v = *(const float4*)(hb + (long)s * H_ + k0);
#pragma unroll
        for (int h = 0; h < NH_; ++h) {
            const float p = pl[h][s];
            acc[h].x += p * v.x; acc[h].y += p * v.y;
            acc[h].z += p * v.z; acc[h].w += p * v.w;
        }
    }
    float* ob = out + (long)b * NH_ * H_;
#pragma unroll
    for (int h = 0; h < NH_; ++h) *(float4*)(ob + h * H_ + k0) = acc[h];
}

__global__ void ohead2_k(const float* __restrict__ attm, const float* __restrict__ V,
                         float* __restrict__ outb)
{
    const int idx = blockIdx.x * blockDim.x + threadIdx.x;
    if (idx >= B_ * H_) return;
    const int c = idx & (H_ - 1);
    const int b = idx >> 10;
    const int h = c >> 7;
    float sv = 0.f;
#pragma unroll
    for (int t = 0; t < T_; ++t)
        sv += attm[b * M128_ + t * NH_ + h] * V[((long)(b * T_ + t)) * H_ + c];
    outb[idx] = sv;
}

__global__ void cat3_k(const float* __restrict__ vs, const float* __restrict__ vt,
                       const float* __restrict__ vo, float* __restrict__ out)
{
    const int idx = blockIdx.x * blockDim.x + threadIdx.x;
    if (idx >= B_ * 3 * H_) return;
    const int k = idx % (3 * H_);
    const int b = idx / (3 * H_);
    float v;
    if (k < H_)          v = vs[b * H_ + k];
    else if (k < 2 * H_) v = vt[b * H_ + k - H_];
    else                 v = vo[b * H_ + k - 2 * H_];
    out[idx] = v;
}

__global__ void ln_k(const float* __restrict__ cat3, const float* __restrict__ g,
                     const float* __restrict__ bta, float* __restrict__ out)
{
    const int b = blockIdx.x;
    const int tid = threadIdx.x;
    __shared__ float buf[3 * H_];
    __shared__ float red[4];
    const float* src = cat3 + (long)b * 3 * H_;
    float sv = 0.f;
    for (int i = tid; i < 3 * H_; i += 256) { const float x = src[i]; buf[i] = x; sv += x; }
    sv = wave_sum(sv);
    if ((tid & 63) == 0) red[tid >> 6] = sv;
    __syncthreads();
    const float mu = (red[0] + red[1] + red[2] + red[3]) * (1.f / (3 * H_));
    __syncthreads();
    float s2 = 0.f;
    for (int i = tid; i < 3 * H_; i += 256) { const float d0 = buf[i] - mu; s2 += d0 * d0; }
    s2 = wave_sum(s2);
    if ((tid & 63) == 0) red[tid >> 6] = s2;
    __syncthreads();
    const float var = (red[0] + red[1] + red[2] + red[3]) * (1.f / (3 * H_));
    const float rstd = rsqrtf(var + 1e-5f);
    float* dst = out + (long)b * 3 * H_;
    for (int i = tid; i < 3 * H_; i += 256)
        dst[i] = (buf[i] - mu) * rstd * g[i] + bta[i];
}

__global__ void mulf_k(const float* __restrict__ a, const float* __restrict__ b2,
                       float* __restrict__ out, int n)
{
    const int idx = blockIdx.x * blockDim.x + threadIdx.x;
    if (idx < n) out[idx] = a[idx] * b2[idx];
}

__global__ void fuse_k(const float* __restrict__ g, const float* __restrict__ flin,
                       const float* __restrict__ bil, float* __restrict__ fused)
{
    const int idx = blockIdx.x * blockDim.x + threadIdx.x;
    if (idx >= B_ * H_) return;
    const float gg = g[idx];
    fused[idx] = gg * flin[idx] + (1.f - gg) * bil[idx];
}

__global__ void catfv_k(const float* __restrict__ fused, const float* __restrict__ vt,
                        float* __restrict__ out)
{
    const int idx = blockIdx.x * blockDim.x + threadIdx.x;
    if (idx >= B_ * 2 * H_) return;
    const int k = idx % (2 * H_);
    const int b = idx / (2 * H_);
    out[idx] = (k < H_) ? fused[b * H_ + k] : vt[b * H_ + k - H_];
}

__global__ void route_k(const float* __restrict__ glog, float* __restrict__ gp)
{
    const int b = blockIdx.x * blockDim.x + threadIdx.x;
    if (b >= B_) return;
    const float x0 = glog[b * 3], x1 = glog[b * 3 + 1], x2 = glog[b * 3 + 2];
    const float m1 = fmaxf(x0, fmaxf(x1, x2));
    float thr;
    if (x0 == m1)      thr = fmaxf(x1, x2);
    else if (x1 == m1) thr = fmaxf(x0, x2);
    else               thr = fmaxf(x0, x1);
    const float y0 = (x0 >= thr) ? x0 : -1e9f;
    const float y1 = (x1 >= thr) ? x1 : -1e9f;
    const float y2 = (x2 >= thr) ? x2 : -1e9f;
    const float mm = fmaxf(y0, fmaxf(y1, y2));
    const float e0 = expf(y0 - mm), e1 = expf(y1 - mm), e2 = expf(y2 - mm);
    const float inv = 1.f / (e0 + e1 + e2);
    gp[b * 3] = e0 * inv; gp[b * 3 + 1] = e1 * inv; gp[b * 3 + 2] = e2 * inv;
}

__global__ void epsm_k(float* __restrict__ elog)
{
    const int idx = blockIdx.x * blockDim.x + threadIdx.x;
    if (idx >= B_ * G_) return;
    float* p = elog + (long)idx * E_;
    float m = p[0];
#pragma unroll
    for (int e = 1; e < E_; ++e) m = fmaxf(m, p[e]);
    float sum = 0.f;
    float v[E_];
#pragma unroll
    for (int e = 0; e < E_; ++e) { v[e] = expf(p[e] - m); sum += v[e]; }
    const float inv = 1.f / sum;
#pragma unroll
    for (int e = 0; e < E_; ++e) p[e] = v[e] * inv;
}

__global__ void moe_k(const float* __restrict__ y, const float* __restrict__ gp,
                      const float* __restrict__ ep, const float* __restrict__ fused,
                      float* __restrict__ res)
{
    const int idx = blockIdx.x * blockDim.x + threadIdx.x;
    if (idx >= B_ * H_) return;
    const int hh = idx & (H_ - 1);
    const int b = idx >> 10;
    float acc = fused[idx];
#pragma unroll
    for (int ge = 0; ge < GE_; ++ge) {
        const float w = gp[b * G_ + (ge >> 3)] * ep[b * GE_ + ge];
        acc += w * y[(long)b * (GE_ * H_) + ge * H_ + hh];
    }
    res[idx] = acc;
}

// ===================== entry =====================
extern "C" void kernel_launch(void* const* d_in, const int* in_sizes, int n_in,
                              void* d_out, int out_size, void* d_ws, size_t ws_size,
                              hipStream_t stream)
{
    const float* h_sent  = (const float*)d_in[0];
    const float* h_term  = (const float*)d_in[1];
    const float* ts_in_w = (const float*)d_in[2];
    const float* ts_out_w= (const float*)d_in[3];
    const float* st_in_w = (const float*)d_in[4];
    const float* st_out_w= (const float*)d_in[5];
    const float* ca_in_w = (const float*)d_in[6];
    const float* ca_out_w= (const float*)d_in[7];
    const float* opq_w   = (const float*)d_in[8];
    const float* fuse_w  = (const float*)d_in[9];
    const float* gate_w  = (const float*)d_in[10];
    const float* bs_w    = (const float*)d_in[11];
    const float* bt_w    = (const float*)d_in[12];
    const float* bo_w    = (const float*)d_in[13];
    const float* cond_w  = (const float*)d_in[14];
    const float* gr_w    = (const float*)d_in[15];
    const float* er_w    = (const float*)d_in[16];
    const float* e_w1    = (const float*)d_in[17];
    const float* e_w2    = (const float*)d_in[18];
    const float* cls_w   = (const float*)d_in[19];
    const float* ts_in_b = (const float*)d_in[20];
    const float* ts_out_b= (const float*)d_in[21];
    const float* st_in_b = (const float*)d_in[22];
    const float* st_out_b= (const float*)d_in[23];
    const float* ca_in_b = (const float*)d_in[24];
    const float* ca_out_b= (const float*)d_in[25];
    const float* fuse_b  = (const float*)d_in[26];
    const float* gate_b  = (const float*)d_in[27];
    const float* bs_b    = (const float*)d_in[28];
    const float* bt_b    = (const float*)d_in[29];
    const float* bo_b    = (const float*)d_in[30];
    const float* cond_b  = (const float*)d_in[31];
    const float* gr_b    = (const float*)d_in[32];
    const float* er_b    = (const float*)d_in[33];
    const float* e_b1    = (const float*)d_in[34];
    const float* e_b2    = (const float*)d_in[35];
    const float* cls_b   = (const float*)d_in[36];
    const float* ln_b    = (const float*)d_in[37];
    const float* ln_g    = (const float*)d_in[38];
    (void)in_sizes; (void)n_in; (void)out_size; (void)ws_size;

    float* ws = (float*)d_ws;
    size_t off = 0;
    auto allocF = [&](size_t n) { float* p = ws + off; off += (n + 63) & ~(size_t)63; return p; };

    float* SC    = allocF(8388608);   // scores [B][128][S]; CTXB alias; y alias
    float* QB    = allocF(4194304);   // [B*T, H]
    float* QB2   = allocF(4194304);
    float* OFFS  = allocF(32768);
    float* ATTM  = allocF(32768);
    float* PBAR  = allocF(524288);    // [B][8][S]
    float* OBAR  = allocF(262144);
    float* VTERM = allocF(262144);
    float* VSENT = allocF(262144);
    float* VOP   = allocF(262144);
    float* CAT3  = allocF(786432);
    float* LNC   = allocF(786432);
    float* FLIN  = allocF(262144);
    float* GATE  = allocF(262144);
    float* BSV   = allocF(65536);
    float* BTV   = allocF(65536);
    float* PROD  = allocF(65536);
    float* BIL   = allocF(262144);
    float* FUSED = allocF(262144);
    float* CATFV = allocF(524288);
    float* COND  = allocF(262144);
    float* GLOG  = allocF(1024);
    float* GP    = allocF(1024);
    float* ELOG  = allocF(8192);
    float* RES   = allocF(262144);
    float* wT    = allocF(1048576);   // shared transposed-weight buffer
    float* BIG   = allocF(33554432);  // A-fold [B][128][H] f32; later h1 [B][24*I]
    float* CTXB  = SC;                // alias: [B][8][H] (2.1M <= 8.4M, scores dead)
    float* H1    = BIG;               // alias: [B][24*I] = 25.2M <= 33.5M
    // total ~227.6 MB (within R1's proven envelope)

    hipStream_t s = stream;
    const float rscale = 0.08838834764831845f;  // 1/sqrt(128)

    // ================= t2s (v_term) =================
    sg(s, 0, h_term, ts_in_w, ts_in_b, nullptr, QB,
       4096, 1024, 1024, 0, H_, 0, 0, H_, 0, 0, H_, 0, 0, 0, 1.f, 1);
    headdot_k<<<dim3(128), dim3(256), 0, s>>>(QB, ts_in_b + H_, OFFS);
    tT_k<<<dim3(H_ / 32, H_ / 32), dim3(256), 0, s>>>(ts_in_w + (long)H_ * H_, wT, H_, H_);
    sg(s, 0, QB, wT, nullptr, nullptr, BIG,
       4096, 1024, 128, 4, 16L * H_, H_, DH_, H_, 128, 0,
       128L * H_, 8L * H_, H_, 0, 1.f, 8);
    sg(s, 0, BIG, h_sent, nullptr, OFFS, SC,
       128, 256, 1024, 0, H_, 0, 128L * H_, H_, (long)S_ * H_, 0,
       S_, 0, 128L * S_, 128, rscale, B_);
    softmax_rows_k<<<dim3(B_ * M128_), dim3(64), 0, s>>>(SC);
    pbar_k<<<dim3(B_ * NH_ * S_ / 256), dim3(256), 0, s>>>(SC, PBAR);
    ctxw_k<<<dim3(B_), dim3(256), 0, s>>>(PBAR, h_sent, CTXB);
    sg(s, 0, CTXB, ts_in_w + 2L * H_ * H_, ts_in_b + 2 * H_, nullptr, OBAR,
       256, 128, 1024, 0, 8L * H_, 0, H_, H_, 128L * H_, 128,
       H_, 0, 128, 0, 1.f, 8);
    sg(s, 0, OBAR, ts_out_w, ts_out_b, nullptr, VTERM,
       256, 1024, 1024, 0, H_, 0, 0, H_, 0, 0, H_, 0, 0, 0, 1.f, 1);

    // ================= ca (v_op) =================
    sg(s, 0, h_term, opq_w, nullptr, nullptr, QB2,
       4096, 1024, 1024, 0, H_, 0, 0, H_, 0, 0, H_, 0, 0, 0, 1.f, 1);
    sg(s, 0, QB2, ca_in_w, ca_in_b, nullptr, QB,
       4096, 1024, 1024, 0, H_, 0, 0, H_, 0, 0, H_, 0, 0, 0, 1.f, 1);
    headdot_k<<<dim3(128), dim3(256), 0, s>>>(QB, ca_in_b + H_, OFFS);
    tT_k<<<dim3(H_ / 32, H_ / 32), dim3(256), 0, s>>>(ca_in_w + (long)H_ * H_, wT, H_, H_);
    sg(s, 0, QB, wT, nullptr, nullptr, BIG,
       4096, 1024, 128, 4, 16L * H_, H_, DH_, H_, 128, 0,
       128L * H_, 8L * H_, H_, 0, 1.f, 8);
    sg(s, 0, BIG, h_sent, nullptr, OFFS, SC,
       128, 256, 1024, 0, H_, 0, 128L * H_, H_, (long)S_ * H_, 0,
       S_, 0, 128L * S_, 128, rscale, B_);
    softmax_rows_k<<<dim3(B_ * M128_), dim3(64), 0, s>>>(SC);
    pbar_k<<<dim3(B_ * NH_ * S_ / 256), dim3(256), 0, s>>>(SC, PBAR);
    ctxw_k<<<dim3(B_), dim3(256), 0, s>>>(PBAR, h_sent, CTXB);
    sg(s, 0, CTXB, ca_in_w + 2L * H_ * H_, ca_in_b + 2 * H_, nullptr, OBAR,
       256, 128, 1024, 0, 8L * H_, 0, H_, H_, 128L * H_, 128,
       H_, 0, 128, 0, 1.f, 8);
    sg(s, 0, OBAR, ca_out_w, ca_out_b, nullptr, VOP,
       256, 1024, 1024, 0, H_, 0, 0, H_, 0, 0, H_, 0, 0, 0, 1.f, 1);

    // ================= s2t (v_sent) =================
    sg(s, 0, h_term, st_in_w + (long)H_ * H_, st_in_b + H_, nullptr, QB,
       4096, 1024, 1024, 0, H_, 0, 0, H_, 0, 0, H_, 0, 0, 0, 1.f, 1);
    sg(s, 0, h_term, st_in_w + 2L * H_ * H_, st_in_b + 2 * H_, nullptr, QB2,
       4096, 1024, 1024, 0, H_, 0, 0, H_, 0, 0, H_, 0, 0, 0, 1.f, 1);
    headdot_k<<<dim3(128), dim3(256), 0, s>>>(QB, st_in_b, OFFS);
    tT_k<<<dim3(H_ / 32, H_ / 32), dim3(256), 0, s>>>(st_in_w, wT, H_, H_);
    sg(s, 0, QB, wT, nullptr, nullptr, BIG,
       4096, 1024, 128, 4, 16L * H_, H_, DH_, H_, 128, 0,
       128L * H_, 8L * H_, H_, 0, 1.f, 8);
    sg(s, 0, BIG, h_sent, nullptr, OFFS, SC,
       128, 256, 1024, 0, H_, 0, 128L * H_, H_, (long)S_ * H_, 0,
       S_, 0, 128L * S_, 128, rscale, B_);
    softmax_t_k<<<dim3((B_ * NH_ * S_ + 255) / 256), dim3(256), 0, s>>>(SC);
    rowmean_k<<<dim3(B_ * M128_), dim3(64), 0, s>>>(SC, ATTM);
    ohead2_k<<<dim3((B_ * H_ + 255) / 256), dim3(256), 0, s>>>(ATTM, QB2, OBAR);
    sg(s, 0, OBAR, st_out_w, st_out_b, nullptr, VSENT,
       256, 1024, 1024, 0, H_, 0, 0, H_, 0, 0, H_, 0, 0, 0, 1.f, 1);

    // ================= fusion head =================
    cat3_k<<<dim3((B_ * 3 * H_ + 255) / 256), dim3(256), 0, s>>>(VSENT, VTERM, VOP, CAT3);
    ln_k<<<dim3(B_), dim3(256), 0, s>>>(CAT3, ln_g, ln_b, LNC);
    sg(s, 0, LNC, fuse_w, fuse_b, nullptr, FLIN,
       256, 1024, 3072, 0, 3L * H_, 0, 0, 3L * H_, 0, 0, H_, 0, 0, 0, 1.f, 1);
    sg(s, 2, CAT3, gate_w, gate_b, nullptr, GATE,
       256, 1024, 3072, 0, 3L * H_, 0, 0, 3L * H_, 0, 0, H_, 0, 0, 0, 1.f, 1);
    sg(s, 0, VSENT, bs_w, bs_b, nullptr, BSV,
       256, 256, 1024, 0, H_, 0, 0, H_, 0, 0, R_, 0, 0, 0, 1.f, 1);
    sg(s, 0, VTERM, bt_w, bt_b, nullptr, BTV,
       256, 256, 1024, 0, H_, 0, 0, H_, 0, 0, R_, 0, 0, 0, 1.f, 1);
    mulf_k<<<dim3((B_ * R_ + 255) / 256), dim3(256), 0, s>>>(BSV, BTV, PROD, B_ * R_);
    sg(s, 0, PROD, bo_w, bo_b, nullptr, BIL,
       256, 1024, 256, 0, R_, 0, 0, R_, 0, 0, H_, 0, 0, 0, 1.f, 1);
    fuse_k<<<dim3((B_ * H_ + 255) / 256), dim3(256), 0, s>>>(GATE, FLIN, BIL, FUSED);
    catfv_k<<<dim3((B_ * 2 * H_ + 255) / 256), dim3(256), 0, s>>>(FUSED, VTERM, CATFV);
    sg(s, 0, CATFV, cond_w, cond_b, nullptr, COND,
       256, 1024, 2048, 0, 2L * H_, 0, 0, 2L * H_, 0, 0, H_, 0, 0, 0, 1.f, 1);

    // ================= routing (small N: f32 VALU) =================
    g_launch(s, FUSED, gr_w, gr_b, GLOG, B_, G_, H_, H_, H_, G_);
    route_k<<<dim3(1), dim3(256), 0, s>>>(GLOG, GP);
    g_launch(s, COND, er_w, er_b, ELOG, B_, GE_, H_, H_, H_, GE_);
    epsm_k<<<dim3(3), dim3(256), 0, s>>>(ELOG);

    // ================= MoE (split-bf16, f32-grade) =================
    sg(s, 1, FUSED, e_w1, e_b1, nullptr, H1,
       256, 4096, 1024, 0, H_, 0, 0, H_, (long)I_ * H_, I_,
       (long)GE_ * I_, 0, I_, 0, 1.f, GE_);
    sg(s, 0, H1, e_w2, e_b2, nullptr, SC,
       256, 1024, 4096, 0, (long)GE_ * I_, 0, I_, I_, (long)H_ * I_, H_,
       (long)GE_ * H_, 0, H_, 0, 1.f, GE_);
    moe_k<<<dim3((B_ * H_ + 255) / 256), dim3(256), 0, s>>>(SC, GP, ELOG, FUSED, RES);

    // ================= classifier =================
    g_launch(s, RES, cls_w, cls_b, (float*)d_out, B_, L_, H_, H_, H_, L_);
}

// Round 5
// 2642.001 us; speedup vs baseline: 2.0535x; 1.0704x over previous
//
#include <hip/hip_runtime.h>
#include <math.h>

// ---------------------------------------------------------------------------
// HAGMoE — round 5.
// R2/R3 failure root-caused: top-2-of-3 routing flip from bf16 noise in the
// FUSED->glog path. Rule: pre-routing stays split-bf16 (f32-grade); post-
// routing (h1/moe weights) may be single-bf16.
// This round: (1) scores GEMM K-split x2 for 2x block parallelism (was 2
// blocks/CU, 2.3 TB/s); (2) MoE restructured: w=gp*ep folded into the h1
// epilogue (bf16), one K=98304 GEMM with K-chunk partials + reduce; e_w1/e_w2
// single-bf16 (post-routing safe), read exactly once.
// ws ~232 MB (R1-proven envelope). Partials alias dead QB/QB2; PART aliases
// SC..QB2; H1W aliases BIG; wT aliases CAT3/LNC.
// ---------------------------------------------------------------------------

#define B_    256
#define S_    256
#define T_    16
#define H_    1024
#define NH_   8
#define DH_   128
#define M128_ 128
#define G_    3
#define E_    8
#define I_    4096
#define R_    256
#define L_    3
#define GE_   24

using bf16x8 = __attribute__((ext_vector_type(8))) __bf16;
using f32x4  = __attribute__((ext_vector_type(4))) float;

// -------------------- wave helpers --------------------
__device__ inline float wave_sum(float v) {
    for (int o = 32; o > 0; o >>= 1) v += __shfl_xor(v, o);
    return v;
}
__device__ inline float wave_max(float v) {
    for (int o = 32; o > 0; o >>= 1) v = fmaxf(v, __shfl_xor(v, o));
    return v;
}

// ===================== split-bf16 (hi+lo) MFMA GEMM, 128x128 =====================
// C[r,n] = act( scale*(sum_k A[r,k]*Bt[n,k] + roff[r]) + bias[n] )
// KSPL=1: blockIdx.y = K-half index; A/B advance khalf*K; khalf1 writes to
// C + sKC with no roff. M must be 128 when KSPL=1.
template <int ACT, int KSPL>
__global__ __launch_bounds__(256) void sgemm_k(
    const float* __restrict__ Ap, const float* __restrict__ Bp,
    const float* __restrict__ biasp, const float* __restrict__ roffp,
    float* __restrict__ Cf,
    int K, int m2shift, int m2mask,
    long sA1, long sA2, long sAz,
    long ldb, long sBz, long sBias,
    long sC1, long sC2, long sCz, long sRoff, long sKC,
    float scale)
{
    const int z    = blockIdx.z;
    const int khalf = KSPL ? blockIdx.y : 0;
    const int row0 = KSPL ? 0 : blockIdx.y * 128;
    const int col0 = blockIdx.x * 128;
    const float* Ab = Ap + (long)z * sAz + (long)khalf * K;
    const float* Bb = Bp + (long)z * sBz + (long)khalf * K;
    const float* biasb = biasp ? biasp + (long)z * sBias : nullptr;
    const float* roffb = (roffp && khalf == 0) ? roffp + (long)z * sRoff : nullptr;

    __shared__ __bf16 Ahs[128 * 40];
    __shared__ __bf16 Als[128 * 40];
    __shared__ __bf16 Bhs[128 * 40];
    __shared__ __bf16 Bls[128 * 40];

    const int tid  = threadIdx.x;
    const int lane = tid & 63;
    const int wid  = tid >> 6;
    const int wm = (wid >> 1) * 64;
    const int wn = (wid & 1) * 64;
    const int fr  = lane & 15;
    const int fkb = (lane >> 4) * 16;
    const int qrow = tid >> 2;
    const int c4   = tid & 3;

    f32x4 acc[4][4] = {};

    for (int k0 = 0; k0 < K; k0 += 32) {
        __syncthreads();
#pragma unroll
        for (int rep = 0; rep < 2; ++rep) {
            const int row = qrow + rep * 64;
            {
                const int r = row0 + row;
                const int r1 = r >> m2shift, r2 = r & m2mask;
                const float* src = Ab + (long)r1 * sA1 + (long)r2 * sA2 + k0 + c4 * 8;
                float4 f0 = *(const float4*)src;
                float4 f1 = *(const float4*)(src + 4);
                const float fv[8] = {f0.x, f0.y, f0.z, f0.w, f1.x, f1.y, f1.z, f1.w};
                bf16x8 hi, lo;
#pragma unroll
                for (int j = 0; j < 8; ++j) {
                    const __bf16 h = (__bf16)fv[j];
                    hi[j] = h; lo[j] = (__bf16)(fv[j] - (float)h);
                }
                *(bf16x8*)&Ahs[row * 40 + c4 * 8] = hi;
                *(bf16x8*)&Als[row * 40 + c4 * 8] = lo;
            }
            {
                const float* src = Bb + (long)(col0 + row) * ldb + k0 + c4 * 8;
                float4 f0 = *(const float4*)src;
                float4 f1 = *(const float4*)(src + 4);
                const float fv[8] = {f0.x, f0.y, f0.z, f0.w, f1.x, f1.y, f1.z, f1.w};
                bf16x8 hi, lo;
#pragma unroll
                for (int j = 0; j < 8; ++j) {
                    const __bf16 h = (__bf16)fv[j];
                    hi[j] = h; lo[j] = (__bf16)(fv[j] - (float)h);
                }
                *(bf16x8*)&Bhs[row * 40 + c4 * 8] = hi;
                *(bf16x8*)&Bls[row * 40 + c4 * 8] = lo;
            }
        }
        __syncthreads();
        bf16x8 bh4[4], bl4[4];
#pragma unroll
        for (int n = 0; n < 4; ++n) {
            bh4[n] = *(const bf16x8*)((const char*)&Bhs[(wn + n * 16 + fr) * 40] + fkb);
            bl4[n] = *(const bf16x8*)((const char*)&Bls[(wn + n * 16 + fr) * 40] + fkb);
        }
#pragma unroll
        for (int m = 0; m < 4; ++m) {
            const bf16x8 ah = *(const bf16x8*)((const char*)&Ahs[(wm + m * 16 + fr) * 40] + fkb);
            const bf16x8 al = *(const bf16x8*)((const char*)&Als[(wm + m * 16 + fr) * 40] + fkb);
#pragma unroll
            for (int n = 0; n < 4; ++n) {
                acc[m][n] = __builtin_amdgcn_mfma_f32_16x16x32_bf16(ah, bh4[n], acc[m][n], 0, 0, 0);
                acc[m][n] = __builtin_amdgcn_mfma_f32_16x16x32_bf16(ah, bl4[n], acc[m][n], 0, 0, 0);
                acc[m][n] = __builtin_amdgcn_mfma_f32_16x16x32_bf16(al, bh4[n], acc[m][n], 0, 0, 0);
            }
        }
    }

    float* Cfb = Cf + (long)z * sCz + (long)khalf * sKC;
    const int lr4 = (lane >> 4) * 4;
#pragma unroll
    for (int m = 0; m < 4; ++m) {
#pragma unroll
        for (int r = 0; r < 4; ++r) {
            const int rr = row0 + wm + m * 16 + lr4 + r;
            const int r1 = rr >> m2shift, r2 = rr & m2mask;
            const float ro = roffb ? roffb[rr] : 0.f;
            const long cb = (long)r1 * sC1 + (long)r2 * sC2;
#pragma unroll
            for (int n = 0; n < 4; ++n) {
                const int cc = col0 + wn + n * 16 + fr;
                float v = (acc[m][n][r] + ro) * scale;
                if (biasp) v += biasb[cc];
                if (ACT == 1) v = 0.5f * v * (1.0f + erff(v * 0.70710678118654752f));
                else if (ACT == 2) v = 1.0f / (1.0f + expf(-v));
                Cfb[cb + cc] = v;
            }
        }
    }
}

static void sg(hipStream_t s, int act, int kspl,
               const float* A, const float* B, const float* bias, const float* roff,
               float* Cf, int M, int N, int K, int m2shift,
               long sA1, long sA2, long sAz, long ldb, long sBz, long sBias,
               long sC1, long sC2, long sCz, long sRoff, long sKC, float scale, int Z)
{
    dim3 g(N / 128, kspl ? 2 : M / 128, Z), b(256);
    const int m2mask = (1 << m2shift) - 1;
#define SARGS A, B, bias, roff, Cf, K, m2shift, m2mask, sA1, sA2, sAz, ldb, sBz, sBias, sC1, sC2, sCz, sRoff, sKC, scale
    if (kspl) {
        sgemm_k<0, 1><<<g, b, 0, s>>>(SARGS);
    } else {
        if (act == 1)      sgemm_k<1, 0><<<g, b, 0, s>>>(SARGS);
        else if (act == 2) sgemm_k<2, 0><<<g, b, 0, s>>>(SARGS);
        else               sgemm_k<0, 0><<<g, b, 0, s>>>(SARGS);
    }
#undef SARGS
}

// ===================== 256x128 MFMA GEMM (MoE) =====================
// ABF16: A is bf16 (no split). BSING: B single-rounded bf16 (post-routing ok).
// WMUL: epilogue v *= wmul[row*sWr + z]. OUTH: bf16 output else f32.
// B base = Bp + (z>>bzshift)*sBz + (z & ((1<<bzshift)-1))*sBz2.
template <int ABF16, int BSING, int ACT, int WMUL, int OUTH>
__global__ __launch_bounds__(512) void sgemm256_k(
    const void* __restrict__ Ap, const float* __restrict__ Bp,
    const float* __restrict__ biasp, const float* __restrict__ wmulp,
    float* __restrict__ Cf, __bf16* __restrict__ Ch,
    int K, long sA1, long sAz, long ldb, long sBz, long sBz2, int bzshift,
    long sBias, long sC1, long sCz, long sWr, float scale)
{
    const int z    = blockIdx.z;
    const int col0 = blockIdx.x * 128;
    const int z1 = z >> bzshift;
    const int z2 = z - (z1 << bzshift);
    const float* Bb = Bp + (long)z1 * sBz + (long)z2 * sBz2;
    const float* biasb = biasp ? biasp + (long)z1 * sBias : nullptr;

    __shared__ __bf16 Ah[256 * 40];
    __shared__ __bf16 Al[ABF16 ? 64 : 256 * 40];
    __shared__ __bf16 Bh[128 * 40];
    __shared__ __bf16 Bl[BSING ? 64 : 128 * 40];

    const int tid  = threadIdx.x;
    const int lane = tid & 63;
    const int wid  = tid >> 6;          // 0..7
    const int wm = (wid >> 1) * 64;     // 0..192
    const int wn = (wid & 1) * 64;      // 0,64
    const int fr  = lane & 15;
    const int fkb = (lane >> 4) * 16;

    f32x4 acc[4][4] = {};

    for (int k0 = 0; k0 < K; k0 += 32) {
        __syncthreads();
        // ---- stage A: 256 rows x 32 ----
#pragma unroll
        for (int rep = 0; rep < 2; ++rep) {
            const int idx = tid + rep * 512;
            const int row = idx >> 2;
            const int c4  = idx & 3;
            if (ABF16) {
                bf16x8 v = *(const bf16x8*)((const __bf16*)Ap + (long)z * sAz +
                                            (long)row * sA1 + k0 + c4 * 8);
                *(bf16x8*)&Ah[row * 40 + c4 * 8] = v;
            } else {
                const float* src = (const float*)Ap + (long)z * sAz +
                                   (long)row * sA1 + k0 + c4 * 8;
                float4 f0 = *(const float4*)src;
                float4 f1 = *(const float4*)(src + 4);
                const float fv[8] = {f0.x, f0.y, f0.z, f0.w, f1.x, f1.y, f1.z, f1.w};
                bf16x8 hi, lo;
#pragma unroll
                for (int j = 0; j < 8; ++j) {
                    const __bf16 h = (__bf16)fv[j];
                    hi[j] = h; lo[j] = (__bf16)(fv[j] - (float)h);
                }
                *(bf16x8*)&Ah[row * 40 + c4 * 8] = hi;
                *(bf16x8*)&Al[row * 40 + c4 * 8] = lo;
            }
        }
        // ---- stage B: 128 rows x 32 ----
        {
            const int row = tid >> 2;
            const int c4  = tid & 3;
            const float* src = Bb + (long)(col0 + row) * ldb + k0 + c4 * 8;
            float4 f0 = *(const float4*)src;
            float4 f1 = *(const float4*)(src + 4);
            const float fv[8] = {f0.x, f0.y, f0.z, f0.w, f1.x, f1.y, f1.z, f1.w};
            bf16x8 hi, lo;
#pragma unroll
            for (int j = 0; j < 8; ++j) {
                const __bf16 h = (__bf16)fv[j];
                hi[j] = h;
                if (!BSING) lo[j] = (__bf16)(fv[j] - (float)h);
            }
            *(bf16x8*)&Bh[row * 40 + c4 * 8] = hi;
            if (!BSING) *(bf16x8*)&Bl[row * 40 + c4 * 8] = lo;
        }
        __syncthreads();
        bf16x8 bh4[4], bl4[4];
#pragma unroll
        for (int n = 0; n < 4; ++n) {
            bh4[n] = *(const bf16x8*)((const char*)&Bh[(wn + n * 16 + fr) * 40] + fkb);
            if (!BSING) bl4[n] = *(const bf16x8*)((const char*)&Bl[(wn + n * 16 + fr) * 40] + fkb);
        }
#pragma unroll
        for (int m = 0; m < 4; ++m) {
            const bf16x8 ah = *(const bf16x8*)((const char*)&Ah[(wm + m * 16 + fr) * 40] + fkb);
            bf16x8 al;
            if (!ABF16) al = *(const bf16x8*)((const char*)&Al[(wm + m * 16 + fr) * 40] + fkb);
#pragma unroll
            for (int n = 0; n < 4; ++n) {
                acc[m][n] = __builtin_amdgcn_mfma_f32_16x16x32_bf16(ah, bh4[n], acc[m][n], 0, 0, 0);
                if (!BSING) acc[m][n] = __builtin_amdgcn_mfma_f32_16x16x32_bf16(ah, bl4[n], acc[m][n], 0, 0, 0);
                if (!ABF16) acc[m][n] = __builtin_amdgcn_mfma_f32_16x16x32_bf16(al, bh4[n], acc[m][n], 0, 0, 0);
            }
        }
    }

    const int lr4 = (lane >> 4) * 4;
#pragma unroll
    for (int m = 0; m < 4; ++m) {
#pragma unroll
        for (int r = 0; r < 4; ++r) {
            const int rr = wm + m * 16 + lr4 + r;
#pragma unroll
            for (int n = 0; n < 4; ++n) {
                const int cc = col0 + wn + n * 16 + fr;
                float v = acc[m][n][r] * scale;
                if (biasp) v += biasb[cc];
                if (ACT == 1) v = 0.5f * v * (1.0f + erff(v * 0.70710678118654752f));
                if (WMUL) v *= wmulp[(long)rr * sWr + z];
                if (OUTH) Ch[(long)z * sCz + (long)rr * sC1 + cc] = (__bf16)v;
                else      Cf[(long)z * sCz + (long)rr * sC1 + cc] = v;
            }
        }
    }
}

// ===================== f32 VALU GEMM (small N only) =====================
#define BM 64
#define BN 64
#define BK 16
__global__ __launch_bounds__(256) void gemm_k(
    const float* __restrict__ Ap, const float* __restrict__ Bp,
    const float* __restrict__ biasp, float* __restrict__ Cp,
    int M, int N, int K, long sA1, long ldb, long sC1)
{
    const int row0 = blockIdx.y * BM;
    const int col0 = blockIdx.x * BN;
    const int tid = threadIdx.x;
    __shared__ float As[BK][BM + 4];
    __shared__ float Bs[BK][BN + 4];
    float acc[4][4] = {};
    const int tm = (tid >> 4) << 2;
    const int tn = (tid & 15) << 2;
    for (int k0 = 0; k0 < K; k0 += BK) {
        {
            const int i = tid << 2;
            const int m = i >> 4, kk = i & 15;
            const int r = row0 + m;
            float4 v = make_float4(0.f, 0.f, 0.f, 0.f);
            if (r < M) v = *(const float4*)(Ap + (long)r * sA1 + k0 + kk);
            As[kk + 0][m] = v.x; As[kk + 1][m] = v.y;
            As[kk + 2][m] = v.z; As[kk + 3][m] = v.w;
        }
        {
            const int i = tid << 2;
            const int n = i >> 4, kk = i & 15;
            const int c = col0 + n;
            float4 v = make_float4(0.f, 0.f, 0.f, 0.f);
            if (c < N) v = *(const float4*)(Bp + (long)c * ldb + k0 + kk);
            Bs[kk + 0][n] = v.x; Bs[kk + 1][n] = v.y;
            Bs[kk + 2][n] = v.z; Bs[kk + 3][n] = v.w;
        }
        __syncthreads();
#pragma unroll
        for (int kk = 0; kk < BK; ++kk) {
            const float4 av = *(const float4*)&As[kk][tm];
            const float4 bv = *(const float4*)&Bs[kk][tn];
            acc[0][0] += av.x * bv.x; acc[0][1] += av.x * bv.y;
            acc[0][2] += av.x * bv.z; acc[0][3] += av.x * bv.w;
            acc[1][0] += av.y * bv.x; acc[1][1] += av.y * bv.y;
            acc[1][2] += av.y * bv.z; acc[1][3] += av.y * bv.w;
            acc[2][0] += av.z * bv.x; acc[2][1] += av.z * bv.y;
            acc[2][2] += av.z * bv.z; acc[2][3] += av.z * bv.w;
            acc[3][0] += av.w * bv.x; acc[3][1] += av.w * bv.y;
            acc[3][2] += av.w * bv.z; acc[3][3] += av.w * bv.w;
        }
        __syncthreads();
    }
#pragma unroll
    for (int i2 = 0; i2 < 4; ++i2) {
        const int r = row0 + tm + i2;
        if (r >= M) continue;
        float* crow = Cp + (long)r * sC1;
#pragma unroll
        for (int j = 0; j < 4; ++j) {
            const int c = col0 + tn + j;
            if (c >= N) continue;
            float v = acc[i2][j];
            if (biasp) v += biasp[c];
            crow[c] = v;
        }
    }
}

static void g_launch(hipStream_t s, const float* A, const float* Bw, const float* bias,
                     float* C, int M, int N, int K, long sA1, long ldb, long sC1)
{
    dim3 grid((N + BN - 1) / BN, (M + BM - 1) / BM, 1);
    gemm_k<<<grid, dim3(256), 0, s>>>(A, Bw, bias, C, M, N, K, sA1, ldb, sC1);
}

// ===================== transpose (f32 -> f32) =====================
__global__ void tT_k(const float* __restrict__ src, float* __restrict__ dst, int R, int C)
{
    __shared__ float t[32][33];
    const int c0 = blockIdx.x * 32, r0 = blockIdx.y * 32;
    const int tx = threadIdx.x & 31, ty = threadIdx.x >> 5;
#pragma unroll
    for (int i = 0; i < 4; ++i) {
        const int r = ty + i * 8;
        t[r][tx] = src[(long)(r0 + r) * C + c0 + tx];
    }
    __syncthreads();
#pragma unroll
    for (int i = 0; i < 4; ++i) {
        const int r = ty + i * 8;
        dst[(long)(c0 + r) * R + r0 + tx] = t[tx][r];
    }
}

// ===================== glue kernels =====================
__global__ void headdot_k(const float* __restrict__ Q, const float* __restrict__ bvec,
                          float* __restrict__ out)
{
    const int idx = blockIdx.x * blockDim.x + threadIdx.x;
    if (idx >= B_ * T_ * NH_) return;
    const int h = idx % NH_;
    const int t = (idx / NH_) % T_;
    const int b = idx / (NH_ * T_);
    const float* q = Q + ((long)(b * T_ + t)) * H_ + h * DH_;
    const float* bb = bvec + h * DH_;
    float sum = 0.f;
    for (int k = 0; k < DH_; ++k) sum += q[k] * bb[k];
    out[idx] = sum;
}

// softmax over rows of length S, input = p0 + p1 (K-split partials)
__global__ void softmax_rows_k(float* __restrict__ x, const float* __restrict__ x2)
{
    const long row = blockIdx.x;
    float* p = x + row * S_;
    const float* q = x2 + row * S_;
    const int t = threadIdx.x;
    float v0 = p[t] + q[t], v1 = p[t + 64] + q[t + 64];
    float v2 = p[t + 128] + q[t + 128], v3 = p[t + 192] + q[t + 192];
    float m = wave_max(fmaxf(fmaxf(v0, v1), fmaxf(v2, v3)));
    v0 = expf(v0 - m); v1 = expf(v1 - m); v2 = expf(v2 - m); v3 = expf(v3 - m);
    const float inv = 1.f / wave_sum(v0 + v1 + v2 + v3);
    p[t] = v0 * inv; p[t + 64] = v1 * inv; p[t + 128] = v2 * inv; p[t + 192] = v3 * inv;
}

__global__ void softmax_t_k(float* __restrict__ sc, const float* __restrict__ sc2)
{
    const int idx = blockIdx.x * blockDim.x + threadIdx.x;
    if (idx >= B_ * NH_ * S_) return;
    const int s = idx % S_;
    const int h = (idx / S_) % NH_;
    const int b = idx / (S_ * NH_);
    const long boff = (long)b * M128_ * S_ + (long)h * S_ + s;
    float* base = sc + boff;
    const float* base2 = sc2 + boff;
    float v[T_];
    float mx = -1e30f;
#pragma unroll
    for (int t = 0; t < T_; ++t) {
        v[t] = base[(long)t * NH_ * S_] + base2[(long)t * NH_ * S_];
        mx = fmaxf(mx, v[t]);
    }
    float sum = 0.f;
#pragma unroll
    for (int t = 0; t < T_; ++t) { v[t] = expf(v[t] - mx); sum += v[t]; }
    const float inv = 1.f / sum;
#pragma unroll
    for (int t = 0; t < T_; ++t) base[(long)t * NH_ * S_] = v[t] * inv;
}

__global__ void rowmean_k(const float* __restrict__ x, float* __restrict__ out)
{
    const int row = blockIdx.x;
    const float* p = x + (long)row * S_;
    float sv = 0.f;
    for (int i = threadIdx.x; i < S_; i += 64) sv += p[i];
    sv = wave_sum(sv);
    if (threadIdx.x == 0) out[row] = sv * (1.0f / S_);
}

__global__ void pbar_k(const float* __restrict__ sc, float* __restrict__ pb)
{
    const int idx = blockIdx.x * blockDim.x + threadIdx.x;
    if (idx >= B_ * NH_ * S_) return;
    const int s = idx & 255;
    const int h = (idx >> 8) & 7;
    const int b = idx >> 11;
    const float* base = sc + (long)b * M128_ * S_ + (long)h * S_ + s;
    float sum = 0.f;
#pragma unroll
    for (int t = 0; t < T_; ++t) sum += base[(long)t * NH_ * S_];
    pb[idx] = sum * (1.0f / T_);
}

// ctxbar[b][h][k] = sum_s pbar[b][h][s] * h_sent[b][s][k]   (pure f32)
__global__ __launch_bounds__(256) void ctxw_k(const float* __restrict__ pbar,
                                              const float* __restrict__ hs,
                                              float* __restrict__ out)
{
    const int b = blockIdx.x;
    __shared__ float pl[NH_][S_];
    const int tid = threadIdx.x;
    for (int i = tid; i < NH_ * S_; i += 256) pl[i >> 8][i & 255] = pbar[(long)b * NH_ * S_ + i];
    __syncthreads();
    const int k0 = tid * 4;
    float4 acc[NH_] = {};
    const float* hb = hs + (long)b * S_ * H_;
    for (int s = 0; s < S_; ++s) {
        const float4 v = *(const float4*)(hb + (long)s * H_ + k0);
#pragma unroll
        for (int h = 0; h < NH_; ++h) {
            const float p = pl[h][s];
            acc[h].x += p * v.x; acc[h].y += p * v.y;
            acc[h].z += p * v.z; acc[h].w += p * v.w;
        }
    }
    float* ob = out + (long)b * NH_ * H_;
#pragma unroll
    for (int h = 0; h < NH_; ++h) *(float4*)(ob + h * H_ + k0) = acc[h];
}

__global__ void ohead2_k(const float* __restrict__ attm, const float* __restrict__ V,
                         float* __restrict__ outb)
{
    const int idx = blockIdx.x * blockDim.x + threadIdx.x;
    if (idx >= B_ * H_) return;
    const int c = idx & (H_ - 1);
    const int b = idx >> 10;
    const int h = c >> 7;
    float sv = 0.f;
#pragma unroll
    for (int t = 0; t < T_; ++t)
        sv += attm[b * M128_ + t * NH_ + h] * V[((long)(b * T_ + t)) * H_ + c];
    outb[idx] = sv;
}

__global__ void cat3_k(const float* __restrict__ vs, const float* __restrict__ vt,
                       const float* __restrict__ vo, float* __restrict__ out)
{
    const int idx = blockIdx.x * blockDim.x + threadIdx.x;
    if (idx >= B_ * 3 * H_) return;
    const int k = idx % (3 * H_);
    const int b = idx / (3 * H_);
    float v;
    if (k < H_)          v = vs[b * H_ + k];
    else if (k < 2 * H_) v = vt[b * H_ + k - H_];
    else                 v = vo[b * H_ + k - 2 * H_];
    out[idx] = v;
}

__global__ void ln_k(const float* __restrict__ cat3, const float* __restrict__ g,
                     const float* __restrict__ bta, float* __restrict__ out)
{
    const int b = blockIdx.x;
    const int tid = threadIdx.x;
    __shared__ float buf[3 * H_];
    __shared__ float red[4];
    const float* src = cat3 + (long)b * 3 * H_;
    float sv = 0.f;
    for (int i = tid; i < 3 * H_; i += 256) { const float x = src[i]; buf[i] = x; sv += x; }
    sv = wave_sum(sv);
    if ((tid & 63) == 0) red[tid >> 6] = sv;
    __syncthreads();
    const float mu = (red[0] + red[1] + red[2] + red[3]) * (1.f / (3 * H_));
    __syncthreads();
    float s2 = 0.f;
    for (int i = tid; i < 3 * H_; i += 256) { const float d0 = buf[i] - mu; s2 += d0 * d0; }
    s2 = wave_sum(s2);
    if ((tid & 63) == 0) red[tid >> 6] = s2;
    __syncthreads();
    const float var = (red[0] + red[1] + red[2] + red[3]) * (1.f / (3 * H_));
    const float rstd = rsqrtf(var + 1e-5f);
    float* dst = out + (long)b * 3 * H_;
    for (int i = tid; i < 3 * H_; i += 256)
        dst[i] = (buf[i] - mu) * rstd * g[i] + bta[i];
}

__global__ void mulf_k(const float* __restrict__ a, const float* __restrict__ b2,
                       float* __restrict__ out, int n)
{
    const int idx = blockIdx.x * blockDim.x + threadIdx.x;
    if (idx < n) out[idx] = a[idx] * b2[idx];
}

__global__ void fuse_k(const float* __restrict__ g, const float* __restrict__ flin,
                       const float* __restrict__ bil, float* __restrict__ fused)
{
    const int idx = blockIdx.x * blockDim.x + threadIdx.x;
    if (idx >= B_ * H_) return;
    const float gg = g[idx];
    fused[idx] = gg * flin[idx] + (1.f - gg) * bil[idx];
}

__global__ void catfv_k(const float* __restrict__ fused, const float* __restrict__ vt,
                        float* __restrict__ out)
{
    const int idx = blockIdx.x * blockDim.x + threadIdx.x;
    if (idx >= B_ * 2 * H_) return;
    const int k = idx % (2 * H_);
    const int b = idx / (2 * H_);
    out[idx] = (k < H_) ? fused[b * H_ + k] : vt[b * H_ + k - H_];
}

__global__ void route_k(const float* __restrict__ glog, float* __restrict__ gp)
{
    const int b = blockIdx.x * blockDim.x + threadIdx.x;
    if (b >= B_) return;
    const float x0 = glog[b * 3], x1 = glog[b * 3 + 1], x2 = glog[b * 3 + 2];
    const float m1 = fmaxf(x0, fmaxf(x1, x2));
    float thr;
    if (x0 == m1)      thr = fmaxf(x1, x2);
    else if (x1 == m1) thr = fmaxf(x0, x2);
    else               thr = fmaxf(x0, x1);
    const float y0 = (x0 >= thr) ? x0 : -1e9f;
    const float y1 = (x1 >= thr) ? x1 : -1e9f;
    const float y2 = (x2 >= thr) ? x2 : -1e9f;
    const float mm = fmaxf(y0, fmaxf(y1, y2));
    const float e0 = expf(y0 - mm), e1 = expf(y1 - mm), e2 = expf(y2 - mm);
    const float inv = 1.f / (e0 + e1 + e2);
    gp[b * 3] = e0 * inv; gp[b * 3 + 1] = e1 * inv; gp[b * 3 + 2] = e2 * inv;
}

// ep softmax, then fold wsc[b,ge] = gp[b,g] * ep[b,ge]  (in place)
__global__ void epsm_k(float* __restrict__ elog, const float* __restrict__ gp)
{
    const int idx = blockIdx.x * blockDim.x + threadIdx.x;
    if (idx >= B_ * G_) return;
    const int b = idx / G_;
    float* p = elog + (long)idx * E_;
    float m = p[0];
#pragma unroll
    for (int e = 1; e < E_; ++e) m = fmaxf(m, p[e]);
    float sum = 0.f;
    float v[E_];
#pragma unroll
    for (int e = 0; e < E_; ++e) { v[e] = expf(p[e] - m); sum += v[e]; }
    const float inv = gp[idx - b * G_ + b * G_] * 0.f + gp[idx] * 0.f + (1.f / sum); // keep simple below
#pragma unroll
    for (int e = 0; e < E_; ++e) p[e] = v[e] * (1.f / sum) * gp[idx];
}

// RES[b,h] = FUSED + sum_z PART[z] + sum_ge wsc*e_b2
__global__ void moefinal_k(const float* __restrict__ part, const float* __restrict__ fused,
                           const float* __restrict__ wsc, const float* __restrict__ e_b2,
                           float* __restrict__ res)
{
    const int idx = blockIdx.x * blockDim.x + threadIdx.x;
    if (idx >= B_ * H_) return;
    const int b = idx >> 10;
    const int h = idx & (H_ - 1);
    float acc = fused[idx];
#pragma unroll 8
    for (int z = 0; z < 48; ++z) acc += part[(long)z * (B_ * H_) + idx];
    float ba = 0.f;
#pragma unroll
    for (int ge = 0; ge < GE_; ++ge) ba += wsc[b * GE_ + ge] * e_b2[ge * H_ + h];
    res[idx] = acc + ba;
}

// ===================== entry =====================
extern "C" void kernel_launch(void* const* d_in, const int* in_sizes, int n_in,
                              void* d_out, int out_size, void* d_ws, size_t ws_size,
                              hipStream_t stream)
{
    const float* h_sent  = (const float*)d_in[0];
    const float* h_term  = (const float*)d_in[1];
    const float* ts_in_w = (const float*)d_in[2];
    const float* ts_out_w= (const float*)d_in[3];
    const float* st_in_w = (const float*)d_in[4];
    const float* st_out_w= (const float*)d_in[5];
    const float* ca_in_w = (const float*)d_in[6];
    const float* ca_out_w= (const float*)d_in[7];
    const float* opq_w   = (const float*)d_in[8];
    const float* fuse_w  = (const float*)d_in[9];
    const float* gate_w  = (const float*)d_in[10];
    const float* bs_w    = (const float*)d_in[11];
    const float* bt_w    = (const float*)d_in[12];
    const float* bo_w    = (const float*)d_in[13];
    const float* cond_w  = (const float*)d_in[14];
    const float* gr_w    = (const float*)d_in[15];
    const float* er_w    = (const float*)d_in[16];
    const float* e_w1    = (const float*)d_in[17];
    const float* e_w2    = (const float*)d_in[18];
    const float* cls_w   = (const float*)d_in[19];
    const float* ts_in_b = (const float*)d_in[20];
    const float* ts_out_b= (const float*)d_in[21];
    const float* st_in_b = (const float*)d_in[22];
    const float* st_out_b= (const float*)d_in[23];
    const float* ca_in_b = (const float*)d_in[24];
    const float* ca_out_b= (const float*)d_in[25];
    const float* fuse_b  = (const float*)d_in[26];
    const float* gate_b  = (const float*)d_in[27];
    const float* bs_b    = (const float*)d_in[28];
    const float* bt_b    = (const float*)d_in[29];
    const float* bo_b    = (const float*)d_in[30];
    const float* cond_b  = (const float*)d_in[31];
    const float* gr_b    = (const float*)d_in[32];
    const float* er_b    = (const float*)d_in[33];
    const float* e_b1    = (const float*)d_in[34];
    const float* e_b2    = (const float*)d_in[35];
    const float* cls_b   = (const float*)d_in[36];
    const float* ln_b    = (const float*)d_in[37];
    const float* ln_g    = (const float*)d_in[38];
    (void)in_sizes; (void)n_in; (void)out_size; (void)ws_size;

    float* ws = (float*)d_ws;
    size_t off = 0;
    auto allocF = [&](size_t n) { float* p = ws + off; off += (n + 63) & ~(size_t)63; return p; };

    // ---- layout (order matters for aliases) ----
    float* SC    = allocF(8388608);   // scores khalf0 [B][128][S]
    float* QB    = allocF(4194304);   // [B*T,H]; also scores khalf1 partial (w/ QB2)
    float* QB2   = allocF(4194304);
    float* OFFS  = allocF(32768);
    float* ATTM  = allocF(32768);
    float* PBAR  = allocF(524288);
    float* CTXB  = allocF(2097152);
    float* OBAR  = allocF(262144);
    float* VTERM = allocF(262144);
    float* VSENT = allocF(262144);
    float* VOP   = allocF(262144);
    float* CAT3  = allocF(786432);    // also wT alias (spans CAT3+LNC)
    float* LNC   = allocF(786432);
    float* FLIN  = allocF(262144);
    float* GATE  = allocF(262144);
    float* BSV   = allocF(65536);
    float* BTV   = allocF(65536);
    float* PROD  = allocF(65536);
    float* BIL   = allocF(262144);
    float* FUSED = allocF(262144);
    float* CATFV = allocF(524288);
    float* COND  = allocF(262144);
    float* GLOG  = allocF(1024);
    float* GP    = allocF(1024);
    float* ELOG  = allocF(8192);      // becomes wsc = gp*ep
    float* RES   = allocF(262144);
    float* BIG   = allocF(33554432);  // A-fold [B][128][H] f32; H1W bf16 alias
    // aliases
    float*  SCB  = QB;                        // scores khalf1 partial (spans QB..QB2)
    float*  wT   = CAT3;                      // transposed weight (1.05M <= 1.57M)
    float*  PART = SC;                        // MoE partials [48][B][H] (12.6M <= 16.8M)
    __bf16* H1W  = (__bf16*)BIG;              // [B][24*I] bf16 (12.6M f32-equiv)
    const long sKC = (long)(QB - SC);         // = 8388608
    // total ~231.7 MB

    hipStream_t s = stream;
    const float rscale = 0.08838834764831845f;  // 1/sqrt(128)

    // ================= t2s (v_term) =================
    sg(s, 0, 0, h_term, ts_in_w, ts_in_b, nullptr, QB,
       4096, 1024, 1024, 0, H_, 0, 0, H_, 0, 0, H_, 0, 0, 0, 0, 1.f, 1);
    headdot_k<<<dim3(128), dim3(256), 0, s>>>(QB, ts_in_b + H_, OFFS);
    tT_k<<<dim3(H_ / 32, H_ / 32), dim3(256), 0, s>>>(ts_in_w + (long)H_ * H_, wT, H_, H_);
    sg(s, 0, 0, QB, wT, nullptr, nullptr, BIG,
       4096, 1024, 128, 4, 16L * H_, H_, DH_, H_, 128, 0,
       128L * H_, 8L * H_, H_, 0, 0, 1.f, 8);
    sg(s, 0, 1, BIG, h_sent, nullptr, OFFS, SC,
       128, 256, 512, 0, H_, 0, 128L * H_, H_, (long)S_ * H_, 0,
       S_, 0, 128L * S_, 128, sKC, rscale, B_);
    softmax_rows_k<<<dim3(B_ * M128_), dim3(64), 0, s>>>(SC, SCB);
    pbar_k<<<dim3(B_ * NH_ * S_ / 256), dim3(256), 0, s>>>(SC, PBAR);
    ctxw_k<<<dim3(B_), dim3(256), 0, s>>>(PBAR, h_sent, CTXB);
    sg(s, 0, 0, CTXB, ts_in_w + 2L * H_ * H_, ts_in_b + 2 * H_, nullptr, OBAR,
       256, 128, 1024, 0, 8L * H_, 0, H_, H_, 128L * H_, 128,
       H_, 0, 128, 0, 0, 1.f, 8);
    sg(s, 0, 0, OBAR, ts_out_w, ts_out_b, nullptr, VTERM,
       256, 1024, 1024, 0, H_, 0, 0, H_, 0, 0, H_, 0, 0, 0, 0, 1.f, 1);

    // ================= ca (v_op) =================
    sg(s, 0, 0, h_term, opq_w, nullptr, nullptr, QB2,
       4096, 1024, 1024, 0, H_, 0, 0, H_, 0, 0, H_, 0, 0, 0, 0, 1.f, 1);
    sg(s, 0, 0, QB2, ca_in_w, ca_in_b, nullptr, QB,
       4096, 1024, 1024, 0, H_, 0, 0, H_, 0, 0, H_, 0, 0, 0, 0, 1.f, 1);
    headdot_k<<<dim3(128), dim3(256), 0, s>>>(QB, ca_in_b + H_, OFFS);
    tT_k<<<dim3(H_ / 32, H_ / 32), dim3(256), 0, s>>>(ca_in_w + (long)H_ * H_, wT, H_, H_);
    sg(s, 0, 0, QB, wT, nullptr, nullptr, BIG,
       4096, 1024, 128, 4, 16L * H_, H_, DH_, H_, 128, 0,
       128L * H_, 8L * H_, H_, 0, 0, 1.f, 8);
    sg(s, 0, 1, BIG, h_sent, nullptr, OFFS, SC,
       128, 256, 512, 0, H_, 0, 128L * H_, H_, (long)S_ * H_, 0,
       S_, 0, 128L * S_, 128, sKC, rscale, B_);
    softmax_rows_k<<<dim3(B_ * M128_), dim3(64), 0, s>>>(SC, SCB);
    pbar_k<<<dim3(B_ * NH_ * S_ / 256), dim3(256), 0, s>>>(SC, PBAR);
    ctxw_k<<<dim3(B_), dim3(256), 0, s>>>(PBAR, h_sent, CTXB);
    sg(s, 0, 0, CTXB, ca_in_w + 2L * H_ * H_, ca_in_b + 2 * H_, nullptr, OBAR,
       256, 128, 1024, 0, 8L * H_, 0, H_, H_, 128L * H_, 128,
       H_, 0, 128, 0, 0, 1.f, 8);
    sg(s, 0, 0, OBAR, ca_out_w, ca_out_b, nullptr, VOP,
       256, 1024, 1024, 0, H_, 0, 0, H_, 0, 0, H_, 0, 0, 0, 0, 1.f, 1);

    // ================= s2t (v_sent) =================
    sg(s, 0, 0, h_term, st_in_w + (long)H_ * H_, st_in_b + H_, nullptr, QB,
       4096, 1024, 1024, 0, H_, 0, 0, H_, 0, 0, H_, 0, 0, 0, 0, 1.f, 1);
    headdot_k<<<dim3(128), dim3(256), 0, s>>>(QB, st_in_b, OFFS);
    tT_k<<<dim3(H_ / 32, H_ / 32), dim3(256), 0, s>>>(st_in_w, wT, H_, H_);
    sg(s, 0, 0, QB, wT, nullptr, nullptr, BIG,
       4096, 1024, 128, 4, 16L * H_, H_, DH_, H_, 128, 0,
       128L * H_, 8L * H_, H_, 0, 0, 1.f, 8);
    sg(s, 0, 1, BIG, h_sent, nullptr, OFFS, SC,
       128, 256, 512, 0, H_, 0, 128L * H_, H_, (long)S_ * H_, 0,
       S_, 0, 128L * S_, 128, sKC, rscale, B_);
    softmax_t_k<<<dim3((B_ * NH_ * S_ + 255) / 256), dim3(256), 0, s>>>(SC, SCB);
    // V projection AFTER scores/softmax (QB2 was the khalf1 partial region)
    sg(s, 0, 0, h_term, st_in_w + 2L * H_ * H_, st_in_b + 2 * H_, nullptr, QB2,
       4096, 1024, 1024, 0, H_, 0, 0, H_, 0, 0, H_, 0, 0, 0, 0, 1.f, 1);
    rowmean_k<<<dim3(B_ * M128_), dim3(64), 0, s>>>(SC, ATTM);
    ohead2_k<<<dim3((B_ * H_ + 255) / 256), dim3(256), 0, s>>>(ATTM, QB2, OBAR);
    sg(s, 0, 0, OBAR, st_out_w, st_out_b, nullptr, VSENT,
       256, 1024, 1024, 0, H_, 0, 0, H_, 0, 0, H_, 0, 0, 0, 0, 1.f, 1);

    // ================= fusion head =================
    cat3_k<<<dim3((B_ * 3 * H_ + 255) / 256), dim3(256), 0, s>>>(VSENT, VTERM, VOP, CAT3);
    ln_k<<<dim3(B_), dim3(256), 0, s>>>(CAT3, ln_g, ln_b, LNC);
    sg(s, 0, 0, LNC, fuse_w, fuse_b, nullptr, FLIN,
       256, 1024, 3072, 0, 3L * H_, 0, 0, 3L * H_, 0, 0, H_, 0, 0, 0, 0, 1.f, 1);
    sg(s, 2, 0, CAT3, gate_w, gate_b, nullptr, GATE,
       256, 1024, 3072, 0, 3L * H_, 0, 0, 3L * H_, 0, 0, H_, 0, 0, 0, 0, 1.f, 1);
    sg(s, 0, 0, VSENT, bs_w, bs_b, nullptr, BSV,
       256, 256, 1024, 0, H_, 0, 0, H_, 0, 0, R_, 0, 0, 0, 0, 1.f, 1);
    sg(s, 0, 0, VTERM, bt_w, bt_b, nullptr, BTV,
       256, 256, 1024, 0, H_, 0, 0, H_, 0, 0, R_, 0, 0, 0, 0, 1.f, 1);
    mulf_k<<<dim3((B_ * R_ + 255) / 256), dim3(256), 0, s>>>(BSV, BTV, PROD, B_ * R_);
    sg(s, 0, 0, PROD, bo_w, bo_b, nullptr, BIL,
       256, 1024, 256, 0, R_, 0, 0, R_, 0, 0, H_, 0, 0, 0, 0, 1.f, 1);
    fuse_k<<<dim3((B_ * H_ + 255) / 256), dim3(256), 0, s>>>(GATE, FLIN, BIL, FUSED);
    catfv_k<<<dim3((B_ * 2 * H_ + 255) / 256), dim3(256), 0, s>>>(FUSED, VTERM, CATFV);
    sg(s, 0, 0, CATFV, cond_w, cond_b, nullptr, COND,
       256, 1024, 2048, 0, 2L * H_, 0, 0, 2L * H_, 0, 0, H_, 0, 0, 0, 0, 1.f, 1);

    // ================= routing (f32 VALU; feeds discontinuous top-k) =========
    g_launch(s, FUSED, gr_w, gr_b, GLOG, B_, G_, H_, H_, H_, G_);
    route_k<<<dim3(1), dim3(256), 0, s>>>(GLOG, GP);
    g_launch(s, COND, er_w, er_b, ELOG, B_, GE_, H_, H_, H_, GE_);
    epsm_k<<<dim3(3), dim3(256), 0, s>>>(ELOG, GP);   // ELOG := wsc = gp*ep

    // ================= MoE (post-routing: bf16 weights OK) =================
    // h1w[b][ge][i] = gelu(FUSED@e_w1[ge]^T + e_b1[ge]) * wsc[b,ge]  (bf16)
    sgemm256_k<0, 1, 1, 1, 1><<<dim3(I_ / 128, 1, GE_), dim3(512), 0, s>>>(
        FUSED, e_w1, e_b1, ELOG, nullptr, H1W,
        1024, H_, 0, H_, (long)I_ * H_, 0, 0, I_,
        (long)GE_ * I_, I_, GE_, 1.f);
    // PART[zc][b][h] = h1w[b][zc*2048 .. ] @ e_w2 chunk   (zc = ge*2 + khalf)
    sgemm256_k<1, 1, 0, 0, 0><<<dim3(H_ / 128, 1, 2 * GE_), dim3(512), 0, s>>>(
        H1W, e_w2, nullptr, nullptr, PART, nullptr,
        2048, (long)GE_ * I_, 2048, I_, (long)H_ * I_, 2048, 1, 0,
        H_, (long)B_ * H_, 0, 1.f);
    moefinal_k<<<dim3(B_ * H_ / 256), dim3(256), 0, s>>>(PART, FUSED, ELOG, e_b2, RES);

    // ================= classifier =================
    g_launch(s, RES, cls_w, cls_b, (float*)d_out, B_, L_, H_, H_, H_, L_);
}

// Round 6
// 2201.761 us; speedup vs baseline: 2.4641x; 1.1999x over previous
//
#include <hip/hip_runtime.h>
#include <math.h>

// ---------------------------------------------------------------------------
// HAGMoE — round 6: module-batched MFMA pipeline (ws is ~1.6 GB, use it).
//  * ONE 4096x4096x1024 projection GEMM (QALL) for {Q_ts, Q_ca(=opq fold), K_st, V_st}
//  * A-fold batched z=24 (3 modules x 8 heads) -> BIG3 [3][B][128][H]
//  * scores batched z=768 -> SC3 [3][B][128][S]  (1536 blocks, no K-split)
//  * softmax/pbar/ctxw/ctx-Vproj/out-proj batched across modules
//  * MoE h1: single-bf16 A (post-routing safe) -> 1 MFMA/k-step
// Precision rule (R2-R4 lesson): everything feeding glog stays split-bf16
// (f32-grade); post-routing may be single-bf16.
// ---------------------------------------------------------------------------

#define B_    256
#define S_    256
#define T_    16
#define H_    1024
#define NH_   8
#define DH_   128
#define M128_ 128
#define G_    3
#define E_    8
#define I_    4096
#define R_    256
#define L_    3
#define GE_   24

using bf16x8 = __attribute__((ext_vector_type(8))) __bf16;
using f32x4  = __attribute__((ext_vector_type(4))) float;

__device__ inline float wave_sum(float v) {
    for (int o = 32; o > 0; o >>= 1) v += __shfl_xor(v, o);
    return v;
}
__device__ inline float wave_max(float v) {
    for (int o = 32; o > 0; o >>= 1) v = fmaxf(v, __shfl_xor(v, o));
    return v;
}

// ===================== split-bf16 MFMA GEMM, 128x128, 2-level z offsets ======
// C[r,n] = act( scale*(sum_k A[r,k]*Bt[n,k] + roff[r]) + bias[n] )
// z1 = z>>zshift, z2 = z & ((1<<zshift)-1); r1 = r>>m2shift, r2 = r&mask.
// A addr: Ap + z1*sAz1 + z2*sAz2 + r1*sA1 + r2*sA2 + k
// B addr: Bp + z1*sBz1 + z2*sBz2 + n*ldb + k
// C addr: Cf + z1*sCz1 + z2*sCz2 + r1*sC1 + r2*sC2 + n
// bias:   biasp + z1*sBia1 + z2*sBia2, indexed [cc]; roff similarly, indexed [rr]
template <int ACT>
__global__ __launch_bounds__(256) void sgemm2_k(
    const float* __restrict__ Ap, const float* __restrict__ Bp,
    const float* __restrict__ biasp, const float* __restrict__ roffp,
    float* __restrict__ Cf,
    int K, int m2shift, int zshift,
    long sA1, long sA2, long sAz1, long sAz2,
    long ldb, long sBz1, long sBz2, long sBia1, long sBia2,
    long sC1, long sC2, long sCz1, long sCz2, long sR1, long sR2,
    float scale)
{
    const int z  = blockIdx.z;
    const int z1 = z >> zshift;
    const int z2 = z & ((1 << zshift) - 1);
    const int m2mask = (1 << m2shift) - 1;
    const int row0 = blockIdx.y * 128;
    const int col0 = blockIdx.x * 128;
    const float* Ab = Ap + (long)z1 * sAz1 + (long)z2 * sAz2;
    const float* Bb = Bp + (long)z1 * sBz1 + (long)z2 * sBz2;
    const float* biasb = biasp ? biasp + (long)z1 * sBia1 + (long)z2 * sBia2 : nullptr;
    const float* roffb = roffp ? roffp + (long)z1 * sR1 + (long)z2 * sR2 : nullptr;

    __shared__ __bf16 Ahs[128 * 40];
    __shared__ __bf16 Als[128 * 40];
    __shared__ __bf16 Bhs[128 * 40];
    __shared__ __bf16 Bls[128 * 40];

    const int tid  = threadIdx.x;
    const int lane = tid & 63;
    const int wid  = tid >> 6;
    const int wm = (wid >> 1) * 64;
    const int wn = (wid & 1) * 64;
    const int fr  = lane & 15;
    const int fkb = (lane >> 4) * 16;
    const int qrow = tid >> 2;
    const int c4   = tid & 3;

    f32x4 acc[4][4] = {};

    for (int k0 = 0; k0 < K; k0 += 32) {
        __syncthreads();
#pragma unroll
        for (int rep = 0; rep < 2; ++rep) {
            const int row = qrow + rep * 64;
            {
                const int r = row0 + row;
                const int r1 = r >> m2shift, r2 = r & m2mask;
                const float* src = Ab + (long)r1 * sA1 + (long)r2 * sA2 + k0 + c4 * 8;
                float4 f0 = *(const float4*)src;
                float4 f1 = *(const float4*)(src + 4);
                const float fv[8] = {f0.x, f0.y, f0.z, f0.w, f1.x, f1.y, f1.z, f1.w};
                bf16x8 hi, lo;
#pragma unroll
                for (int j = 0; j < 8; ++j) {
                    const __bf16 h = (__bf16)fv[j];
                    hi[j] = h; lo[j] = (__bf16)(fv[j] - (float)h);
                }
                *(bf16x8*)&Ahs[row * 40 + c4 * 8] = hi;
                *(bf16x8*)&Als[row * 40 + c4 * 8] = lo;
            }
            {
                const float* src = Bb + (long)(col0 + row) * ldb + k0 + c4 * 8;
                float4 f0 = *(const float4*)src;
                float4 f1 = *(const float4*)(src + 4);
                const float fv[8] = {f0.x, f0.y, f0.z, f0.w, f1.x, f1.y, f1.z, f1.w};
                bf16x8 hi, lo;
#pragma unroll
                for (int j = 0; j < 8; ++j) {
                    const __bf16 h = (__bf16)fv[j];
                    hi[j] = h; lo[j] = (__bf16)(fv[j] - (float)h);
                }
                *(bf16x8*)&Bhs[row * 40 + c4 * 8] = hi;
                *(bf16x8*)&Bls[row * 40 + c4 * 8] = lo;
            }
        }
        __syncthreads();
        bf16x8 bh4[4], bl4[4];
#pragma unroll
        for (int n = 0; n < 4; ++n) {
            bh4[n] = *(const bf16x8*)((const char*)&Bhs[(wn + n * 16 + fr) * 40] + fkb);
            bl4[n] = *(const bf16x8*)((const char*)&Bls[(wn + n * 16 + fr) * 40] + fkb);
        }
#pragma unroll
        for (int m = 0; m < 4; ++m) {
            const bf16x8 ah = *(const bf16x8*)((const char*)&Ahs[(wm + m * 16 + fr) * 40] + fkb);
            const bf16x8 al = *(const bf16x8*)((const char*)&Als[(wm + m * 16 + fr) * 40] + fkb);
#pragma unroll
            for (int n = 0; n < 4; ++n) {
                acc[m][n] = __builtin_amdgcn_mfma_f32_16x16x32_bf16(ah, bh4[n], acc[m][n], 0, 0, 0);
                acc[m][n] = __builtin_amdgcn_mfma_f32_16x16x32_bf16(ah, bl4[n], acc[m][n], 0, 0, 0);
                acc[m][n] = __builtin_amdgcn_mfma_f32_16x16x32_bf16(al, bh4[n], acc[m][n], 0, 0, 0);
            }
        }
    }

    float* Cfb = Cf + (long)z1 * sCz1 + (long)z2 * sCz2;
    const int lr4 = (lane >> 4) * 4;
#pragma unroll
    for (int m = 0; m < 4; ++m) {
#pragma unroll
        for (int r = 0; r < 4; ++r) {
            const int rr = row0 + wm + m * 16 + lr4 + r;
            const int r1 = rr >> m2shift, r2 = rr & m2mask;
            const float ro = roffb ? roffb[rr] : 0.f;
            const long cb = (long)r1 * sC1 + (long)r2 * sC2;
#pragma unroll
            for (int n = 0; n < 4; ++n) {
                const int cc = col0 + wn + n * 16 + fr;
                float v = (acc[m][n][r] + ro) * scale;
                if (biasp) v += biasb[cc];
                if (ACT == 2) v = 1.0f / (1.0f + expf(-v));
                Cfb[cb + cc] = v;
            }
        }
    }
}

static void sg2(hipStream_t s, int act,
                const float* A, const float* B, const float* bias, const float* roff,
                float* C, int gx, int gy, int gz,
                int K, int m2shift, int zshift,
                long sA1, long sA2, long sAz1, long sAz2,
                long ldb, long sBz1, long sBz2, long sBia1, long sBia2,
                long sC1, long sC2, long sCz1, long sCz2, long sR1, long sR2,
                float scale)
{
    dim3 g(gx, gy, gz), b(256);
#define S2ARGS A, B, bias, roff, C, K, m2shift, zshift, sA1, sA2, sAz1, sAz2, \
               ldb, sBz1, sBz2, sBia1, sBia2, sC1, sC2, sCz1, sCz2, sR1, sR2, scale
    if (act == 2) sgemm2_k<2><<<g, b, 0, s>>>(S2ARGS);
    else          sgemm2_k<0><<<g, b, 0, s>>>(S2ARGS);
#undef S2ARGS
}

// ===================== 256x128 MFMA GEMM (MoE) — unchanged from R5 ==========
template <int ABF16, int BSING, int ACT, int WMUL, int OUTH>
__global__ __launch_bounds__(512) void sgemm256_k(
    const void* __restrict__ Ap, const float* __restrict__ Bp,
    const float* __restrict__ biasp, const float* __restrict__ wmulp,
    float* __restrict__ Cf, __bf16* __restrict__ Ch,
    int K, long sA1, long sAz, long ldb, long sBz, long sBz2, int bzshift,
    long sBias, long sC1, long sCz, long sWr, float scale)
{
    const int z    = blockIdx.z;
    const int col0 = blockIdx.x * 128;
    const int z1 = z >> bzshift;
    const int z2 = z - (z1 << bzshift);
    const float* Bb = Bp + (long)z1 * sBz + (long)z2 * sBz2;
    const float* biasb = biasp ? biasp + (long)z1 * sBias : nullptr;

    __shared__ __bf16 Ah[256 * 40];
    __shared__ __bf16 Al[ABF16 ? 64 : 256 * 40];
    __shared__ __bf16 Bh[128 * 40];
    __shared__ __bf16 Bl[BSING ? 64 : 128 * 40];

    const int tid  = threadIdx.x;
    const int lane = tid & 63;
    const int wid  = tid >> 6;
    const int wm = (wid >> 1) * 64;
    const int wn = (wid & 1) * 64;
    const int fr  = lane & 15;
    const int fkb = (lane >> 4) * 16;

    f32x4 acc[4][4] = {};

    for (int k0 = 0; k0 < K; k0 += 32) {
        __syncthreads();
#pragma unroll
        for (int rep = 0; rep < 2; ++rep) {
            const int idx = tid + rep * 512;
            const int row = idx >> 2;
            const int c4  = idx & 3;
            if (ABF16) {
                bf16x8 v = *(const bf16x8*)((const __bf16*)Ap + (long)z * sAz +
                                            (long)row * sA1 + k0 + c4 * 8);
                *(bf16x8*)&Ah[row * 40 + c4 * 8] = v;
            } else {
                const float* src = (const float*)Ap + (long)z * sAz +
                                   (long)row * sA1 + k0 + c4 * 8;
                float4 f0 = *(const float4*)src;
                float4 f1 = *(const float4*)(src + 4);
                const float fv[8] = {f0.x, f0.y, f0.z, f0.w, f1.x, f1.y, f1.z, f1.w};
                bf16x8 hi, lo;
#pragma unroll
                for (int j = 0; j < 8; ++j) {
                    const __bf16 h = (__bf16)fv[j];
                    hi[j] = h; lo[j] = (__bf16)(fv[j] - (float)h);
                }
                *(bf16x8*)&Ah[row * 40 + c4 * 8] = hi;
                *(bf16x8*)&Al[row * 40 + c4 * 8] = lo;
            }
        }
        {
            const int row = tid >> 2;
            const int c4  = tid & 3;
            const float* src = Bb + (long)(col0 + row) * ldb + k0 + c4 * 8;
            float4 f0 = *(const float4*)src;
            float4 f1 = *(const float4*)(src + 4);
            const float fv[8] = {f0.x, f0.y, f0.z, f0.w, f1.x, f1.y, f1.z, f1.w};
            bf16x8 hi, lo;
#pragma unroll
            for (int j = 0; j < 8; ++j) {
                const __bf16 h = (__bf16)fv[j];
                hi[j] = h;
                if (!BSING) lo[j] = (__bf16)(fv[j] - (float)h);
            }
            *(bf16x8*)&Bh[row * 40 + c4 * 8] = hi;
            if (!BSING) *(bf16x8*)&Bl[row * 40 + c4 * 8] = lo;
        }
        __syncthreads();
        bf16x8 bh4[4], bl4[4];
#pragma unroll
        for (int n = 0; n < 4; ++n) {
            bh4[n] = *(const bf16x8*)((const char*)&Bh[(wn + n * 16 + fr) * 40] + fkb);
            if (!BSING) bl4[n] = *(const bf16x8*)((const char*)&Bl[(wn + n * 16 + fr) * 40] + fkb);
        }
#pragma unroll
        for (int m = 0; m < 4; ++m) {
            const bf16x8 ah = *(const bf16x8*)((const char*)&Ah[(wm + m * 16 + fr) * 40] + fkb);
            bf16x8 al;
            if (!ABF16) al = *(const bf16x8*)((const char*)&Al[(wm + m * 16 + fr) * 40] + fkb);
#pragma unroll
            for (int n = 0; n < 4; ++n) {
                acc[m][n] = __builtin_amdgcn_mfma_f32_16x16x32_bf16(ah, bh4[n], acc[m][n], 0, 0, 0);
                if (!BSING) acc[m][n] = __builtin_amdgcn_mfma_f32_16x16x32_bf16(ah, bl4[n], acc[m][n], 0, 0, 0);
                if (!ABF16) acc[m][n] = __builtin_amdgcn_mfma_f32_16x16x32_bf16(al, bh4[n], acc[m][n], 0, 0, 0);
            }
        }
    }

    const int lr4 = (lane >> 4) * 4;
#pragma unroll
    for (int m = 0; m < 4; ++m) {
#pragma unroll
        for (int r = 0; r < 4; ++r) {
            const int rr = wm + m * 16 + lr4 + r;
#pragma unroll
            for (int n = 0; n < 4; ++n) {
                const int cc = col0 + wn + n * 16 + fr;
                float v = acc[m][n][r] * scale;
                if (biasp) v += biasb[cc];
                if (ACT == 1) v = 0.5f * v * (1.0f + erff(v * 0.70710678118654752f));
                if (WMUL) v *= wmulp[(long)rr * sWr + z];
                if (OUTH) Ch[(long)z * sCz + (long)rr * sC1 + cc] = (__bf16)v;
                else      Cf[(long)z * sCz + (long)rr * sC1 + cc] = v;
            }
        }
    }
}

// ===================== f32 VALU GEMM (small N only) =====================
#define BM 64
#define BN 64
#define BK 16
__global__ __launch_bounds__(256) void gemm_k(
    const float* __restrict__ Ap, const float* __restrict__ Bp,
    const float* __restrict__ biasp, float* __restrict__ Cp,
    int M, int N, int K, long sA1, long ldb, long sC1)
{
    const int row0 = blockIdx.y * BM;
    const int col0 = blockIdx.x * BN;
    const int tid = threadIdx.x;
    __shared__ float As[BK][BM + 4];
    __shared__ float Bs[BK][BN + 4];
    float acc[4][4] = {};
    const int tm = (tid >> 4) << 2;
    const int tn = (tid & 15) << 2;
    for (int k0 = 0; k0 < K; k0 += BK) {
        {
            const int i = tid << 2;
            const int m = i >> 4, kk = i & 15;
            const int r = row0 + m;
            float4 v = make_float4(0.f, 0.f, 0.f, 0.f);
            if (r < M) v = *(const float4*)(Ap + (long)r * sA1 + k0 + kk);
            As[kk + 0][m] = v.x; As[kk + 1][m] = v.y;
            As[kk + 2][m] = v.z; As[kk + 3][m] = v.w;
        }
        {
            const int i = tid << 2;
            const int n = i >> 4, kk = i & 15;
            const int c = col0 + n;
            float4 v = make_float4(0.f, 0.f, 0.f, 0.f);
            if (c < N) v = *(const float4*)(Bp + (long)c * ldb + k0 + kk);
            Bs[kk + 0][n] = v.x; Bs[kk + 1][n] = v.y;
            Bs[kk + 2][n] = v.z; Bs[kk + 3][n] = v.w;
        }
        __syncthreads();
#pragma unroll
        for (int kk = 0; kk < BK; ++kk) {
            const float4 av = *(const float4*)&As[kk][tm];
            const float4 bv = *(const float4*)&Bs[kk][tn];
            acc[0][0] += av.x * bv.x; acc[0][1] += av.x * bv.y;
            acc[0][2] += av.x * bv.z; acc[0][3] += av.x * bv.w;
            acc[1][0] += av.y * bv.x; acc[1][1] += av.y * bv.y;
            acc[1][2] += av.y * bv.z; acc[1][3] += av.y * bv.w;
            acc[2][0] += av.z * bv.x; acc[2][1] += av.z * bv.y;
            acc[2][2] += av.z * bv.z; acc[2][3] += av.z * bv.w;
            acc[3][0] += av.w * bv.x; acc[3][1] += av.w * bv.y;
            acc[3][2] += av.w * bv.z; acc[3][3] += av.w * bv.w;
        }
        __syncthreads();
    }
#pragma unroll
    for (int i2 = 0; i2 < 4; ++i2) {
        const int r = row0 + tm + i2;
        if (r >= M) continue;
        float* crow = Cp + (long)r * sC1;
#pragma unroll
        for (int j = 0; j < 4; ++j) {
            const int c = col0 + tn + j;
            if (c >= N) continue;
            float v = acc[i2][j];
            if (biasp) v += biasp[c];
            crow[c] = v;
        }
    }
}

static void g_launch(hipStream_t s, const float* A, const float* Bw, const float* bias,
                     float* C, int M, int N, int K, long sA1, long ldb, long sC1)
{
    dim3 grid((N + BN - 1) / BN, (M + BM - 1) / BM, 1);
    gemm_k<<<grid, dim3(256), 0, s>>>(A, Bw, bias, C, M, N, K, sA1, ldb, sC1);
}

// ===================== transpose / copy / bias concat =====================
__global__ void tT_k(const float* __restrict__ src, float* __restrict__ dst, int R, int C)
{
    __shared__ float t[32][33];
    const int c0 = blockIdx.x * 32, r0 = blockIdx.y * 32;
    const int tx = threadIdx.x & 31, ty = threadIdx.x >> 5;
#pragma unroll
    for (int i = 0; i < 4; ++i) {
        const int r = ty + i * 8;
        t[r][tx] = src[(long)(r0 + r) * C + c0 + tx];
    }
    __syncthreads();
#pragma unroll
    for (int i = 0; i < 4; ++i) {
        const int r = ty + i * 8;
        dst[(long)(c0 + r) * R + r0 + tx] = t[tx][r];
    }
}

__global__ void cpy_k(const float* __restrict__ src, float* __restrict__ dst, int n4)
{
    const int i = blockIdx.x * blockDim.x + threadIdx.x;
    if (i < n4) ((float4*)dst)[i] = ((const float4*)src)[i];
}

__global__ void biascat_k(const float* __restrict__ ts_b, const float* __restrict__ ca_b,
                          const float* __restrict__ st_b,
                          const float* __restrict__ ts_ob, const float* __restrict__ ca_ob,
                          const float* __restrict__ st_ob,
                          float* __restrict__ BCAT, float* __restrict__ BKCAT,
                          float* __restrict__ WVB, float* __restrict__ WOB)
{
    const int i = blockIdx.x * blockDim.x + threadIdx.x;
    if (i >= 1024) return;
    BCAT[i] = ts_b[i]; BCAT[1024 + i] = ca_b[i];
    BCAT[2048 + i] = st_b[1024 + i]; BCAT[3072 + i] = st_b[2048 + i];
    BKCAT[i] = ts_b[1024 + i]; BKCAT[1024 + i] = ca_b[1024 + i]; BKCAT[2048 + i] = st_b[i];
    WVB[i] = ts_b[2048 + i]; WVB[1024 + i] = ca_b[2048 + i];
    WOB[i] = ts_ob[i]; WOB[1024 + i] = ca_ob[i]; WOB[2048 + i] = st_ob[i];
}

// ===================== glue kernels =====================
// OFFS3[mod][b][t*8+h] = QALL[(b*16+t)][mod*1024 + h*128 ..] . BKCAT[mod*1024 + h*128 ..]
__global__ void headdot3_k(const float* __restrict__ QALL, const float* __restrict__ BKCAT,
                           float* __restrict__ out)
{
    const int idx = blockIdx.x * blockDim.x + threadIdx.x;
    if (idx >= 3 * B_ * T_ * NH_) return;
    const int mod = idx >> 15;
    const int b = (idx >> 7) & 255;
    const int t = (idx >> 3) & 15;
    const int h = idx & 7;
    const float* q = QALL + (long)(b * 16 + t) * 4096 + mod * 1024 + h * 128;
    const float* bb = BKCAT + mod * 1024 + h * 128;
    float sum = 0.f;
    for (int k = 0; k < DH_; ++k) sum += q[k] * bb[k];
    out[idx] = sum;
}

__global__ void softmax_rows_k(float* __restrict__ x)
{
    const long row = blockIdx.x;
    float* p = x + row * S_;
    const int t = threadIdx.x;
    float v0 = p[t], v1 = p[t + 64], v2 = p[t + 128], v3 = p[t + 192];
    float m = wave_max(fmaxf(fmaxf(v0, v1), fmaxf(v2, v3)));
    v0 = expf(v0 - m); v1 = expf(v1 - m); v2 = expf(v2 - m); v3 = expf(v3 - m);
    const float inv = 1.f / wave_sum(v0 + v1 + v2 + v3);
    p[t] = v0 * inv; p[t + 64] = v1 * inv; p[t + 128] = v2 * inv; p[t + 192] = v3 * inv;
}

__global__ void softmax_t_k(float* __restrict__ sc)
{
    const int idx = blockIdx.x * blockDim.x + threadIdx.x;
    if (idx >= B_ * NH_ * S_) return;
    const int s = idx % S_;
    const int h = (idx / S_) % NH_;
    const int b = idx / (S_ * NH_);
    float* base = sc + (long)b * M128_ * S_ + (long)h * S_ + s;
    float v[T_];
    float mx = -1e30f;
#pragma unroll
    for (int t = 0; t < T_; ++t) { v[t] = base[(long)t * NH_ * S_]; mx = fmaxf(mx, v[t]); }
    float sum = 0.f;
#pragma unroll
    for (int t = 0; t < T_; ++t) { v[t] = expf(v[t] - mx); sum += v[t]; }
    const float inv = 1.f / sum;
#pragma unroll
    for (int t = 0; t < T_; ++t) base[(long)t * NH_ * S_] = v[t] * inv;
}

__global__ void rowmean_k(const float* __restrict__ x, float* __restrict__ out)
{
    const int row = blockIdx.x;
    const float* p = x + (long)row * S_;
    float sv = 0.f;
    for (int i = threadIdx.x; i < S_; i += 64) sv += p[i];
    sv = wave_sum(sv);
    if (threadIdx.x == 0) out[row] = sv * (1.0f / S_);
}

// PBAR3[mod][b][h][s] = mean_t SC3[mod][b][t*8+h][s]   (mod in {0,1})
__global__ void pbar3_k(const float* __restrict__ sc3, float* __restrict__ pb)
{
    const int idx = blockIdx.x * blockDim.x + threadIdx.x;
    if (idx >= 2 * B_ * NH_ * S_) return;
    const int mod = idx >> 19;
    const int b = (idx >> 11) & 255;
    const int hs = idx & 2047;            // h*256 + s
    const float* base = sc3 + (long)mod * 8388608 + (long)b * 32768 + hs;
    float sum = 0.f;
#pragma unroll
    for (int t = 0; t < T_; ++t) sum += base[(long)t * 2048];
    pb[idx] = sum * (1.0f / T_);
}

// CTXB3[mod][b][h][k] = sum_s PBAR3[mod][b][h][s] * h_sent[b][s][k], 16 heads/block
__global__ __launch_bounds__(256) void ctxw2_k(const float* __restrict__ pbar,
                                               const float* __restrict__ hs,
                                               float* __restrict__ out)
{
    const int b = blockIdx.x;
    __shared__ float pl[16][S_];
    const int tid = threadIdx.x;
    for (int i = tid; i < 16 * S_; i += 256) {
        const int mod = i >> 11;
        pl[i >> 8][i & 255] = pbar[(long)mod * 524288 + (long)b * 2048 + (i & 2047)];
    }
    __syncthreads();
    const int k0 = tid * 4;
    float4 acc[16] = {};
    const float* hb = hs + (long)b * S_ * H_;
    for (int s = 0; s < S_; ++s) {
        const float4 v = *(const float4*)(hb + (long)s * H_ + k0);
#pragma unroll
        for (int j = 0; j < 16; ++j) {
            const float p = pl[j][s];
            acc[j].x += p * v.x; acc[j].y += p * v.y;
            acc[j].z += p * v.z; acc[j].w += p * v.w;
        }
    }
#pragma unroll
    for (int j = 0; j < 16; ++j) {
        const int mod = j >> 3, h = j & 7;
        *(float4*)(out + (long)mod * 2097152 + (long)b * 8192 + h * 1024 + k0) = acc[j];
    }
}

// OBAR3[2][b][c] (st) = sum_t attm * QALL V-block (col 3072)
__global__ void ohead2_k(const float* __restrict__ attm, const float* __restrict__ QALL,
                         float* __restrict__ outb)
{
    const int idx = blockIdx.x * blockDim.x + threadIdx.x;
    if (idx >= B_ * H_) return;
    const int c = idx & (H_ - 1);
    const int b = idx >> 10;
    const int h = c >> 7;
    float sv = 0.f;
#pragma unroll
    for (int t = 0; t < T_; ++t)
        sv += attm[b * M128_ + t * NH_ + h] * QALL[(long)(b * 16 + t) * 4096 + 3072 + c];
    outb[idx] = sv;
}

__global__ void cat3_k(const float* __restrict__ vs, const float* __restrict__ vt,
                       const float* __restrict__ vo, float* __restrict__ out)
{
    const int idx = blockIdx.x * blockDim.x + threadIdx.x;
    if (idx >= B_ * 3 * H_) return;
    const int k = idx % (3 * H_);
    const int b = idx / (3 * H_);
    float v;
    if (k < H_)          v = vs[b * H_ + k];
    else if (k < 2 * H_) v = vt[b * H_ + k - H_];
    else                 v = vo[b * H_ + k - 2 * H_];
    out[idx] = v;
}

__global__ void ln_k(const float* __restrict__ cat3, const float* __restrict__ g,
                     const float* __restrict__ bta, float* __restrict__ out)
{
    const int b = blockIdx.x;
    const int tid = threadIdx.x;
    __shared__ float buf[3 * H_];
    __shared__ float red[4];
    const float* src = cat3 + (long)b * 3 * H_;
    float sv = 0.f;
    for (int i = tid; i < 3 * H_; i += 256) { const float x = src[i]; buf[i] = x; sv += x; }
    sv = wave_sum(sv);
    if ((tid & 63) == 0) red[tid >> 6] = sv;
    __syncthreads();
    const float mu = (red[0] + red[1] + red[2] + red[3]) * (1.f / (3 * H_));
    __syncthreads();
    float s2 = 0.f;
    for (int i = tid; i < 3 * H_; i += 256) { const float d0 = buf[i] - mu; s2 += d0 * d0; }
    s2 = wave_sum(s2);
    if ((tid & 63) == 0) red[tid >> 6] = s2;
    __syncthreads();
    const float var = (red[0] + red[1] + red[2] + red[3]) * (1.f / (3 * H_));
    const float rstd = rsqrtf(var + 1e-5f);
    float* dst = out + (long)b * 3 * H_;
    for (int i = tid; i < 3 * H_; i += 256)
        dst[i] = (buf[i] - mu) * rstd * g[i] + bta[i];
}

__global__ void mulf_k(const float* __restrict__ a, const float* __restrict__ b2,
                       float* __restrict__ out, int n)
{
    const int idx = blockIdx.x * blockDim.x + threadIdx.x;
    if (idx < n) out[idx] = a[idx] * b2[idx];
}

__global__ void fuse_k(const float* __restrict__ g, const float* __restrict__ flin,
                       const float* __restrict__ bil, float* __restrict__ fused,
                       __bf16* __restrict__ fusedh)
{
    const int idx = blockIdx.x * blockDim.x + threadIdx.x;
    if (idx >= B_ * H_) return;
    const float gg = g[idx];
    const float v = gg * flin[idx] + (1.f - gg) * bil[idx];
    fused[idx] = v;
    fusedh[idx] = (__bf16)v;
}

__global__ void catfv_k(const float* __restrict__ fused, const float* __restrict__ vt,
                        float* __restrict__ out)
{
    const int idx = blockIdx.x * blockDim.x + threadIdx.x;
    if (idx >= B_ * 2 * H_) return;
    const int k = idx % (2 * H_);
    const int b = idx / (2 * H_);
    out[idx] = (k < H_) ? fused[b * H_ + k] : vt[b * H_ + k - H_];
}

__global__ void route_k(const float* __restrict__ glog, float* __restrict__ gp)
{
    const int b = blockIdx.x * blockDim.x + threadIdx.x;
    if (b >= B_) return;
    const float x0 = glog[b * 3], x1 = glog[b * 3 + 1], x2 = glog[b * 3 + 2];
    const float m1 = fmaxf(x0, fmaxf(x1, x2));
    float thr;
    if (x0 == m1)      thr = fmaxf(x1, x2);
    else if (x1 == m1) thr = fmaxf(x0, x2);
    else               thr = fmaxf(x0, x1);
    const float y0 = (x0 >= thr) ? x0 : -1e9f;
    const float y1 = (x1 >= thr) ? x1 : -1e9f;
    const float y2 = (x2 >= thr) ? x2 : -1e9f;
    const float mm = fmaxf(y0, fmaxf(y1, y2));
    const float e0 = expf(y0 - mm), e1 = expf(y1 - mm), e2 = expf(y2 - mm);
    const float inv = 1.f / (e0 + e1 + e2);
    gp[b * 3] = e0 * inv; gp[b * 3 + 1] = e1 * inv; gp[b * 3 + 2] = e2 * inv;
}

// ep softmax then wsc[b,ge] = gp[b,g]*ep[b,ge]  (in place over ELOG)
__global__ void epsm_k(float* __restrict__ elog, const float* __restrict__ gp)
{
    const int idx = blockIdx.x * blockDim.x + threadIdx.x;
    if (idx >= B_ * G_) return;
    float* p = elog + (long)idx * E_;
    float m = p[0];
#pragma unroll
    for (int e = 1; e < E_; ++e) m = fmaxf(m, p[e]);
    float sum = 0.f;
    float v[E_];
#pragma unroll
    for (int e = 0; e < E_; ++e) { v[e] = expf(p[e] - m); sum += v[e]; }
    const float w = gp[idx] / sum;
#pragma unroll
    for (int e = 0; e < E_; ++e) p[e] = v[e] * w;
}

__global__ void moefinal_k(const float* __restrict__ part, const float* __restrict__ fused,
                           const float* __restrict__ wsc, const float* __restrict__ e_b2,
                           float* __restrict__ res)
{
    const int idx = blockIdx.x * blockDim.x + threadIdx.x;
    if (idx >= B_ * H_) return;
    const int b = idx >> 10;
    const int h = idx & (H_ - 1);
    float acc = fused[idx];
#pragma unroll 8
    for (int z = 0; z < 48; ++z) acc += part[(long)z * (B_ * H_) + idx];
    float ba = 0.f;
#pragma unroll
    for (int ge = 0; ge < GE_; ++ge) ba += wsc[b * GE_ + ge] * e_b2[ge * H_ + h];
    res[idx] = acc + ba;
}

// ===================== entry =====================
extern "C" void kernel_launch(void* const* d_in, const int* in_sizes, int n_in,
                              void* d_out, int out_size, void* d_ws, size_t ws_size,
                              hipStream_t stream)
{
    const float* h_sent  = (const float*)d_in[0];
    const float* h_term  = (const float*)d_in[1];
    const float* ts_in_w = (const float*)d_in[2];
    const float* ts_out_w= (const float*)d_in[3];
    const float* st_in_w = (const float*)d_in[4];
    const float* st_out_w= (const float*)d_in[5];
    const float* ca_in_w = (const float*)d_in[6];
    const float* ca_out_w= (const float*)d_in[7];
    const float* opq_w   = (const float*)d_in[8];
    const float* fuse_w  = (const float*)d_in[9];
    const float* gate_w  = (const float*)d_in[10];
    const float* bs_w    = (const float*)d_in[11];
    const float* bt_w    = (const float*)d_in[12];
    const float* bo_w    = (const float*)d_in[13];
    const float* cond_w  = (const float*)d_in[14];
    const float* gr_w    = (const float*)d_in[15];
    const float* er_w    = (const float*)d_in[16];
    const float* e_w1    = (const float*)d_in[17];
    const float* e_w2    = (const float*)d_in[18];
    const float* cls_w   = (const float*)d_in[19];
    const float* ts_in_b = (const float*)d_in[20];
    const float* ts_out_b= (const float*)d_in[21];
    const float* st_in_b = (const float*)d_in[22];
    const float* st_out_b= (const float*)d_in[23];
    const float* ca_in_b = (const float*)d_in[24];
    const float* ca_out_b= (const float*)d_in[25];
    const float* fuse_b  = (const float*)d_in[26];
    const float* gate_b  = (const float*)d_in[27];
    const float* bs_b    = (const float*)d_in[28];
    const float* bt_b    = (const float*)d_in[29];
    const float* bo_b    = (const float*)d_in[30];
    const float* cond_b  = (const float*)d_in[31];
    const float* gr_b    = (const float*)d_in[32];
    const float* er_b    = (const float*)d_in[33];
    const float* e_b1    = (const float*)d_in[34];
    const float* e_b2    = (const float*)d_in[35];
    const float* cls_b   = (const float*)d_in[36];
    const float* ln_b    = (const float*)d_in[37];
    const float* ln_g    = (const float*)d_in[38];
    (void)in_sizes; (void)n_in; (void)out_size; (void)ws_size;

    float* ws = (float*)d_ws;
    size_t off = 0;
    auto allocF = [&](size_t n) { float* p = ws + off; off += (n + 63) & ~(size_t)63; return p; };

    float* QALL  = allocF(16777216);  // [B*T][4096] = {Q_ts | Q_ca | K_st | V_st}
    float* WCAT  = allocF(4194304);   // [4096][1024]
    float* BCAT  = allocF(4096);
    float* BKCAT = allocF(3072);
    float* wT3   = allocF(3145728);   // [3][1024][1024] fold weights (transposed)
    float* opqT  = allocF(1048576);
    float* WVCAT = allocF(2097152);   // [2][1024][1024] Wv ts/ca
    float* WVB   = allocF(2048);
    float* WOCAT = allocF(3145728);   // [3][1024][1024] out_w ts/ca/st
    float* WOB   = allocF(3072);
    float* OFFS3 = allocF(98304);     // [3][B][128]
    float* BIG3  = allocF(100663296); // [3][B][128][H]
    float* SC3   = allocF(25165824);  // [3][B][128][S]
    float* PBAR3 = allocF(1048576);   // [2][B][8][S]
    float* CTXB3 = allocF(4194304);   // [2][B][8][H]
    float* OBAR3 = allocF(786432);    // [3][B][H]
    float* VOUT3 = allocF(786432);    // [3][B][H] = {VTERM | VOP | VSENT}
    float* ATTM  = allocF(32768);
    float* CAT3  = allocF(786432);
    float* LNC   = allocF(786432);
    float* FLIN  = allocF(262144);
    float* GATE  = allocF(262144);
    float* BSV   = allocF(65536);
    float* BTV   = allocF(65536);
    float* PROD  = allocF(65536);
    float* BIL   = allocF(262144);
    float* FUSED = allocF(262144);
    float* FUSEDH= allocF(131072);    // bf16 [B][H]
    float* CATFV = allocF(524288);
    float* COND  = allocF(262144);
    float* GLOG  = allocF(1024);
    float* GP    = allocF(1024);
    float* ELOG  = allocF(8192);
    float* RES   = allocF(262144);
    float* H1Wf  = allocF(12582912);  // bf16 [B][24*I]
    float* PART  = allocF(12582912);  // [48][B][H]
    // total ~ 193M floats ~ 772 MB  (ws >= 1.6 GB per profile fill size)
    __bf16* FUSEDbf = (__bf16*)FUSEDH;
    __bf16* H1W     = (__bf16*)H1Wf;
    float* VTERM = VOUT3;
    float* VOP   = VOUT3 + 262144;
    float* VSENT = VOUT3 + 524288;

    hipStream_t s = stream;
    const float rscale = 0.08838834764831845f;  // 1/sqrt(128)

    // ---------- precompute: copies / transposes / bias concat ----------
    cpy_k<<<dim3(1024), dim3(256), 0, s>>>(ts_in_w, WCAT, 262144);                       // Wq_ts
    cpy_k<<<dim3(1024), dim3(256), 0, s>>>(st_in_w + 1048576, WCAT + 2097152, 262144);   // Wk_st
    cpy_k<<<dim3(1024), dim3(256), 0, s>>>(st_in_w + 2097152, WCAT + 3145728, 262144);   // Wv_st
    cpy_k<<<dim3(1024), dim3(256), 0, s>>>(ts_in_w + 2097152, WVCAT, 262144);            // Wv_ts
    cpy_k<<<dim3(1024), dim3(256), 0, s>>>(ca_in_w + 2097152, WVCAT + 1048576, 262144);  // Wv_ca
    cpy_k<<<dim3(1024), dim3(256), 0, s>>>(ts_out_w, WOCAT, 262144);
    cpy_k<<<dim3(1024), dim3(256), 0, s>>>(ca_out_w, WOCAT + 1048576, 262144);
    cpy_k<<<dim3(1024), dim3(256), 0, s>>>(st_out_w, WOCAT + 2097152, 262144);
    biascat_k<<<dim3(4), dim3(256), 0, s>>>(ts_in_b, ca_in_b, st_in_b,
                                            ts_out_b, ca_out_b, st_out_b,
                                            BCAT, BKCAT, WVB, WOB);
    tT_k<<<dim3(32, 32), dim3(256), 0, s>>>(ts_in_w + 1048576, wT3, 1024, 1024);           // Wk_ts^T
    tT_k<<<dim3(32, 32), dim3(256), 0, s>>>(ca_in_w + 1048576, wT3 + 1048576, 1024, 1024); // Wk_ca^T
    tT_k<<<dim3(32, 32), dim3(256), 0, s>>>(st_in_w, wT3 + 2097152, 1024, 1024);           // Wq_st^T
    tT_k<<<dim3(32, 32), dim3(256), 0, s>>>(opq_w, opqT, 1024, 1024);

    // Wcomb_ca = Wq_ca @ opq_w  -> WCAT rows 1024:2048
    sg2(s, 0, ca_in_w, opqT, nullptr, nullptr, WCAT + 1048576,
        8, 8, 1, 1024, 12, 0,
        0, 1024, 0, 0,
        1024, 0, 0, 0, 0,
        0, 1024, 0, 0, 0, 0, 1.f);

    // ---------- QALL = h_term @ WCAT^T + BCAT  (M=4096, N=4096) ----------
    sg2(s, 0, h_term, WCAT, BCAT, nullptr, QALL,
        32, 32, 1, 1024, 12, 0,
        0, 1024, 0, 0,
        1024, 0, 0, 0, 0,
        0, 4096, 0, 0, 0, 0, 1.f);

    // ---------- OFFS3 ----------
    headdot3_k<<<dim3(384), dim3(256), 0, s>>>(QALL, BKCAT, OFFS3);

    // ---------- A-fold batched z=24 (mod,h): BIG3 ----------
    sg2(s, 0, QALL, wT3, nullptr, nullptr, BIG3,
        8, 32, 24, 128, 4, 3,
        65536, 4096, 1024, 128,
        1024, 1048576, 128, 0, 0,
        131072, 8192, 33554432, 1024, 0, 0, 1.f);

    // ---------- scores batched z=768 (mod,b): SC3 ----------
    sg2(s, 0, BIG3, h_sent, nullptr, OFFS3, SC3,
        2, 1, 768, 1024, 12, 8,
        0, 1024, 33554432, 131072,
        1024, 0, 262144, 0, 0,
        0, 256, 8388608, 32768, 32768, 128, rscale);

    // ---------- softmax ----------
    softmax_rows_k<<<dim3(2 * B_ * M128_), dim3(64), 0, s>>>(SC3);              // mods 0,1
    softmax_t_k<<<dim3((B_ * NH_ * S_ + 255) / 256), dim3(256), 0, s>>>(SC3 + 2 * 8388608);

    // ---------- ctx path (t2s + ca) ----------
    pbar3_k<<<dim3(2 * B_ * NH_ * S_ / 256), dim3(256), 0, s>>>(SC3, PBAR3);
    ctxw2_k<<<dim3(B_), dim3(256), 0, s>>>(PBAR3, h_sent, CTXB3);
    // ctx V-proj batched z=16 (mod,h): OBAR3 mods 0,1
    sg2(s, 0, CTXB3, WVCAT, WVB, nullptr, OBAR3,
        1, 2, 16, 1024, 12, 3,
        0, 8192, 2097152, 1024,
        1024, 1048576, 131072, 1024, 128,
        0, 1024, 262144, 128, 0, 0, 1.f);

    // ---------- st path ----------
    rowmean_k<<<dim3(B_ * M128_), dim3(64), 0, s>>>(SC3 + 2 * 8388608, ATTM);
    ohead2_k<<<dim3((B_ * H_ + 255) / 256), dim3(256), 0, s>>>(ATTM, QALL, OBAR3 + 524288);

    // ---------- out-proj batched z=3: VOUT3 = {VTERM, VOP, VSENT} ----------
    sg2(s, 0, OBAR3, WOCAT, WOB, nullptr, VOUT3,
        8, 2, 3, 1024, 12, 0,
        0, 1024, 262144, 0,
        1024, 1048576, 0, 1024, 0,
        0, 1024, 262144, 0, 0, 0, 1.f);

    // ---------- fusion head ----------
    cat3_k<<<dim3((B_ * 3 * H_ + 255) / 256), dim3(256), 0, s>>>(VSENT, VTERM, VOP, CAT3);
    ln_k<<<dim3(B_), dim3(256), 0, s>>>(CAT3, ln_g, ln_b, LNC);
    sg2(s, 0, LNC, fuse_w, fuse_b, nullptr, FLIN,
        8, 2, 1, 3072, 12, 0, 0, 3072, 0, 0, 3072, 0, 0, 0, 0, 0, 1024, 0, 0, 0, 0, 1.f);
    sg2(s, 2, CAT3, gate_w, gate_b, nullptr, GATE,
        8, 2, 1, 3072, 12, 0, 0, 3072, 0, 0, 3072, 0, 0, 0, 0, 0, 1024, 0, 0, 0, 0, 1.f);
    sg2(s, 0, VSENT, bs_w, bs_b, nullptr, BSV,
        2, 2, 1, 1024, 12, 0, 0, 1024, 0, 0, 1024, 0, 0, 0, 0, 0, 256, 0, 0, 0, 0, 1.f);
    sg2(s, 0, VTERM, bt_w, bt_b, nullptr, BTV,
        2, 2, 1, 1024, 12, 0, 0, 1024, 0, 0, 1024, 0, 0, 0, 0, 0, 256, 0, 0, 0, 0, 1.f);
    mulf_k<<<dim3((B_ * R_ + 255) / 256), dim3(256), 0, s>>>(BSV, BTV, PROD, B_ * R_);
    sg2(s, 0, PROD, bo_w, bo_b, nullptr, BIL,
        8, 2, 1, 256, 12, 0, 0, 256, 0, 0, 256, 0, 0, 0, 0, 0, 1024, 0, 0, 0, 0, 1.f);
    fuse_k<<<dim3((B_ * H_ + 255) / 256), dim3(256), 0, s>>>(GATE, FLIN, BIL, FUSED, FUSEDbf);
    catfv_k<<<dim3((B_ * 2 * H_ + 255) / 256), dim3(256), 0, s>>>(FUSED, VTERM, CATFV);
    sg2(s, 0, CATFV, cond_w, cond_b, nullptr, COND,
        8, 2, 1, 2048, 12, 0, 0, 2048, 0, 0, 2048, 0, 0, 0, 0, 0, 1024, 0, 0, 0, 0, 1.f);

    // ---------- routing (f32 VALU; feeds discontinuous top-k) ----------
    g_launch(s, FUSED, gr_w, gr_b, GLOG, B_, G_, H_, H_, H_, G_);
    route_k<<<dim3(1), dim3(256), 0, s>>>(GLOG, GP);
    g_launch(s, COND, er_w, er_b, ELOG, B_, GE_, H_, H_, H_, GE_);
    epsm_k<<<dim3(3), dim3(256), 0, s>>>(ELOG, GP);   // ELOG := wsc = gp*ep

    // ---------- MoE (post-routing: single-bf16 A and B) ----------
    // h1w[b][ge*I+i] = gelu(FUSEDbf @ e_w1[ge]^T + e_b1) * wsc[b,ge]  (bf16)
    sgemm256_k<1, 1, 1, 1, 1><<<dim3(I_ / 128, 1, GE_), dim3(512), 0, s>>>(
        FUSEDbf, e_w1, e_b1, ELOG, nullptr, H1W,
        1024, H_, 0, H_, (long)I_ * H_, 0, 0, I_,
        (long)GE_ * I_, I_, GE_, 1.f);
    // PART[zc][b][h] = h1w chunk @ e_w2 chunk (zc = ge*2 + khalf)
    sgemm256_k<1, 1, 0, 0, 0><<<dim3(H_ / 128, 1, 2 * GE_), dim3(512), 0, s>>>(
        H1W, e_w2, nullptr, nullptr, PART, nullptr,
        2048, (long)GE_ * I_, 2048, I_, (long)H_ * I_, 2048, 1, 0,
        H_, (long)B_ * H_, 0, 1.f);
    moefinal_k<<<dim3(B_ * H_ / 256), dim3(256), 0, s>>>(PART, FUSED, ELOG, e_b2, RES);

    // ---------- classifier ----------
    g_launch(s, RES, cls_w, cls_b, (float*)d_out, B_, L_, H_, H_, H_, L_);
}

// Round 7
// 1635.962 us; speedup vs baseline: 3.3163x; 1.3459x over previous
//
#include <hip/hip_runtime.h>
#include <math.h>

// ---------------------------------------------------------------------------
// HAGMoE — round 7: latency-hiding pass.
//  * register prefetch double-buffer in both MFMA GEMMs (loads for chunk k+1
//    issued after the barrier, consumed next iteration -> overlap with MFMA)
//  * fused softmax/pbar/attm kernel (1 launch, no SC3 writeback/re-read)
//  * ctxw split x4 over s + reduce (256 -> 1024 blocks)
//  * K-split + reduce-act for the tiny fusion-head GEMMs
// Precision rule unchanged: pre-routing split-bf16 (f32-grade); post-routing
// single-bf16. All partial sums f32.
// ---------------------------------------------------------------------------

#define B_    256
#define S_    256
#define T_    16
#define H_    1024
#define NH_   8
#define DH_   128
#define M128_ 128
#define G_    3
#define E_    8
#define I_    4096
#define R_    256
#define L_    3
#define GE_   24

using bf16x8 = __attribute__((ext_vector_type(8))) __bf16;
using f32x4  = __attribute__((ext_vector_type(4))) float;

__device__ inline float wave_sum(float v) {
    for (int o = 32; o > 0; o >>= 1) v += __shfl_xor(v, o);
    return v;
}
__device__ inline float wave_max(float v) {
    for (int o = 32; o > 0; o >>= 1) v = fmaxf(v, __shfl_xor(v, o));
    return v;
}

// ===================== split-bf16 MFMA GEMM, 128x128, prefetched =====================
template <int ACT>
__global__ __launch_bounds__(256) void sgemm2_k(
    const float* __restrict__ Ap, const float* __restrict__ Bp,
    const float* __restrict__ biasp, const float* __restrict__ roffp,
    float* __restrict__ Cf,
    int K, int m2shift, int zshift,
    long sA1, long sA2, long sAz1, long sAz2,
    long ldb, long sBz1, long sBz2, long sBia1, long sBia2,
    long sC1, long sC2, long sCz1, long sCz2, long sR1, long sR2,
    float scale)
{
    const int z  = blockIdx.z;
    const int z1 = z >> zshift;
    const int z2 = z & ((1 << zshift) - 1);
    const int m2mask = (1 << m2shift) - 1;
    const int row0 = blockIdx.y * 128;
    const int col0 = blockIdx.x * 128;
    const float* Ab = Ap + (long)z1 * sAz1 + (long)z2 * sAz2;
    const float* Bb = Bp + (long)z1 * sBz1 + (long)z2 * sBz2;
    const float* biasb = biasp ? biasp + (long)z1 * sBia1 + (long)z2 * sBia2 : nullptr;
    const float* roffb = roffp ? roffp + (long)z1 * sR1 + (long)z2 * sR2 : nullptr;

    __shared__ __bf16 Ahs[128 * 40];
    __shared__ __bf16 Als[128 * 40];
    __shared__ __bf16 Bhs[128 * 40];
    __shared__ __bf16 Bls[128 * 40];

    const int tid  = threadIdx.x;
    const int lane = tid & 63;
    const int wid  = tid >> 6;
    const int wm = (wid >> 1) * 64;
    const int wn = (wid & 1) * 64;
    const int fr  = lane & 15;
    const int fkb = (lane >> 4) * 16;
    const int qrow = tid >> 2;
    const int c4   = tid & 3;

    f32x4 acc[4][4] = {};
    float4 pfa[2][2], pfb[2][2];

    auto loadAB = [&](int k0) {
#pragma unroll
        for (int rep = 0; rep < 2; ++rep) {
            const int row = qrow + rep * 64;
            const int r = row0 + row;
            const int r1 = r >> m2shift, r2 = r & m2mask;
            const float* srcA = Ab + (long)r1 * sA1 + (long)r2 * sA2 + k0 + c4 * 8;
            pfa[rep][0] = *(const float4*)srcA;
            pfa[rep][1] = *(const float4*)(srcA + 4);
            const float* srcB = Bb + (long)(col0 + row) * ldb + k0 + c4 * 8;
            pfb[rep][0] = *(const float4*)srcB;
            pfb[rep][1] = *(const float4*)(srcB + 4);
        }
    };

    loadAB(0);
    for (int k0 = 0; k0 < K; k0 += 32) {
        __syncthreads();
#pragma unroll
        for (int rep = 0; rep < 2; ++rep) {
            const int row = qrow + rep * 64;
            {
                const float fv[8] = {pfa[rep][0].x, pfa[rep][0].y, pfa[rep][0].z, pfa[rep][0].w,
                                     pfa[rep][1].x, pfa[rep][1].y, pfa[rep][1].z, pfa[rep][1].w};
                bf16x8 hi, lo;
#pragma unroll
                for (int j = 0; j < 8; ++j) {
                    const __bf16 h = (__bf16)fv[j];
                    hi[j] = h; lo[j] = (__bf16)(fv[j] - (float)h);
                }
                *(bf16x8*)&Ahs[row * 40 + c4 * 8] = hi;
                *(bf16x8*)&Als[row * 40 + c4 * 8] = lo;
            }
            {
                const float fv[8] = {pfb[rep][0].x, pfb[rep][0].y, pfb[rep][0].z, pfb[rep][0].w,
                                     pfb[rep][1].x, pfb[rep][1].y, pfb[rep][1].z, pfb[rep][1].w};
                bf16x8 hi, lo;
#pragma unroll
                for (int j = 0; j < 8; ++j) {
                    const __bf16 h = (__bf16)fv[j];
                    hi[j] = h; lo[j] = (__bf16)(fv[j] - (float)h);
                }
                *(bf16x8*)&Bhs[row * 40 + c4 * 8] = hi;
                *(bf16x8*)&Bls[row * 40 + c4 * 8] = lo;
            }
        }
        __syncthreads();
        if (k0 + 32 < K) loadAB(k0 + 32);   // hidden under the MFMA phase

        bf16x8 bh4[4], bl4[4];
#pragma unroll
        for (int n = 0; n < 4; ++n) {
            bh4[n] = *(const bf16x8*)((const char*)&Bhs[(wn + n * 16 + fr) * 40] + fkb);
            bl4[n] = *(const bf16x8*)((const char*)&Bls[(wn + n * 16 + fr) * 40] + fkb);
        }
#pragma unroll
        for (int m = 0; m < 4; ++m) {
            const bf16x8 ah = *(const bf16x8*)((const char*)&Ahs[(wm + m * 16 + fr) * 40] + fkb);
            const bf16x8 al = *(const bf16x8*)((const char*)&Als[(wm + m * 16 + fr) * 40] + fkb);
#pragma unroll
            for (int n = 0; n < 4; ++n) {
                acc[m][n] = __builtin_amdgcn_mfma_f32_16x16x32_bf16(ah, bh4[n], acc[m][n], 0, 0, 0);
                acc[m][n] = __builtin_amdgcn_mfma_f32_16x16x32_bf16(ah, bl4[n], acc[m][n], 0, 0, 0);
                acc[m][n] = __builtin_amdgcn_mfma_f32_16x16x32_bf16(al, bh4[n], acc[m][n], 0, 0, 0);
            }
        }
    }

    float* Cfb = Cf + (long)z1 * sCz1 + (long)z2 * sCz2;
    const int lr4 = (lane >> 4) * 4;
#pragma unroll
    for (int m = 0; m < 4; ++m) {
#pragma unroll
        for (int r = 0; r < 4; ++r) {
            const int rr = row0 + wm + m * 16 + lr4 + r;
            const int r1 = rr >> m2shift, r2 = rr & m2mask;
            const float ro = roffb ? roffb[rr] : 0.f;
            const long cb = (long)r1 * sC1 + (long)r2 * sC2;
#pragma unroll
            for (int n = 0; n < 4; ++n) {
                const int cc = col0 + wn + n * 16 + fr;
                float v = (acc[m][n][r] + ro) * scale;
                if (biasp) v += biasb[cc];
                if (ACT == 2) v = 1.0f / (1.0f + expf(-v));
                Cfb[cb + cc] = v;
            }
        }
    }
}

static void sg2(hipStream_t s, int act,
                const float* A, const float* B, const float* bias, const float* roff,
                float* C, int gx, int gy, int gz,
                int K, int m2shift, int zshift,
                long sA1, long sA2, long sAz1, long sAz2,
                long ldb, long sBz1, long sBz2, long sBia1, long sBia2,
                long sC1, long sC2, long sCz1, long sCz2, long sR1, long sR2,
                float scale)
{
    dim3 g(gx, gy, gz), b(256);
#define S2ARGS A, B, bias, roff, C, K, m2shift, zshift, sA1, sA2, sAz1, sAz2, \
               ldb, sBz1, sBz2, sBia1, sBia2, sC1, sC2, sCz1, sCz2, sR1, sR2, scale
    if (act == 2) sgemm2_k<2><<<g, b, 0, s>>>(S2ARGS);
    else          sgemm2_k<0><<<g, b, 0, s>>>(S2ARGS);
#undef S2ARGS
}

// ===================== 256x128 MFMA GEMM (MoE), prefetched =====================
template <int ABF16, int BSING, int ACT, int WMUL, int OUTH>
__global__ __launch_bounds__(512) void sgemm256_k(
    const void* __restrict__ Ap, const float* __restrict__ Bp,
    const float* __restrict__ biasp, const float* __restrict__ wmulp,
    float* __restrict__ Cf, __bf16* __restrict__ Ch,
    int K, long sA1, long sAz, long ldb, long sBz, long sBz2, int bzshift,
    long sBias, long sC1, long sCz, long sWr, float scale)
{
    const int z    = blockIdx.z;
    const int col0 = blockIdx.x * 128;
    const int z1 = z >> bzshift;
    const int z2 = z - (z1 << bzshift);
    const float* Bb = Bp + (long)z1 * sBz + (long)z2 * sBz2;
    const float* biasb = biasp ? biasp + (long)z1 * sBias : nullptr;

    __shared__ __bf16 Ah[256 * 40];
    __shared__ __bf16 Al[ABF16 ? 64 : 256 * 40];
    __shared__ __bf16 Bh[128 * 40];
    __shared__ __bf16 Bl[BSING ? 64 : 128 * 40];

    const int tid  = threadIdx.x;
    const int lane = tid & 63;
    const int wid  = tid >> 6;
    const int wm = (wid >> 1) * 64;
    const int wn = (wid & 1) * 64;
    const int fr  = lane & 15;
    const int fkb = (lane >> 4) * 16;

    f32x4 acc[4][4] = {};
    bf16x8 pfah[2];
    float4 pfaf[2][2];
    float4 pfb[2];

    auto loadAB = [&](int k0) {
#pragma unroll
        for (int rep = 0; rep < 2; ++rep) {
            const int idx = tid + rep * 512;
            const int row = idx >> 2;
            const int cc4 = idx & 3;
            if (ABF16) {
                pfah[rep] = *(const bf16x8*)((const __bf16*)Ap + (long)z * sAz +
                                             (long)row * sA1 + k0 + cc4 * 8);
            } else {
                const float* src = (const float*)Ap + (long)z * sAz +
                                   (long)row * sA1 + k0 + cc4 * 8;
                pfaf[rep][0] = *(const float4*)src;
                pfaf[rep][1] = *(const float4*)(src + 4);
            }
        }
        {
            const int row = tid >> 2;
            const int cc4 = tid & 3;
            const float* src = Bb + (long)(col0 + row) * ldb + k0 + cc4 * 8;
            pfb[0] = *(const float4*)src;
            pfb[1] = *(const float4*)(src + 4);
        }
    };

    loadAB(0);
    for (int k0 = 0; k0 < K; k0 += 32) {
        __syncthreads();
#pragma unroll
        for (int rep = 0; rep < 2; ++rep) {
            const int idx = tid + rep * 512;
            const int row = idx >> 2;
            const int cc4 = idx & 3;
            if (ABF16) {
                *(bf16x8*)&Ah[row * 40 + cc4 * 8] = pfah[rep];
            } else {
                const float fv[8] = {pfaf[rep][0].x, pfaf[rep][0].y, pfaf[rep][0].z, pfaf[rep][0].w,
                                     pfaf[rep][1].x, pfaf[rep][1].y, pfaf[rep][1].z, pfaf[rep][1].w};
                bf16x8 hi, lo;
#pragma unroll
                for (int j = 0; j < 8; ++j) {
                    const __bf16 h = (__bf16)fv[j];
                    hi[j] = h; lo[j] = (__bf16)(fv[j] - (float)h);
                }
                *(bf16x8*)&Ah[row * 40 + cc4 * 8] = hi;
                *(bf16x8*)&Al[row * 40 + cc4 * 8] = lo;
            }
        }
        {
            const int row = tid >> 2;
            const int cc4 = tid & 3;
            const float fv[8] = {pfb[0].x, pfb[0].y, pfb[0].z, pfb[0].w,
                                 pfb[1].x, pfb[1].y, pfb[1].z, pfb[1].w};
            bf16x8 hi, lo;
#pragma unroll
            for (int j = 0; j < 8; ++j) {
                const __bf16 h = (__bf16)fv[j];
                hi[j] = h;
                if (!BSING) lo[j] = (__bf16)(fv[j] - (float)h);
            }
            *(bf16x8*)&Bh[row * 40 + cc4 * 8] = hi;
            if (!BSING) *(bf16x8*)&Bl[row * 40 + cc4 * 8] = lo;
        }
        __syncthreads();
        if (k0 + 32 < K) loadAB(k0 + 32);

        bf16x8 bh4[4], bl4[4];
#pragma unroll
        for (int n = 0; n < 4; ++n) {
            bh4[n] = *(const bf16x8*)((const char*)&Bh[(wn + n * 16 + fr) * 40] + fkb);
            if (!BSING) bl4[n] = *(const bf16x8*)((const char*)&Bl[(wn + n * 16 + fr) * 40] + fkb);
        }
#pragma unroll
        for (int m = 0; m < 4; ++m) {
            const bf16x8 ah = *(const bf16x8*)((const char*)&Ah[(wm + m * 16 + fr) * 40] + fkb);
            bf16x8 al;
            if (!ABF16) al = *(const bf16x8*)((const char*)&Al[(wm + m * 16 + fr) * 40] + fkb);
#pragma unroll
            for (int n = 0; n < 4; ++n) {
                acc[m][n] = __builtin_amdgcn_mfma_f32_16x16x32_bf16(ah, bh4[n], acc[m][n], 0, 0, 0);
                if (!BSING) acc[m][n] = __builtin_amdgcn_mfma_f32_16x16x32_bf16(ah, bl4[n], acc[m][n], 0, 0, 0);
                if (!ABF16) acc[m][n] = __builtin_amdgcn_mfma_f32_16x16x32_bf16(al, bh4[n], acc[m][n], 0, 0, 0);
            }
        }
    }

    const int lr4 = (lane >> 4) * 4;
#pragma unroll
    for (int m = 0; m < 4; ++m) {
#pragma unroll
        for (int r = 0; r < 4; ++r) {
            const int rr = wm + m * 16 + lr4 + r;
#pragma unroll
            for (int n = 0; n < 4; ++n) {
                const int cc = col0 + wn + n * 16 + fr;
                float v = acc[m][n][r] * scale;
                if (biasp) v += biasb[cc];
                if (ACT == 1) v = 0.5f * v * (1.0f + erff(v * 0.70710678118654752f));
                if (WMUL) v *= wmulp[(long)rr * sWr + z];
                if (OUTH) Ch[(long)z * sCz + (long)rr * sC1 + cc] = (__bf16)v;
                else      Cf[(long)z * sCz + (long)rr * sC1 + cc] = v;
            }
        }
    }
}

// ===================== f32 VALU GEMM (small N only) =====================
#define BM 64
#define BN 64
#define BK 16
__global__ __launch_bounds__(256) void gemm_k(
    const float* __restrict__ Ap, const float* __restrict__ Bp,
    const float* __restrict__ biasp, float* __restrict__ Cp,
    int M, int N, int K, long sA1, long ldb, long sC1)
{
    const int row0 = blockIdx.y * BM;
    const int col0 = blockIdx.x * BN;
    const int tid = threadIdx.x;
    __shared__ float As[BK][BM + 4];
    __shared__ float Bs[BK][BN + 4];
    float acc[4][4] = {};
    const int tm = (tid >> 4) << 2;
    const int tn = (tid & 15) << 2;
    for (int k0 = 0; k0 < K; k0 += BK) {
        {
            const int i = tid << 2;
            const int m = i >> 4, kk = i & 15;
            const int r = row0 + m;
            float4 v = make_float4(0.f, 0.f, 0.f, 0.f);
            if (r < M) v = *(const float4*)(Ap + (long)r * sA1 + k0 + kk);
            As[kk + 0][m] = v.x; As[kk + 1][m] = v.y;
            As[kk + 2][m] = v.z; As[kk + 3][m] = v.w;
        }
        {
            const int i = tid << 2;
            const int n = i >> 4, kk = i & 15;
            const int c = col0 + n;
            float4 v = make_float4(0.f, 0.f, 0.f, 0.f);
            if (c < N) v = *(const float4*)(Bp + (long)c * ldb + k0 + kk);
            Bs[kk + 0][n] = v.x; Bs[kk + 1][n] = v.y;
            Bs[kk + 2][n] = v.z; Bs[kk + 3][n] = v.w;
        }
        __syncthreads();
#pragma unroll
        for (int kk = 0; kk < BK; ++kk) {
            const float4 av = *(const float4*)&As[kk][tm];
            const float4 bv = *(const float4*)&Bs[kk][tn];
            acc[0][0] += av.x * bv.x; acc[0][1] += av.x * bv.y;
            acc[0][2] += av.x * bv.z; acc[0][3] += av.x * bv.w;
            acc[1][0] += av.y * bv.x; acc[1][1] += av.y * bv.y;
            acc[1][2] += av.y * bv.z; acc[1][3] += av.y * bv.w;
            acc[2][0] += av.z * bv.x; acc[2][1] += av.z * bv.y;
            acc[2][2] += av.z * bv.z; acc[2][3] += av.z * bv.w;
            acc[3][0] += av.w * bv.x; acc[3][1] += av.w * bv.y;
            acc[3][2] += av.w * bv.z; acc[3][3] += av.w * bv.w;
        }
        __syncthreads();
    }
#pragma unroll
    for (int i2 = 0; i2 < 4; ++i2) {
        const int r = row0 + tm + i2;
        if (r >= M) continue;
        float* crow = Cp + (long)r * sC1;
#pragma unroll
        for (int j = 0; j < 4; ++j) {
            const int c = col0 + tn + j;
            if (c >= N) continue;
            float v = acc[i2][j];
            if (biasp) v += biasp[c];
            crow[c] = v;
        }
    }
}

static void g_launch(hipStream_t s, const float* A, const float* Bw, const float* bias,
                     float* C, int M, int N, int K, long sA1, long ldb, long sC1)
{
    dim3 grid((N + BN - 1) / BN, (M + BM - 1) / BM, 1);
    gemm_k<<<grid, dim3(256), 0, s>>>(A, Bw, bias, C, M, N, K, sA1, ldb, sC1);
}

// ===================== reduce-act: out[i] = act(sum_z part + bias) ===========
template <int ACT>
__global__ void kred_k(const float* __restrict__ part, const float* __restrict__ bias,
                       float* __restrict__ out, int n, long stride, int nz, int biasMask)
{
    const int i = blockIdx.x * blockDim.x + threadIdx.x;
    if (i >= n) return;
    float v = 0.f;
    for (int z = 0; z < nz; ++z) v += part[(long)z * stride + i];
    if (bias) v += bias[i & biasMask];
    if (ACT == 2) v = 1.0f / (1.0f + expf(-v));
    out[i] = v;
}

// ===================== transpose / copy / bias concat =====================
__global__ void tT_k(const float* __restrict__ src, float* __restrict__ dst, int R, int C)
{
    __shared__ float t[32][33];
    const int c0 = blockIdx.x * 32, r0 = blockIdx.y * 32;
    const int tx = threadIdx.x & 31, ty = threadIdx.x >> 5;
#pragma unroll
    for (int i = 0; i < 4; ++i) {
        const int r = ty + i * 8;
        t[r][tx] = src[(long)(r0 + r) * C + c0 + tx];
    }
    __syncthreads();
#pragma unroll
    for (int i = 0; i < 4; ++i) {
        const int r = ty + i * 8;
        dst[(long)(c0 + r) * R + r0 + tx] = t[tx][r];
    }
}

__global__ void cpy_k(const float* __restrict__ src, float* __restrict__ dst, int n4)
{
    const int i = blockIdx.x * blockDim.x + threadIdx.x;
    if (i < n4) ((float4*)dst)[i] = ((const float4*)src)[i];
}

__global__ void biascat_k(const float* __restrict__ ts_b, const float* __restrict__ ca_b,
                          const float* __restrict__ st_b,
                          const float* __restrict__ ts_ob, const float* __restrict__ ca_ob,
                          const float* __restrict__ st_ob,
                          float* __restrict__ BCAT, float* __restrict__ BKCAT,
                          float* __restrict__ WVB, float* __restrict__ WOB)
{
    const int i = blockIdx.x * blockDim.x + threadIdx.x;
    if (i >= 1024) return;
    BCAT[i] = ts_b[i]; BCAT[1024 + i] = ca_b[i];
    BCAT[2048 + i] = st_b[1024 + i]; BCAT[3072 + i] = st_b[2048 + i];
    BKCAT[i] = ts_b[1024 + i]; BKCAT[1024 + i] = ca_b[1024 + i]; BKCAT[2048 + i] = st_b[i];
    WVB[i] = ts_b[2048 + i]; WVB[1024 + i] = ca_b[2048 + i];
    WOB[i] = ts_ob[i]; WOB[1024 + i] = ca_ob[i]; WOB[2048 + i] = st_ob[i];
}

// ===================== glue kernels =====================
__global__ void headdot3_k(const float* __restrict__ QALL, const float* __restrict__ BKCAT,
                           float* __restrict__ out)
{
    const int idx = blockIdx.x * blockDim.x + threadIdx.x;
    if (idx >= 3 * B_ * T_ * NH_) return;
    const int mod = idx >> 15;
    const int b = (idx >> 7) & 255;
    const int t = (idx >> 3) & 15;
    const int h = idx & 7;
    const float* q = QALL + (long)(b * 16 + t) * 4096 + mod * 1024 + h * 128;
    const float* bb = BKCAT + mod * 1024 + h * 128;
    float sum = 0.f;
    for (int k = 0; k < DH_; ++k) sum += q[k] * bb[k];
    out[idx] = sum;
}

// Fused softmax+pool: one 64-thread block per (mod, b, h).
// mods 0,1: PBAR[mod][b][h][s] = mean_t softmax_s(SC3 row t*8+h)
// mod  2  : ATTM[b][t*8+h]     = mean_s softmax_t(per-column over 16 t's)
__global__ __launch_bounds__(64) void softpb_k(const float* __restrict__ sc3,
                                               float* __restrict__ pbar,
                                               float* __restrict__ attm)
{
    const int blk = blockIdx.x;
    const int h = blk & 7;
    const int b = (blk >> 3) & 255;
    const int mod = blk >> 11;
    const int lane = threadIdx.x;
    const float* base = sc3 + (long)mod * 8388608 + (long)b * 32768 + (long)h * 256;
    float v[16][4];
#pragma unroll
    for (int t = 0; t < 16; ++t) {
        const float* rowp = base + (long)t * 2048;
#pragma unroll
        for (int j = 0; j < 4; ++j) v[t][j] = rowp[j * 64 + lane];
    }
    if (mod < 2) {
        float pb[4] = {0.f, 0.f, 0.f, 0.f};
#pragma unroll
        for (int t = 0; t < 16; ++t) {
            float m = fmaxf(fmaxf(v[t][0], v[t][1]), fmaxf(v[t][2], v[t][3]));
            m = wave_max(m);
            const float e0 = expf(v[t][0] - m), e1 = expf(v[t][1] - m);
            const float e2 = expf(v[t][2] - m), e3 = expf(v[t][3] - m);
            const float inv = 1.f / wave_sum(e0 + e1 + e2 + e3);
            pb[0] += e0 * inv; pb[1] += e1 * inv; pb[2] += e2 * inv; pb[3] += e3 * inv;
        }
        float* pd = pbar + (long)mod * 524288 + (long)b * 2048 + h * 256;
#pragma unroll
        for (int j = 0; j < 4; ++j) pd[j * 64 + lane] = pb[j] * (1.0f / 16.f);
    } else {
        float am[16];
#pragma unroll
        for (int t = 0; t < 16; ++t) am[t] = 0.f;
#pragma unroll
        for (int j = 0; j < 4; ++j) {
            float mx = v[0][j];
#pragma unroll
            for (int t = 1; t < 16; ++t) mx = fmaxf(mx, v[t][j]);
            float e[16];
            float sum = 0.f;
#pragma unroll
            for (int t = 0; t < 16; ++t) { e[t] = expf(v[t][j] - mx); sum += e[t]; }
            const float inv = 1.f / sum;
#pragma unroll
            for (int t = 0; t < 16; ++t) am[t] += e[t] * inv;
        }
#pragma unroll
        for (int t = 0; t < 16; ++t) {
            const float sm = wave_sum(am[t]) * (1.0f / 256.f);
            if (lane == 0) attm[b * 128 + t * 8 + h] = sm;
        }
    }
}

// ctx partial: grid (B, 4); PARTC[sc][mod][b][h][k] = sum over 64-s chunk
__global__ __launch_bounds__(256) void ctxw2_k(const float* __restrict__ pbar,
                                               const float* __restrict__ hs,
                                               float* __restrict__ part)
{
    const int b = blockIdx.x;
    const int sc = blockIdx.y;
    __shared__ float pl[16][64];
    const int tid = threadIdx.x;
    for (int i = tid; i < 16 * 64; i += 256) {
        const int row = i >> 6;                 // mod*8 + h
        const int mod = row >> 3;
        pl[row][i & 63] = pbar[(long)mod * 524288 + (long)b * 2048 +
                               (row & 7) * 256 + sc * 64 + (i & 63)];
    }
    __syncthreads();
    const int k0 = tid * 4;
    float4 acc[16] = {};
    const float* hb = hs + (long)b * S_ * H_ + (long)sc * 64 * H_;
    for (int s = 0; s < 64; ++s) {
        const float4 vv = *(const float4*)(hb + (long)s * H_ + k0);
#pragma unroll
        for (int j = 0; j < 16; ++j) {
            const float p = pl[j][s];
            acc[j].x += p * vv.x; acc[j].y += p * vv.y;
            acc[j].z += p * vv.z; acc[j].w += p * vv.w;
        }
    }
    float* ob = part + (long)sc * 4194304;
#pragma unroll
    for (int j = 0; j < 16; ++j) {
        const int mod = j >> 3, hh = j & 7;
        *(float4*)(ob + (long)mod * 2097152 + (long)b * 8192 + hh * 1024 + k0) = acc[j];
    }
}

__global__ void ohead2_k(const float* __restrict__ attm, const float* __restrict__ QALL,
                         float* __restrict__ outb)
{
    const int idx = blockIdx.x * blockDim.x + threadIdx.x;
    if (idx >= B_ * H_) return;
    const int c = idx & (H_ - 1);
    const int b = idx >> 10;
    float sv = 0.f;
#pragma unroll
    for (int t = 0; t < T_; ++t)
        sv += attm[b * M128_ + t * NH_ + (c >> 7)] * QALL[(long)(b * 16 + t) * 4096 + 3072 + c];
    outb[idx] = sv;
}

__global__ void cat3_k(const float* __restrict__ vs, const float* __restrict__ vt,
                       const float* __restrict__ vo, float* __restrict__ out)
{
    const int idx = blockIdx.x * blockDim.x + threadIdx.x;
    if (idx >= B_ * 3 * H_) return;
    const int k = idx % (3 * H_);
    const int b = idx / (3 * H_);
    float v;
    if (k < H_)          v = vs[b * H_ + k];
    else if (k < 2 * H_) v = vt[b * H_ + k - H_];
    else                 v = vo[b * H_ + k - 2 * H_];
    out[idx] = v;
}

__global__ void ln_k(const float* __restrict__ cat3, const float* __restrict__ g,
                     const float* __restrict__ bta, float* __restrict__ out)
{
    const int b = blockIdx.x;
    const int tid = threadIdx.x;
    __shared__ float buf[3 * H_];
    __shared__ float red[4];
    const float* src = cat3 + (long)b * 3 * H_;
    float sv = 0.f;
    for (int i = tid; i < 3 * H_; i += 256) { const float x = src[i]; buf[i] = x; sv += x; }
    sv = wave_sum(sv);
    if ((tid & 63) == 0) red[tid >> 6] = sv;
    __syncthreads();
    const float mu = (red[0] + red[1] + red[2] + red[3]) * (1.f / (3 * H_));
    __syncthreads();
    float s2 = 0.f;
    for (int i = tid; i < 3 * H_; i += 256) { const float d0 = buf[i] - mu; s2 += d0 * d0; }
    s2 = wave_sum(s2);
    if ((tid & 63) == 0) red[tid >> 6] = s2;
    __syncthreads();
    const float var = (red[0] + red[1] + red[2] + red[3]) * (1.f / (3 * H_));
    const float rstd = rsqrtf(var + 1e-5f);
    float* dst = out + (long)b * 3 * H_;
    for (int i = tid; i < 3 * H_; i += 256)
        dst[i] = (buf[i] - mu) * rstd * g[i] + bta[i];
}

__global__ void mulf_k(const float* __restrict__ a, const float* __restrict__ b2,
                       float* __restrict__ out, int n)
{
    const int idx = blockIdx.x * blockDim.x + threadIdx.x;
    if (idx < n) out[idx] = a[idx] * b2[idx];
}

__global__ void fuse_k(const float* __restrict__ g, const float* __restrict__ flin,
                       const float* __restrict__ bil, float* __restrict__ fused,
                       __bf16* __restrict__ fusedh)
{
    const int idx = blockIdx.x * blockDim.x + threadIdx.x;
    if (idx >= B_ * H_) return;
    const float gg = g[idx];
    const float v = gg * flin[idx] + (1.f - gg) * bil[idx];
    fused[idx] = v;
    fusedh[idx] = (__bf16)v;
}

__global__ void catfv_k(const float* __restrict__ fused, const float* __restrict__ vt,
                        float* __restrict__ out)
{
    const int idx = blockIdx.x * blockDim.x + threadIdx.x;
    if (idx >= B_ * 2 * H_) return;
    const int k = idx % (2 * H_);
    const int b = idx / (2 * H_);
    out[idx] = (k < H_) ? fused[b * H_ + k] : vt[b * H_ + k - H_];
}

__global__ void route_k(const float* __restrict__ glog, float* __restrict__ gp)
{
    const int b = blockIdx.x * blockDim.x + threadIdx.x;
    if (b >= B_) return;
    const float x0 = glog[b * 3], x1 = glog[b * 3 + 1], x2 = glog[b * 3 + 2];
    const float m1 = fmaxf(x0, fmaxf(x1, x2));
    float thr;
    if (x0 == m1)      thr = fmaxf(x1, x2);
    else if (x1 == m1) thr = fmaxf(x0, x2);
    else               thr = fmaxf(x0, x1);
    const float y0 = (x0 >= thr) ? x0 : -1e9f;
    const float y1 = (x1 >= thr) ? x1 : -1e9f;
    const float y2 = (x2 >= thr) ? x2 : -1e9f;
    const float mm = fmaxf(y0, fmaxf(y1, y2));
    const float e0 = expf(y0 - mm), e1 = expf(y1 - mm), e2 = expf(y2 - mm);
    const float inv = 1.f / (e0 + e1 + e2);
    gp[b * 3] = e0 * inv; gp[b * 3 + 1] = e1 * inv; gp[b * 3 + 2] = e2 * inv;
}

__global__ void epsm_k(float* __restrict__ elog, const float* __restrict__ gp)
{
    const int idx = blockIdx.x * blockDim.x + threadIdx.x;
    if (idx >= B_ * G_) return;
    float* p = elog + (long)idx * E_;
    float m = p[0];
#pragma unroll
    for (int e = 1; e < E_; ++e) m = fmaxf(m, p[e]);
    float sum = 0.f;
    float v[E_];
#pragma unroll
    for (int e = 0; e < E_; ++e) { v[e] = expf(p[e] - m); sum += v[e]; }
    const float w = gp[idx] / sum;
#pragma unroll
    for (int e = 0; e < E_; ++e) p[e] = v[e] * w;
}

__global__ void moefinal_k(const float* __restrict__ part, const float* __restrict__ fused,
                           const float* __restrict__ wsc, const float* __restrict__ e_b2,
                           float* __restrict__ res)
{
    const int idx = blockIdx.x * blockDim.x + threadIdx.x;
    if (idx >= B_ * H_) return;
    const int b = idx >> 10;
    const int h = idx & (H_ - 1);
    float acc = fused[idx];
#pragma unroll 8
    for (int z = 0; z < 48; ++z) acc += part[(long)z * (B_ * H_) + idx];
    float ba = 0.f;
#pragma unroll
    for (int ge = 0; ge < GE_; ++ge) ba += wsc[b * GE_ + ge] * e_b2[ge * H_ + h];
    res[idx] = acc + ba;
}

// ===================== entry =====================
extern "C" void kernel_launch(void* const* d_in, const int* in_sizes, int n_in,
                              void* d_out, int out_size, void* d_ws, size_t ws_size,
                              hipStream_t stream)
{
    const float* h_sent  = (const float*)d_in[0];
    const float* h_term  = (const float*)d_in[1];
    const float* ts_in_w = (const float*)d_in[2];
    const float* ts_out_w= (const float*)d_in[3];
    const float* st_in_w = (const float*)d_in[4];
    const float* st_out_w= (const float*)d_in[5];
    const float* ca_in_w = (const float*)d_in[6];
    const float* ca_out_w= (const float*)d_in[7];
    const float* opq_w   = (const float*)d_in[8];
    const float* fuse_w  = (const float*)d_in[9];
    const float* gate_w  = (const float*)d_in[10];
    const float* bs_w    = (const float*)d_in[11];
    const float* bt_w    = (const float*)d_in[12];
    const float* bo_w    = (const float*)d_in[13];
    const float* cond_w  = (const float*)d_in[14];
    const float* gr_w    = (const float*)d_in[15];
    const float* er_w    = (const float*)d_in[16];
    const float* e_w1    = (const float*)d_in[17];
    const float* e_w2    = (const float*)d_in[18];
    const float* cls_w   = (const float*)d_in[19];
    const float* ts_in_b = (const float*)d_in[20];
    const float* ts_out_b= (const float*)d_in[21];
    const float* st_in_b = (const float*)d_in[22];
    const float* st_out_b= (const float*)d_in[23];
    const float* ca_in_b = (const float*)d_in[24];
    const float* ca_out_b= (const float*)d_in[25];
    const float* fuse_b  = (const float*)d_in[26];
    const float* gate_b  = (const float*)d_in[27];
    const float* bs_b    = (const float*)d_in[28];
    const float* bt_b    = (const float*)d_in[29];
    const float* bo_b    = (const float*)d_in[30];
    const float* cond_b  = (const float*)d_in[31];
    const float* gr_b    = (const float*)d_in[32];
    const float* er_b    = (const float*)d_in[33];
    const float* e_b1    = (const float*)d_in[34];
    const float* e_b2    = (const float*)d_in[35];
    const float* cls_b   = (const float*)d_in[36];
    const float* ln_b    = (const float*)d_in[37];
    const float* ln_g    = (const float*)d_in[38];
    (void)in_sizes; (void)n_in; (void)out_size; (void)ws_size;

    float* ws = (float*)d_ws;
    size_t off = 0;
    auto allocF = [&](size_t n) { float* p = ws + off; off += (n + 63) & ~(size_t)63; return p; };

    float* QALL  = allocF(16777216);  // [B*T][4096]
    float* WCAT  = allocF(4194304);
    float* BCAT  = allocF(4096);
    float* BKCAT = allocF(3072);
    float* wT3   = allocF(3145728);
    float* opqT  = allocF(1048576);
    float* WVCAT = allocF(2097152);
    float* WVB   = allocF(2048);
    float* WOCAT = allocF(3145728);
    float* WOB   = allocF(3072);
    float* OFFS3 = allocF(98304);
    float* BIG3  = allocF(100663296); // [3][B][128][H]
    float* SC3   = allocF(25165824);  // [3][B][128][S]
    float* PBAR3 = allocF(1048576);   // [2][B][8][S]
    float* CTXB3 = allocF(4194304);   // [2][B][8][H]
    float* PARTC = allocF(16777216);  // [4] ctx partials
    float* OBAR3 = allocF(786432);
    float* VOUT3 = allocF(786432);
    float* ATTM  = allocF(32768);
    float* CAT3  = allocF(786432);
    float* LNC   = allocF(786432);
    float* FLIN  = allocF(262144);
    float* GATE  = allocF(262144);
    float* BSV   = allocF(65536);
    float* BTV   = allocF(65536);
    float* PROD  = allocF(65536);
    float* BIL   = allocF(262144);
    float* FUSED = allocF(262144);
    float* FUSEDH= allocF(131072);
    float* CATFV = allocF(524288);
    float* COND  = allocF(262144);
    float* GLOG  = allocF(1024);
    float* GP    = allocF(1024);
    float* ELOG  = allocF(8192);
    float* RES   = allocF(262144);
    float* PARTF = allocF(1048576);   // k-split partials (<= 4 x 262144)
    float* H1Wf  = allocF(12582912);
    float* PART  = allocF(12582912);
    __bf16* FUSEDbf = (__bf16*)FUSEDH;
    __bf16* H1W     = (__bf16*)H1Wf;
    float* VTERM = VOUT3;
    float* VOP   = VOUT3 + 262144;
    float* VSENT = VOUT3 + 524288;

    hipStream_t s = stream;
    const float rscale = 0.08838834764831845f;

    // ---------- precompute ----------
    cpy_k<<<dim3(1024), dim3(256), 0, s>>>(ts_in_w, WCAT, 262144);
    cpy_k<<<dim3(1024), dim3(256), 0, s>>>(st_in_w + 1048576, WCAT + 2097152, 262144);
    cpy_k<<<dim3(1024), dim3(256), 0, s>>>(st_in_w + 2097152, WCAT + 3145728, 262144);
    cpy_k<<<dim3(1024), dim3(256), 0, s>>>(ts_in_w + 2097152, WVCAT, 262144);
    cpy_k<<<dim3(1024), dim3(256), 0, s>>>(ca_in_w + 2097152, WVCAT + 1048576, 262144);
    cpy_k<<<dim3(1024), dim3(256), 0, s>>>(ts_out_w, WOCAT, 262144);
    cpy_k<<<dim3(1024), dim3(256), 0, s>>>(ca_out_w, WOCAT + 1048576, 262144);
    cpy_k<<<dim3(1024), dim3(256), 0, s>>>(st_out_w, WOCAT + 2097152, 262144);
    biascat_k<<<dim3(4), dim3(256), 0, s>>>(ts_in_b, ca_in_b, st_in_b,
                                            ts_out_b, ca_out_b, st_out_b,
                                            BCAT, BKCAT, WVB, WOB);
    tT_k<<<dim3(32, 32), dim3(256), 0, s>>>(ts_in_w + 1048576, wT3, 1024, 1024);
    tT_k<<<dim3(32, 32), dim3(256), 0, s>>>(ca_in_w + 1048576, wT3 + 1048576, 1024, 1024);
    tT_k<<<dim3(32, 32), dim3(256), 0, s>>>(st_in_w, wT3 + 2097152, 1024, 1024);
    tT_k<<<dim3(32, 32), dim3(256), 0, s>>>(opq_w, opqT, 1024, 1024);

    // Wcomb_ca = Wq_ca @ opq_w
    sg2(s, 0, ca_in_w, opqT, nullptr, nullptr, WCAT + 1048576,
        8, 8, 1, 1024, 12, 0, 0, 1024, 0, 0, 1024, 0, 0, 0, 0,
        0, 1024, 0, 0, 0, 0, 1.f);

    // QALL
    sg2(s, 0, h_term, WCAT, BCAT, nullptr, QALL,
        32, 32, 1, 1024, 12, 0, 0, 1024, 0, 0, 1024, 0, 0, 0, 0,
        0, 4096, 0, 0, 0, 0, 1.f);

    headdot3_k<<<dim3(384), dim3(256), 0, s>>>(QALL, BKCAT, OFFS3);

    // A-fold z=24
    sg2(s, 0, QALL, wT3, nullptr, nullptr, BIG3,
        8, 32, 24, 128, 4, 3,
        65536, 4096, 1024, 128,
        1024, 1048576, 128, 0, 0,
        131072, 8192, 33554432, 1024, 0, 0, 1.f);

    // scores z=768
    sg2(s, 0, BIG3, h_sent, nullptr, OFFS3, SC3,
        2, 1, 768, 1024, 12, 8,
        0, 1024, 33554432, 131072,
        1024, 0, 262144, 0, 0,
        0, 256, 8388608, 32768, 32768, 128, rscale);

    // fused softmax + pool
    softpb_k<<<dim3(3 * B_ * NH_), dim3(64), 0, s>>>(SC3, PBAR3, ATTM);

    // ctx weighted sum (s-split x4) + reduce
    ctxw2_k<<<dim3(B_, 4), dim3(256), 0, s>>>(PBAR3, h_sent, PARTC);
    kred_k<0><<<dim3(4194304 / 256), dim3(256), 0, s>>>(PARTC, nullptr, CTXB3,
                                                        4194304, 4194304, 4, 0);
    // ctx V-proj z=16
    sg2(s, 0, CTXB3, WVCAT, WVB, nullptr, OBAR3,
        1, 2, 16, 1024, 12, 3,
        0, 8192, 2097152, 1024,
        1024, 1048576, 131072, 1024, 128,
        0, 1024, 262144, 128, 0, 0, 1.f);

    // st path
    ohead2_k<<<dim3((B_ * H_ + 255) / 256), dim3(256), 0, s>>>(ATTM, QALL, OBAR3 + 524288);

    // out-proj z=3
    sg2(s, 0, OBAR3, WOCAT, WOB, nullptr, VOUT3,
        8, 2, 3, 1024, 12, 0,
        0, 1024, 262144, 0,
        1024, 1048576, 0, 1024, 0,
        0, 1024, 262144, 0, 0, 0, 1.f);

    // ---------- fusion head ----------
    cat3_k<<<dim3((B_ * 3 * H_ + 255) / 256), dim3(256), 0, s>>>(VSENT, VTERM, VOP, CAT3);
    ln_k<<<dim3(B_), dim3(256), 0, s>>>(CAT3, ln_g, ln_b, LNC);
    // FLIN: k-split x4 (K=3072 -> 768)
    sg2(s, 0, LNC, fuse_w, nullptr, nullptr, PARTF,
        8, 2, 4, 768, 12, 2, 0, 3072, 0, 768, 3072, 0, 768, 0, 0,
        0, 1024, 0, 262144, 0, 0, 1.f);
    kred_k<0><<<dim3(1024), dim3(256), 0, s>>>(PARTF, fuse_b, FLIN, 262144, 262144, 4, 1023);
    // GATE: k-split x4 + sigmoid in reduce
    sg2(s, 0, CAT3, gate_w, nullptr, nullptr, PARTF,
        8, 2, 4, 768, 12, 2, 0, 3072, 0, 768, 3072, 0, 768, 0, 0,
        0, 1024, 0, 262144, 0, 0, 1.f);
    kred_k<2><<<dim3(1024), dim3(256), 0, s>>>(PARTF, gate_b, GATE, 262144, 262144, 4, 1023);
    // BSV / BTV: k-split x4 (K=1024 -> 256)
    sg2(s, 0, VSENT, bs_w, nullptr, nullptr, PARTF,
        2, 2, 4, 256, 12, 2, 0, 1024, 0, 256, 1024, 0, 256, 0, 0,
        0, 256, 0, 65536, 0, 0, 1.f);
    kred_k<0><<<dim3(256), dim3(256), 0, s>>>(PARTF, bs_b, BSV, 65536, 65536, 4, 255);
    sg2(s, 0, VTERM, bt_w, nullptr, nullptr, PARTF,
        2, 2, 4, 256, 12, 2, 0, 1024, 0, 256, 1024, 0, 256, 0, 0,
        0, 256, 0, 65536, 0, 0, 1.f);
    kred_k<0><<<dim3(256), dim3(256), 0, s>>>(PARTF, bt_b, BTV, 65536, 65536, 4, 255);
    mulf_k<<<dim3((B_ * R_ + 255) / 256), dim3(256), 0, s>>>(BSV, BTV, PROD, B_ * R_);
    // BIL: k-split x2 (K=256 -> 128)
    sg2(s, 0, PROD, bo_w, nullptr, nullptr, PARTF,
        8, 2, 2, 128, 12, 1, 0, 256, 0, 128, 256, 0, 128, 0, 0,
        0, 1024, 0, 262144, 0, 0, 1.f);
    kred_k<0><<<dim3(1024), dim3(256), 0, s>>>(PARTF, bo_b, BIL, 262144, 262144, 2, 1023);
    fuse_k<<<dim3((B_ * H_ + 255) / 256), dim3(256), 0, s>>>(GATE, FLIN, BIL, FUSED, FUSEDbf);
    catfv_k<<<dim3((B_ * 2 * H_ + 255) / 256), dim3(256), 0, s>>>(FUSED, VTERM, CATFV);
    // COND: k-split x4 (K=2048 -> 512)
    sg2(s, 0, CATFV, cond_w, nullptr, nullptr, PARTF,
        8, 2, 4, 512, 12, 2, 0, 2048, 0, 512, 2048, 0, 512, 0, 0,
        0, 1024, 0, 262144, 0, 0, 1.f);
    kred_k<0><<<dim3(1024), dim3(256), 0, s>>>(PARTF, cond_b, COND, 262144, 262144, 4, 1023);

    // ---------- routing ----------
    g_launch(s, FUSED, gr_w, gr_b, GLOG, B_, G_, H_, H_, H_, G_);
    route_k<<<dim3(1), dim3(256), 0, s>>>(GLOG, GP);
    g_launch(s, COND, er_w, er_b, ELOG, B_, GE_, H_, H_, H_, GE_);
    epsm_k<<<dim3(3), dim3(256), 0, s>>>(ELOG, GP);

    // ---------- MoE ----------
    sgemm256_k<1, 1, 1, 1, 1><<<dim3(I_ / 128, 1, GE_), dim3(512), 0, s>>>(
        FUSEDbf, e_w1, e_b1, ELOG, nullptr, H1W,
        1024, H_, 0, H_, (long)I_ * H_, 0, 0, I_,
        (long)GE_ * I_, I_, GE_, 1.f);
    sgemm256_k<1, 1, 0, 0, 0><<<dim3(H_ / 128, 1, 2 * GE_), dim3(512), 0, s>>>(
        H1W, e_w2, nullptr, nullptr, PART, nullptr,
        2048, (long)GE_ * I_, 2048, I_, (long)H_ * I_, 2048, 1, 0,
        H_, (long)B_ * H_, 0, 1.f);
    moefinal_k<<<dim3(B_ * H_ / 256), dim3(256), 0, s>>>(PART, FUSED, ELOG, e_b2, RES);

    // ---------- classifier ----------
    g_launch(s, RES, cls_w, cls_b, (float*)d_out, B_, L_, H_, H_, H_, L_);
}

// Round 8
// 1627.333 us; speedup vs baseline: 3.3338x; 1.0053x over previous
//
#include <hip/hip_runtime.h>
#include <math.h>

// ---------------------------------------------------------------------------
// HAGMoE — round 8: memory-locality pass on the scores GEMM.
//  * scores: gx=1, in-block col-half loop (NCH=2) -> A-tile (BIG3) second read
//    is an L2 hit instead of a second HBM fetch (805 -> 402 MB).
//  * scores z-order: z = b*4 + mod (dummy mod=3 exits) -> the 3 mods sharing
//    h_sent[b] dispatch adjacently -> L3/L2 temporal locality.
//  * merged setup copies/transposes (launch overhead trim).
// Precision rule unchanged: pre-routing split-bf16 (f32-grade); post-routing
// single-bf16. All partial sums f32.
// ---------------------------------------------------------------------------

#define B_    256
#define S_    256
#define T_    16
#define H_    1024
#define NH_   8
#define DH_   128
#define M128_ 128
#define G_    3
#define E_    8
#define I_    4096
#define R_    256
#define L_    3
#define GE_   24

using bf16x8 = __attribute__((ext_vector_type(8))) __bf16;
using f32x4  = __attribute__((ext_vector_type(4))) float;

__device__ inline float wave_sum(float v) {
    for (int o = 32; o > 0; o >>= 1) v += __shfl_xor(v, o);
    return v;
}
__device__ inline float wave_max(float v) {
    for (int o = 32; o > 0; o >>= 1) v = fmaxf(v, __shfl_xor(v, o));
    return v;
}

// ===================== split-bf16 MFMA GEMM, 128x128, prefetched =============
// NCH col-halves per block (A-tile L2 reuse). z2 >= z2max -> dummy block exit.
template <int ACT, int NCH>
__global__ __launch_bounds__(256) void sgemm2_k(
    const float* __restrict__ Ap, const float* __restrict__ Bp,
    const float* __restrict__ biasp, const float* __restrict__ roffp,
    float* __restrict__ Cf,
    int K, int m2shift, int zshift, int z2max,
    long sA1, long sA2, long sAz1, long sAz2,
    long ldb, long sBz1, long sBz2, long sBia1, long sBia2,
    long sC1, long sC2, long sCz1, long sCz2, long sR1, long sR2,
    float scale)
{
    const int z  = blockIdx.z;
    const int z1 = z >> zshift;
    const int z2 = z & ((1 << zshift) - 1);
    if (z2 >= z2max) return;
    const int m2mask = (1 << m2shift) - 1;
    const int row0 = blockIdx.y * 128;
    const float* Ab = Ap + (long)z1 * sAz1 + (long)z2 * sAz2;
    const float* Bb = Bp + (long)z1 * sBz1 + (long)z2 * sBz2;
    const float* biasb = biasp ? biasp + (long)z1 * sBia1 + (long)z2 * sBia2 : nullptr;
    const float* roffb = roffp ? roffp + (long)z1 * sR1 + (long)z2 * sR2 : nullptr;

    __shared__ __bf16 Ahs[128 * 40];
    __shared__ __bf16 Als[128 * 40];
    __shared__ __bf16 Bhs[128 * 40];
    __shared__ __bf16 Bls[128 * 40];

    const int tid  = threadIdx.x;
    const int lane = tid & 63;
    const int wid  = tid >> 6;
    const int wm = (wid >> 1) * 64;
    const int wn = (wid & 1) * 64;
    const int fr  = lane & 15;
    const int fkb = (lane >> 4) * 16;
    const int qrow = tid >> 2;
    const int c4   = tid & 3;

    float4 pfa[2][2], pfb[2][2];

    auto loadAB = [&](int k0, int col0) {
#pragma unroll
        for (int rep = 0; rep < 2; ++rep) {
            const int row = qrow + rep * 64;
            const int r = row0 + row;
            const int r1 = r >> m2shift, r2 = r & m2mask;
            const float* srcA = Ab + (long)r1 * sA1 + (long)r2 * sA2 + k0 + c4 * 8;
            pfa[rep][0] = *(const float4*)srcA;
            pfa[rep][1] = *(const float4*)(srcA + 4);
            const float* srcB = Bb + (long)(col0 + row) * ldb + k0 + c4 * 8;
            pfb[rep][0] = *(const float4*)srcB;
            pfb[rep][1] = *(const float4*)(srcB + 4);
        }
    };

    for (int ch = 0; ch < NCH; ++ch) {
        const int col0 = (blockIdx.x * NCH + ch) * 128;
        f32x4 acc[4][4] = {};
        loadAB(0, col0);
        for (int k0 = 0; k0 < K; k0 += 32) {
            __syncthreads();
#pragma unroll
            for (int rep = 0; rep < 2; ++rep) {
                const int row = qrow + rep * 64;
                {
                    const float fv[8] = {pfa[rep][0].x, pfa[rep][0].y, pfa[rep][0].z, pfa[rep][0].w,
                                         pfa[rep][1].x, pfa[rep][1].y, pfa[rep][1].z, pfa[rep][1].w};
                    bf16x8 hi, lo;
#pragma unroll
                    for (int j = 0; j < 8; ++j) {
                        const __bf16 h = (__bf16)fv[j];
                        hi[j] = h; lo[j] = (__bf16)(fv[j] - (float)h);
                    }
                    *(bf16x8*)&Ahs[row * 40 + c4 * 8] = hi;
                    *(bf16x8*)&Als[row * 40 + c4 * 8] = lo;
                }
                {
                    const float fv[8] = {pfb[rep][0].x, pfb[rep][0].y, pfb[rep][0].z, pfb[rep][0].w,
                                         pfb[rep][1].x, pfb[rep][1].y, pfb[rep][1].z, pfb[rep][1].w};
                    bf16x8 hi, lo;
#pragma unroll
                    for (int j = 0; j < 8; ++j) {
                        const __bf16 h = (__bf16)fv[j];
                        hi[j] = h; lo[j] = (__bf16)(fv[j] - (float)h);
                    }
                    *(bf16x8*)&Bhs[row * 40 + c4 * 8] = hi;
                    *(bf16x8*)&Bls[row * 40 + c4 * 8] = lo;
                }
            }
            __syncthreads();
            if (k0 + 32 < K) loadAB(k0 + 32, col0);

            bf16x8 bh4[4], bl4[4];
#pragma unroll
            for (int n = 0; n < 4; ++n) {
                bh4[n] = *(const bf16x8*)((const char*)&Bhs[(wn + n * 16 + fr) * 40] + fkb);
                bl4[n] = *(const bf16x8*)((const char*)&Bls[(wn + n * 16 + fr) * 40] + fkb);
            }
#pragma unroll
            for (int m = 0; m < 4; ++m) {
                const bf16x8 ah = *(const bf16x8*)((const char*)&Ahs[(wm + m * 16 + fr) * 40] + fkb);
                const bf16x8 al = *(const bf16x8*)((const char*)&Als[(wm + m * 16 + fr) * 40] + fkb);
#pragma unroll
                for (int n = 0; n < 4; ++n) {
                    acc[m][n] = __builtin_amdgcn_mfma_f32_16x16x32_bf16(ah, bh4[n], acc[m][n], 0, 0, 0);
                    acc[m][n] = __builtin_amdgcn_mfma_f32_16x16x32_bf16(ah, bl4[n], acc[m][n], 0, 0, 0);
                    acc[m][n] = __builtin_amdgcn_mfma_f32_16x16x32_bf16(al, bh4[n], acc[m][n], 0, 0, 0);
                }
            }
        }

        float* Cfb = Cf + (long)z1 * sCz1 + (long)z2 * sCz2;
        const int lr4 = (lane >> 4) * 4;
#pragma unroll
        for (int m = 0; m < 4; ++m) {
#pragma unroll
            for (int r = 0; r < 4; ++r) {
                const int rr = row0 + wm + m * 16 + lr4 + r;
                const int r1 = rr >> m2shift, r2 = rr & m2mask;
                const float ro = roffb ? roffb[rr] : 0.f;
                const long cb = (long)r1 * sC1 + (long)r2 * sC2;
#pragma unroll
                for (int n = 0; n < 4; ++n) {
                    const int cc = col0 + wn + n * 16 + fr;
                    float v = (acc[m][n][r] + ro) * scale;
                    if (biasp) v += biasb[cc];
                    if (ACT == 2) v = 1.0f / (1.0f + expf(-v));
                    Cfb[cb + cc] = v;
                }
            }
        }
    }
}

static void sg2(hipStream_t s, int act, int nch, int z2max,
                const float* A, const float* B, const float* bias, const float* roff,
                float* C, int gx, int gy, int gz,
                int K, int m2shift, int zshift,
                long sA1, long sA2, long sAz1, long sAz2,
                long ldb, long sBz1, long sBz2, long sBia1, long sBia2,
                long sC1, long sC2, long sCz1, long sCz2, long sR1, long sR2,
                float scale)
{
    dim3 g(gx, gy, gz), b(256);
#define S2ARGS A, B, bias, roff, C, K, m2shift, zshift, z2max, sA1, sA2, sAz1, sAz2, \
               ldb, sBz1, sBz2, sBia1, sBia2, sC1, sC2, sCz1, sCz2, sR1, sR2, scale
    if (nch == 2)      sgemm2_k<0, 2><<<g, b, 0, s>>>(S2ARGS);
    else if (act == 2) sgemm2_k<2, 1><<<g, b, 0, s>>>(S2ARGS);
    else               sgemm2_k<0, 1><<<g, b, 0, s>>>(S2ARGS);
#undef S2ARGS
}

// ===================== 256x128 MFMA GEMM (MoE), prefetched =====================
template <int ABF16, int BSING, int ACT, int WMUL, int OUTH>
__global__ __launch_bounds__(512) void sgemm256_k(
    const void* __restrict__ Ap, const float* __restrict__ Bp,
    const float* __restrict__ biasp, const float* __restrict__ wmulp,
    float* __restrict__ Cf, __bf16* __restrict__ Ch,
    int K, long sA1, long sAz, long ldb, long sBz, long sBz2, int bzshift,
    long sBias, long sC1, long sCz, long sWr, float scale)
{
    const int z    = blockIdx.z;
    const int col0 = blockIdx.x * 128;
    const int z1 = z >> bzshift;
    const int z2 = z - (z1 << bzshift);
    const float* Bb = Bp + (long)z1 * sBz + (long)z2 * sBz2;
    const float* biasb = biasp ? biasp + (long)z1 * sBias : nullptr;

    __shared__ __bf16 Ah[256 * 40];
    __shared__ __bf16 Al[ABF16 ? 64 : 256 * 40];
    __shared__ __bf16 Bh[128 * 40];
    __shared__ __bf16 Bl[BSING ? 64 : 128 * 40];

    const int tid  = threadIdx.x;
    const int lane = tid & 63;
    const int wid  = tid >> 6;
    const int wm = (wid >> 1) * 64;
    const int wn = (wid & 1) * 64;
    const int fr  = lane & 15;
    const int fkb = (lane >> 4) * 16;

    f32x4 acc[4][4] = {};
    bf16x8 pfah[2];
    float4 pfaf[2][2];
    float4 pfb[2];

    auto loadAB = [&](int k0) {
#pragma unroll
        for (int rep = 0; rep < 2; ++rep) {
            const int idx = tid + rep * 512;
            const int row = idx >> 2;
            const int cc4 = idx & 3;
            if (ABF16) {
                pfah[rep] = *(const bf16x8*)((const __bf16*)Ap + (long)z * sAz +
                                             (long)row * sA1 + k0 + cc4 * 8);
            } else {
                const float* src = (const float*)Ap + (long)z * sAz +
                                   (long)row * sA1 + k0 + cc4 * 8;
                pfaf[rep][0] = *(const float4*)src;
                pfaf[rep][1] = *(const float4*)(src + 4);
            }
        }
        {
            const int row = tid >> 2;
            const int cc4 = tid & 3;
            const float* src = Bb + (long)(col0 + row) * ldb + k0 + cc4 * 8;
            pfb[0] = *(const float4*)src;
            pfb[1] = *(const float4*)(src + 4);
        }
    };

    loadAB(0);
    for (int k0 = 0; k0 < K; k0 += 32) {
        __syncthreads();
#pragma unroll
        for (int rep = 0; rep < 2; ++rep) {
            const int idx = tid + rep * 512;
            const int row = idx >> 2;
            const int cc4 = idx & 3;
            if (ABF16) {
                *(bf16x8*)&Ah[row * 40 + cc4 * 8] = pfah[rep];
            } else {
                const float fv[8] = {pfaf[rep][0].x, pfaf[rep][0].y, pfaf[rep][0].z, pfaf[rep][0].w,
                                     pfaf[rep][1].x, pfaf[rep][1].y, pfaf[rep][1].z, pfaf[rep][1].w};
                bf16x8 hi, lo;
#pragma unroll
                for (int j = 0; j < 8; ++j) {
                    const __bf16 h = (__bf16)fv[j];
                    hi[j] = h; lo[j] = (__bf16)(fv[j] - (float)h);
                }
                *(bf16x8*)&Ah[row * 40 + cc4 * 8] = hi;
                *(bf16x8*)&Al[row * 40 + cc4 * 8] = lo;
            }
        }
        {
            const int row = tid >> 2;
            const int cc4 = tid & 3;
            const float fv[8] = {pfb[0].x, pfb[0].y, pfb[0].z, pfb[0].w,
                                 pfb[1].x, pfb[1].y, pfb[1].z, pfb[1].w};
            bf16x8 hi, lo;
#pragma unroll
            for (int j = 0; j < 8; ++j) {
                const __bf16 h = (__bf16)fv[j];
                hi[j] = h;
                if (!BSING) lo[j] = (__bf16)(fv[j] - (float)h);
            }
            *(bf16x8*)&Bh[row * 40 + cc4 * 8] = hi;
            if (!BSING) *(bf16x8*)&Bl[row * 40 + cc4 * 8] = lo;
        }
        __syncthreads();
        if (k0 + 32 < K) loadAB(k0 + 32);

        bf16x8 bh4[4], bl4[4];
#pragma unroll
        for (int n = 0; n < 4; ++n) {
            bh4[n] = *(const bf16x8*)((const char*)&Bh[(wn + n * 16 + fr) * 40] + fkb);
            if (!BSING) bl4[n] = *(const bf16x8*)((const char*)&Bl[(wn + n * 16 + fr) * 40] + fkb);
        }
#pragma unroll
        for (int m = 0; m < 4; ++m) {
            const bf16x8 ah = *(const bf16x8*)((const char*)&Ah[(wm + m * 16 + fr) * 40] + fkb);
            bf16x8 al;
            if (!ABF16) al = *(const bf16x8*)((const char*)&Al[(wm + m * 16 + fr) * 40] + fkb);
#pragma unroll
            for (int n = 0; n < 4; ++n) {
                acc[m][n] = __builtin_amdgcn_mfma_f32_16x16x32_bf16(ah, bh4[n], acc[m][n], 0, 0, 0);
                if (!BSING) acc[m][n] = __builtin_amdgcn_mfma_f32_16x16x32_bf16(ah, bl4[n], acc[m][n], 0, 0, 0);
                if (!ABF16) acc[m][n] = __builtin_amdgcn_mfma_f32_16x16x32_bf16(al, bh4[n], acc[m][n], 0, 0, 0);
            }
        }
    }

    const int lr4 = (lane >> 4) * 4;
#pragma unroll
    for (int m = 0; m < 4; ++m) {
#pragma unroll
        for (int r = 0; r < 4; ++r) {
            const int rr = wm + m * 16 + lr4 + r;
#pragma unroll
            for (int n = 0; n < 4; ++n) {
                const int cc = col0 + wn + n * 16 + fr;
                float v = acc[m][n][r] * scale;
                if (biasp) v += biasb[cc];
                if (ACT == 1) v = 0.5f * v * (1.0f + erff(v * 0.70710678118654752f));
                if (WMUL) v *= wmulp[(long)rr * sWr + z];
                if (OUTH) Ch[(long)z * sCz + (long)rr * sC1 + cc] = (__bf16)v;
                else      Cf[(long)z * sCz + (long)rr * sC1 + cc] = v;
            }
        }
    }
}

// ===================== f32 VALU GEMM (small N only) =====================
#define BM 64
#define BN 64
#define BK 16
__global__ __launch_bounds__(256) void gemm_k(
    const float* __restrict__ Ap, const float* __restrict__ Bp,
    const float* __restrict__ biasp, float* __restrict__ Cp,
    int M, int N, int K, long sA1, long ldb, long sC1)
{
    const int row0 = blockIdx.y * BM;
    const int col0 = blockIdx.x * BN;
    const int tid = threadIdx.x;
    __shared__ float As[BK][BM + 4];
    __shared__ float Bs[BK][BN + 4];
    float acc[4][4] = {};
    const int tm = (tid >> 4) << 2;
    const int tn = (tid & 15) << 2;
    for (int k0 = 0; k0 < K; k0 += BK) {
        {
            const int i = tid << 2;
            const int m = i >> 4, kk = i & 15;
            const int r = row0 + m;
            float4 v = make_float4(0.f, 0.f, 0.f, 0.f);
            if (r < M) v = *(const float4*)(Ap + (long)r * sA1 + k0 + kk);
            As[kk + 0][m] = v.x; As[kk + 1][m] = v.y;
            As[kk + 2][m] = v.z; As[kk + 3][m] = v.w;
        }
        {
            const int i = tid << 2;
            const int n = i >> 4, kk = i & 15;
            const int c = col0 + n;
            float4 v = make_float4(0.f, 0.f, 0.f, 0.f);
            if (c < N) v = *(const float4*)(Bp + (long)c * ldb + k0 + kk);
            Bs[kk + 0][n] = v.x; Bs[kk + 1][n] = v.y;
            Bs[kk + 2][n] = v.z; Bs[kk + 3][n] = v.w;
        }
        __syncthreads();
#pragma unroll
        for (int kk = 0; kk < BK; ++kk) {
            const float4 av = *(const float4*)&As[kk][tm];
            const float4 bv = *(const float4*)&Bs[kk][tn];
            acc[0][0] += av.x * bv.x; acc[0][1] += av.x * bv.y;
            acc[0][2] += av.x * bv.z; acc[0][3] += av.x * bv.w;
            acc[1][0] += av.y * bv.x; acc[1][1] += av.y * bv.y;
            acc[1][2] += av.y * bv.z; acc[1][3] += av.y * bv.w;
            acc[2][0] += av.z * bv.x; acc[2][1] += av.z * bv.y;
            acc[2][2] += av.z * bv.z; acc[2][3] += av.z * bv.w;
            acc[3][0] += av.w * bv.x; acc[3][1] += av.w * bv.y;
            acc[3][2] += av.w * bv.z; acc[3][3] += av.w * bv.w;
        }
        __syncthreads();
    }
#pragma unroll
    for (int i2 = 0; i2 < 4; ++i2) {
        const int r = row0 + tm + i2;
        if (r >= M) continue;
        float* crow = Cp + (long)r * sC1;
#pragma unroll
        for (int j = 0; j < 4; ++j) {
            const int c = col0 + tn + j;
            if (c >= N) continue;
            float v = acc[i2][j];
            if (biasp) v += biasp[c];
            crow[c] = v;
        }
    }
}

static void g_launch(hipStream_t s, const float* A, const float* Bw, const float* bias,
                     float* C, int M, int N, int K, long sA1, long ldb, long sC1)
{
    dim3 grid((N + BN - 1) / BN, (M + BM - 1) / BM, 1);
    gemm_k<<<grid, dim3(256), 0, s>>>(A, Bw, bias, C, M, N, K, sA1, ldb, sC1);
}

// ===================== reduce-act =====================
template <int ACT>
__global__ void kred_k(const float* __restrict__ part, const float* __restrict__ bias,
                       float* __restrict__ out, int n, long stride, int nz, int biasMask)
{
    const int i = blockIdx.x * blockDim.x + threadIdx.x;
    if (i >= n) return;
    float v = 0.f;
    for (int z = 0; z < nz; ++z) v += part[(long)z * stride + i];
    if (bias) v += bias[i & biasMask];
    if (ACT == 2) v = 1.0f / (1.0f + expf(-v));
    out[i] = v;
}

// ===================== merged setup: 8 copies in one launch =====================
__global__ void cpy8_k(const float* s0, const float* s1, const float* s2, const float* s3,
                       const float* s4, const float* s5, const float* s6, const float* s7,
                       float* d0, float* d1, float* d2, float* d3,
                       float* d4, float* d5, float* d6, float* d7)
{
    const int seg = blockIdx.x >> 10;
    const int i = ((blockIdx.x & 1023) * 256 + threadIdx.x);
    const float* srcs[8] = {s0, s1, s2, s3, s4, s5, s6, s7};
    float* dsts[8] = {d0, d1, d2, d3, d4, d5, d6, d7};
    ((float4*)dsts[seg])[i] = ((const float4*)srcs[seg])[i];
}

// 4 transposes (1024x1024 each) in one launch
__global__ void tT4_k(const float* s0, const float* s1, const float* s2, const float* s3,
                      float* d0, float* d1, float* d2, float* d3)
{
    __shared__ float t[32][33];
    const int seg = blockIdx.y >> 5;
    const float* src = seg == 0 ? s0 : seg == 1 ? s1 : seg == 2 ? s2 : s3;
    float* dst = seg == 0 ? d0 : seg == 1 ? d1 : seg == 2 ? d2 : d3;
    const int c0 = blockIdx.x * 32, r0 = (blockIdx.y & 31) * 32;
    const int tx = threadIdx.x & 31, ty = threadIdx.x >> 5;
#pragma unroll
    for (int i = 0; i < 4; ++i) {
        const int r = ty + i * 8;
        t[r][tx] = src[(long)(r0 + r) * 1024 + c0 + tx];
    }
    __syncthreads();
#pragma unroll
    for (int i = 0; i < 4; ++i) {
        const int r = ty + i * 8;
        dst[(long)(c0 + r) * 1024 + r0 + tx] = t[tx][r];
    }
}

__global__ void biascat_k(const float* __restrict__ ts_b, const float* __restrict__ ca_b,
                          const float* __restrict__ st_b,
                          const float* __restrict__ ts_ob, const float* __restrict__ ca_ob,
                          const float* __restrict__ st_ob,
                          float* __restrict__ BCAT, float* __restrict__ BKCAT,
                          float* __restrict__ WVB, float* __restrict__ WOB)
{
    const int i = blockIdx.x * blockDim.x + threadIdx.x;
    if (i >= 1024) return;
    BCAT[i] = ts_b[i]; BCAT[1024 + i] = ca_b[i];
    BCAT[2048 + i] = st_b[1024 + i]; BCAT[3072 + i] = st_b[2048 + i];
    BKCAT[i] = ts_b[1024 + i]; BKCAT[1024 + i] = ca_b[1024 + i]; BKCAT[2048 + i] = st_b[i];
    WVB[i] = ts_b[2048 + i]; WVB[1024 + i] = ca_b[2048 + i];
    WOB[i] = ts_ob[i]; WOB[1024 + i] = ca_ob[i]; WOB[2048 + i] = st_ob[i];
}

// ===================== glue kernels =====================
__global__ void headdot3_k(const float* __restrict__ QALL, const float* __restrict__ BKCAT,
                           float* __restrict__ out)
{
    const int idx = blockIdx.x * blockDim.x + threadIdx.x;
    if (idx >= 3 * B_ * T_ * NH_) return;
    const int mod = idx >> 15;
    const int b = (idx >> 7) & 255;
    const int t = (idx >> 3) & 15;
    const int h = idx & 7;
    const float* q = QALL + (long)(b * 16 + t) * 4096 + mod * 1024 + h * 128;
    const float* bb = BKCAT + mod * 1024 + h * 128;
    float sum = 0.f;
    for (int k = 0; k < DH_; ++k) sum += q[k] * bb[k];
    out[idx] = sum;
}

__global__ __launch_bounds__(64) void softpb_k(const float* __restrict__ sc3,
                                               float* __restrict__ pbar,
                                               float* __restrict__ attm)
{
    const int blk = blockIdx.x;
    const int h = blk & 7;
    const int b = (blk >> 3) & 255;
    const int mod = blk >> 11;
    const int lane = threadIdx.x;
    const float* base = sc3 + (long)mod * 8388608 + (long)b * 32768 + (long)h * 256;
    float v[16][4];
#pragma unroll
    for (int t = 0; t < 16; ++t) {
        const float* rowp = base + (long)t * 2048;
#pragma unroll
        for (int j = 0; j < 4; ++j) v[t][j] = rowp[j * 64 + lane];
    }
    if (mod < 2) {
        float pb[4] = {0.f, 0.f, 0.f, 0.f};
#pragma unroll
        for (int t = 0; t < 16; ++t) {
            float m = fmaxf(fmaxf(v[t][0], v[t][1]), fmaxf(v[t][2], v[t][3]));
            m = wave_max(m);
            const float e0 = expf(v[t][0] - m), e1 = expf(v[t][1] - m);
            const float e2 = expf(v[t][2] - m), e3 = expf(v[t][3] - m);
            const float inv = 1.f / wave_sum(e0 + e1 + e2 + e3);
            pb[0] += e0 * inv; pb[1] += e1 * inv; pb[2] += e2 * inv; pb[3] += e3 * inv;
        }
        float* pd = pbar + (long)mod * 524288 + (long)b * 2048 + h * 256;
#pragma unroll
        for (int j = 0; j < 4; ++j) pd[j * 64 + lane] = pb[j] * (1.0f / 16.f);
    } else {
        float am[16];
#pragma unroll
        for (int t = 0; t < 16; ++t) am[t] = 0.f;
#pragma unroll
        for (int j = 0; j < 4; ++j) {
            float mx = v[0][j];
#pragma unroll
            for (int t = 1; t < 16; ++t) mx = fmaxf(mx, v[t][j]);
            float e[16];
            float sum = 0.f;
#pragma unroll
            for (int t = 0; t < 16; ++t) { e[t] = expf(v[t][j] - mx); sum += e[t]; }
            const float inv = 1.f / sum;
#pragma unroll
            for (int t = 0; t < 16; ++t) am[t] += e[t] * inv;
        }
#pragma unroll
        for (int t = 0; t < 16; ++t) {
            const float sm = wave_sum(am[t]) * (1.0f / 256.f);
            if (lane == 0) attm[b * 128 + t * 8 + h] = sm;
        }
    }
}

__global__ __launch_bounds__(256) void ctxw2_k(const float* __restrict__ pbar,
                                               const float* __restrict__ hs,
                                               float* __restrict__ part)
{
    const int b = blockIdx.x;
    const int sc = blockIdx.y;
    __shared__ float pl[16][64];
    const int tid = threadIdx.x;
    for (int i = tid; i < 16 * 64; i += 256) {
        const int row = i >> 6;
        const int mod = row >> 3;
        pl[row][i & 63] = pbar[(long)mod * 524288 + (long)b * 2048 +
                               (row & 7) * 256 + sc * 64 + (i & 63)];
    }
    __syncthreads();
    const int k0 = tid * 4;
    float4 acc[16] = {};
    const float* hb = hs + (long)b * S_ * H_ + (long)sc * 64 * H_;
    for (int s = 0; s < 64; ++s) {
        const float4 vv = *(const float4*)(hb + (long)s * H_ + k0);
#pragma unroll
        for (int j = 0; j < 16; ++j) {
            const float p = pl[j][s];
            acc[j].x += p * vv.x; acc[j].y += p * vv.y;
            acc[j].z += p * vv.z; acc[j].w += p * vv.w;
        }
    }
    float* ob = part + (long)sc * 4194304;
#pragma unroll
    for (int j = 0; j < 16; ++j) {
        const int mod = j >> 3, hh = j & 7;
        *(float4*)(ob + (long)mod * 2097152 + (long)b * 8192 + hh * 1024 + k0) = acc[j];
    }
}

__global__ void ohead2_k(const float* __restrict__ attm, const float* __restrict__ QALL,
                         float* __restrict__ outb)
{
    const int idx = blockIdx.x * blockDim.x + threadIdx.x;
    if (idx >= B_ * H_) return;
    const int c = idx & (H_ - 1);
    const int b = idx >> 10;
    float sv = 0.f;
#pragma unroll
    for (int t = 0; t < T_; ++t)
        sv += attm[b * M128_ + t * NH_ + (c >> 7)] * QALL[(long)(b * 16 + t) * 4096 + 3072 + c];
    outb[idx] = sv;
}

__global__ void cat3_k(const float* __restrict__ vs, const float* __restrict__ vt,
                       const float* __restrict__ vo, float* __restrict__ out)
{
    const int idx = blockIdx.x * blockDim.x + threadIdx.x;
    if (idx >= B_ * 3 * H_) return;
    const int k = idx % (3 * H_);
    const int b = idx / (3 * H_);
    float v;
    if (k < H_)          v = vs[b * H_ + k];
    else if (k < 2 * H_) v = vt[b * H_ + k - H_];
    else                 v = vo[b * H_ + k - 2 * H_];
    out[idx] = v;
}

__global__ void ln_k(const float* __restrict__ cat3, const float* __restrict__ g,
                     const float* __restrict__ bta, float* __restrict__ out)
{
    const int b = blockIdx.x;
    const int tid = threadIdx.x;
    __shared__ float buf[3 * H_];
    __shared__ float red[4];
    const float* src = cat3 + (long)b * 3 * H_;
    float sv = 0.f;
    for (int i = tid; i < 3 * H_; i += 256) { const float x = src[i]; buf[i] = x; sv += x; }
    sv = wave_sum(sv);
    if ((tid & 63) == 0) red[tid >> 6] = sv;
    __syncthreads();
    const float mu = (red[0] + red[1] + red[2] + red[3]) * (1.f / (3 * H_));
    __syncthreads();
    float s2 = 0.f;
    for (int i = tid; i < 3 * H_; i += 256) { const float d0 = buf[i] - mu; s2 += d0 * d0; }
    s2 = wave_sum(s2);
    if ((tid & 63) == 0) red[tid >> 6] = s2;
    __syncthreads();
    const float var = (red[0] + red[1] + red[2] + red[3]) * (1.f / (3 * H_));
    const float rstd = rsqrtf(var + 1e-5f);
    float* dst = out + (long)b * 3 * H_;
    for (int i = tid; i < 3 * H_; i += 256)
        dst[i] = (buf[i] - mu) * rstd * g[i] + bta[i];
}

__global__ void mulf_k(const float* __restrict__ a, const float* __restrict__ b2,
                       float* __restrict__ out, int n)
{
    const int idx = blockIdx.x * blockDim.x + threadIdx.x;
    if (idx < n) out[idx] = a[idx] * b2[idx];
}

__global__ void fuse_k(const float* __restrict__ g, const float* __restrict__ flin,
                       const float* __restrict__ bil, float* __restrict__ fused,
                       __bf16* __restrict__ fusedh)
{
    const int idx = blockIdx.x * blockDim.x + threadIdx.x;
    if (idx >= B_ * H_) return;
    const float gg = g[idx];
    const float v = gg * flin[idx] + (1.f - gg) * bil[idx];
    fused[idx] = v;
    fusedh[idx] = (__bf16)v;
}

__global__ void catfv_k(const float* __restrict__ fused, const float* __restrict__ vt,
                        float* __restrict__ out)
{
    const int idx = blockIdx.x * blockDim.x + threadIdx.x;
    if (idx >= B_ * 2 * H_) return;
    const int k = idx % (2 * H_);
    const int b = idx / (2 * H_);
    out[idx] = (k < H_) ? fused[b * H_ + k] : vt[b * H_ + k - H_];
}

__global__ void route_k(const float* __restrict__ glog, float* __restrict__ gp)
{
    const int b = blockIdx.x * blockDim.x + threadIdx.x;
    if (b >= B_) return;
    const float x0 = glog[b * 3], x1 = glog[b * 3 + 1], x2 = glog[b * 3 + 2];
    const float m1 = fmaxf(x0, fmaxf(x1, x2));
    float thr;
    if (x0 == m1)      thr = fmaxf(x1, x2);
    else if (x1 == m1) thr = fmaxf(x0, x2);
    else               thr = fmaxf(x0, x1);
    const float y0 = (x0 >= thr) ? x0 : -1e9f;
    const float y1 = (x1 >= thr) ? x1 : -1e9f;
    const float y2 = (x2 >= thr) ? x2 : -1e9f;
    const float mm = fmaxf(y0, fmaxf(y1, y2));
    const float e0 = expf(y0 - mm), e1 = expf(y1 - mm), e2 = expf(y2 - mm);
    const float inv = 1.f / (e0 + e1 + e2);
    gp[b * 3] = e0 * inv; gp[b * 3 + 1] = e1 * inv; gp[b * 3 + 2] = e2 * inv;
}

__global__ void epsm_k(float* __restrict__ elog, const float* __restrict__ gp)
{
    const int idx = blockIdx.x * blockDim.x + threadIdx.x;
    if (idx >= B_ * G_) return;
    float* p = elog + (long)idx * E_;
    float m = p[0];
#pragma unroll
    for (int e = 1; e < E_; ++e) m = fmaxf(m, p[e]);
    float sum = 0.f;
    float v[E_];
#pragma unroll
    for (int e = 0; e < E_; ++e) { v[e] = expf(p[e] - m); sum += v[e]; }
    const float w = gp[idx] / sum;
#pragma unroll
    for (int e = 0; e < E_; ++e) p[e] = v[e] * w;
}

__global__ void moefinal_k(const float* __restrict__ part, const float* __restrict__ fused,
                           const float* __restrict__ wsc, const float* __restrict__ e_b2,
                           float* __restrict__ res)
{
    const int idx = blockIdx.x * blockDim.x + threadIdx.x;
    if (idx >= B_ * H_) return;
    const int b = idx >> 10;
    const int h = idx & (H_ - 1);
    float acc = fused[idx];
#pragma unroll 8
    for (int z = 0; z < 48; ++z) acc += part[(long)z * (B_ * H_) + idx];
    float ba = 0.f;
#pragma unroll
    for (int ge = 0; ge < GE_; ++ge) ba += wsc[b * GE_ + ge] * e_b2[ge * H_ + h];
    res[idx] = acc + ba;
}

// ===================== entry =====================
extern "C" void kernel_launch(void* const* d_in, const int* in_sizes, int n_in,
                              void* d_out, int out_size, void* d_ws, size_t ws_size,
                              hipStream_t stream)
{
    const float* h_sent  = (const float*)d_in[0];
    const float* h_term  = (const float*)d_in[1];
    const float* ts_in_w = (const float*)d_in[2];
    const float* ts_out_w= (const float*)d_in[3];
    const float* st_in_w = (const float*)d_in[4];
    const float* st_out_w= (const float*)d_in[5];
    const float* ca_in_w = (const float*)d_in[6];
    const float* ca_out_w= (const float*)d_in[7];
    const float* opq_w   = (const float*)d_in[8];
    const float* fuse_w  = (const float*)d_in[9];
    const float* gate_w  = (const float*)d_in[10];
    const float* bs_w    = (const float*)d_in[11];
    const float* bt_w    = (const float*)d_in[12];
    const float* bo_w    = (const float*)d_in[13];
    const float* cond_w  = (const float*)d_in[14];
    const float* gr_w    = (const float*)d_in[15];
    const float* er_w    = (const float*)d_in[16];
    const float* e_w1    = (const float*)d_in[17];
    const float* e_w2    = (const float*)d_in[18];
    const float* cls_w   = (const float*)d_in[19];
    const float* ts_in_b = (const float*)d_in[20];
    const float* ts_out_b= (const float*)d_in[21];
    const float* st_in_b = (const float*)d_in[22];
    const float* st_out_b= (const float*)d_in[23];
    const float* ca_in_b = (const float*)d_in[24];
    const float* ca_out_b= (const float*)d_in[25];
    const float* fuse_b  = (const float*)d_in[26];
    const float* gate_b  = (const float*)d_in[27];
    const float* bs_b    = (const float*)d_in[28];
    const float* bt_b    = (const float*)d_in[29];
    const float* bo_b    = (const float*)d_in[30];
    const float* cond_b  = (const float*)d_in[31];
    const float* gr_b    = (const float*)d_in[32];
    const float* er_b    = (const float*)d_in[33];
    const float* e_b1    = (const float*)d_in[34];
    const float* e_b2    = (const float*)d_in[35];
    const float* cls_b   = (const float*)d_in[36];
    const float* ln_b    = (const float*)d_in[37];
    const float* ln_g    = (const float*)d_in[38];
    (void)in_sizes; (void)n_in; (void)out_size; (void)ws_size;

    float* ws = (float*)d_ws;
    size_t off = 0;
    auto allocF = [&](size_t n) { float* p = ws + off; off += (n + 63) & ~(size_t)63; return p; };

    float* QALL  = allocF(16777216);
    float* WCAT  = allocF(4194304);
    float* BCAT  = allocF(4096);
    float* BKCAT = allocF(3072);
    float* wT3   = allocF(3145728);
    float* opqT  = allocF(1048576);
    float* WVCAT = allocF(2097152);
    float* WVB   = allocF(2048);
    float* WOCAT = allocF(3145728);
    float* WOB   = allocF(3072);
    float* OFFS3 = allocF(98304);
    float* BIG3  = allocF(100663296);
    float* SC3   = allocF(25165824);
    float* PBAR3 = allocF(1048576);
    float* CTXB3 = allocF(4194304);
    float* PARTC = allocF(16777216);
    float* OBAR3 = allocF(786432);
    float* VOUT3 = allocF(786432);
    float* ATTM  = allocF(32768);
    float* CAT3  = allocF(786432);
    float* LNC   = allocF(786432);
    float* FLIN  = allocF(262144);
    float* GATE  = allocF(262144);
    float* BSV   = allocF(65536);
    float* BTV   = allocF(65536);
    float* PROD  = allocF(65536);
    float* BIL   = allocF(262144);
    float* FUSED = allocF(262144);
    float* FUSEDH= allocF(131072);
    float* CATFV = allocF(524288);
    float* COND  = allocF(262144);
    float* GLOG  = allocF(1024);
    float* GP    = allocF(1024);
    float* ELOG  = allocF(8192);
    float* RES   = allocF(262144);
    float* PARTF = allocF(1048576);
    float* H1Wf  = allocF(12582912);
    float* PART  = allocF(12582912);
    __bf16* FUSEDbf = (__bf16*)FUSEDH;
    __bf16* H1W     = (__bf16*)H1Wf;
    float* VTERM = VOUT3;
    float* VOP   = VOUT3 + 262144;
    float* VSENT = VOUT3 + 524288;

    hipStream_t s = stream;
    const float rscale = 0.08838834764831845f;
    const int ZBIG = 1 << 30;

    // ---------- precompute (merged) ----------
    cpy8_k<<<dim3(8 * 1024), dim3(256), 0, s>>>(
        ts_in_w, st_in_w + 1048576, st_in_w + 2097152, ts_in_w + 2097152,
        ca_in_w + 2097152, ts_out_w, ca_out_w, st_out_w,
        WCAT, WCAT + 2097152, WCAT + 3145728, WVCAT,
        WVCAT + 1048576, WOCAT, WOCAT + 1048576, WOCAT + 2097152);
    biascat_k<<<dim3(4), dim3(256), 0, s>>>(ts_in_b, ca_in_b, st_in_b,
                                            ts_out_b, ca_out_b, st_out_b,
                                            BCAT, BKCAT, WVB, WOB);
    tT4_k<<<dim3(32, 128), dim3(256), 0, s>>>(
        ts_in_w + 1048576, ca_in_w + 1048576, st_in_w, opq_w,
        wT3, wT3 + 1048576, wT3 + 2097152, opqT);

    // Wcomb_ca = Wq_ca @ opq_w
    sg2(s, 0, 1, ZBIG, ca_in_w, opqT, nullptr, nullptr, WCAT + 1048576,
        8, 8, 1, 1024, 12, 0, 0, 1024, 0, 0, 1024, 0, 0, 0, 0,
        0, 1024, 0, 0, 0, 0, 1.f);

    // QALL
    sg2(s, 0, 1, ZBIG, h_term, WCAT, BCAT, nullptr, QALL,
        32, 32, 1, 1024, 12, 0, 0, 1024, 0, 0, 1024, 0, 0, 0, 0,
        0, 4096, 0, 0, 0, 0, 1.f);

    headdot3_k<<<dim3(384), dim3(256), 0, s>>>(QALL, BKCAT, OFFS3);

    // A-fold z=24
    sg2(s, 0, 1, ZBIG, QALL, wT3, nullptr, nullptr, BIG3,
        8, 32, 24, 128, 4, 3,
        65536, 4096, 1024, 128,
        1024, 1048576, 128, 0, 0,
        131072, 8192, 33554432, 1024, 0, 0, 1.f);

    // scores: z = b*4 + mod (b-locality), NCH=2 (A-tile L2 reuse), mod=3 dummy
    sg2(s, 0, 2, 3, BIG3, h_sent, nullptr, OFFS3, SC3,
        1, 1, 1024, 1024, 12, 2,
        0, 1024, 131072, 33554432,
        1024, 262144, 0, 0, 0,
        0, 256, 32768, 8388608, 128, 32768, rscale);

    // fused softmax + pool
    softpb_k<<<dim3(3 * B_ * NH_), dim3(64), 0, s>>>(SC3, PBAR3, ATTM);

    // ctx weighted sum (s-split x4) + reduce
    ctxw2_k<<<dim3(B_, 4), dim3(256), 0, s>>>(PBAR3, h_sent, PARTC);
    kred_k<0><<<dim3(4194304 / 256), dim3(256), 0, s>>>(PARTC, nullptr, CTXB3,
                                                        4194304, 4194304, 4, 0);
    // ctx V-proj z=16
    sg2(s, 0, 1, ZBIG, CTXB3, WVCAT, WVB, nullptr, OBAR3,
        1, 2, 16, 1024, 12, 3,
        0, 8192, 2097152, 1024,
        1024, 1048576, 131072, 1024, 128,
        0, 1024, 262144, 128, 0, 0, 1.f);

    // st path
    ohead2_k<<<dim3((B_ * H_ + 255) / 256), dim3(256), 0, s>>>(ATTM, QALL, OBAR3 + 524288);

    // out-proj z=3
    sg2(s, 0, 1, ZBIG, OBAR3, WOCAT, WOB, nullptr, VOUT3,
        8, 2, 3, 1024, 12, 0,
        0, 1024, 262144, 0,
        1024, 1048576, 0, 1024, 0,
        0, 1024, 262144, 0, 0, 0, 1.f);

    // ---------- fusion head ----------
    cat3_k<<<dim3((B_ * 3 * H_ + 255) / 256), dim3(256), 0, s>>>(VSENT, VTERM, VOP, CAT3);
    ln_k<<<dim3(B_), dim3(256), 0, s>>>(CAT3, ln_g, ln_b, LNC);
    sg2(s, 0, 1, ZBIG, LNC, fuse_w, nullptr, nullptr, PARTF,
        8, 2, 4, 768, 12, 2, 0, 3072, 0, 768, 3072, 0, 768, 0, 0,
        0, 1024, 0, 262144, 0, 0, 1.f);
    kred_k<0><<<dim3(1024), dim3(256), 0, s>>>(PARTF, fuse_b, FLIN, 262144, 262144, 4, 1023);
    sg2(s, 0, 1, ZBIG, CAT3, gate_w, nullptr, nullptr, PARTF,
        8, 2, 4, 768, 12, 2, 0, 3072, 0, 768, 3072, 0, 768, 0, 0,
        0, 1024, 0, 262144, 0, 0, 1.f);
    kred_k<2><<<dim3(1024), dim3(256), 0, s>>>(PARTF, gate_b, GATE, 262144, 262144, 4, 1023);
    sg2(s, 0, 1, ZBIG, VSENT, bs_w, nullptr, nullptr, PARTF,
        2, 2, 4, 256, 12, 2, 0, 1024, 0, 256, 1024, 0, 256, 0, 0,
        0, 256, 0, 65536, 0, 0, 1.f);
    kred_k<0><<<dim3(256), dim3(256), 0, s>>>(PARTF, bs_b, BSV, 65536, 65536, 4, 255);
    sg2(s, 0, 1, ZBIG, VTERM, bt_w, nullptr, nullptr, PARTF,
        2, 2, 4, 256, 12, 2, 0, 1024, 0, 256, 1024, 0, 256, 0, 0,
        0, 256, 0, 65536, 0, 0, 1.f);
    kred_k<0><<<dim3(256), dim3(256), 0, s>>>(PARTF, bt_b, BTV, 65536, 65536, 4, 255);
    mulf_k<<<dim3((B_ * R_ + 255) / 256), dim3(256), 0, s>>>(BSV, BTV, PROD, B_ * R_);
    sg2(s, 0, 1, ZBIG, PROD, bo_w, nullptr, nullptr, PARTF,
        8, 2, 2, 128, 12, 1, 0, 256, 0, 128, 256, 0, 128, 0, 0,
        0, 1024, 0, 262144, 0, 0, 1.f);
    kred_k<0><<<dim3(1024), dim3(256), 0, s>>>(PARTF, bo_b, BIL, 262144, 262144, 2, 1023);
    fuse_k<<<dim3((B_ * H_ + 255) / 256), dim3(256), 0, s>>>(GATE, FLIN, BIL, FUSED, FUSEDbf);
    catfv_k<<<dim3((B_ * 2 * H_ + 255) / 256), dim3(256), 0, s>>>(FUSED, VTERM, CATFV);
    sg2(s, 0, 1, ZBIG, CATFV, cond_w, nullptr, nullptr, PARTF,
        8, 2, 4, 512, 12, 2, 0, 2048, 0, 512, 2048, 0, 512, 0, 0,
        0, 1024, 0, 262144, 0, 0, 1.f);
    kred_k<0><<<dim3(1024), dim3(256), 0, s>>>(PARTF, cond_b, COND, 262144, 262144, 4, 1023);

    // ---------- routing ----------
    g_launch(s, FUSED, gr_w, gr_b, GLOG, B_, G_, H_, H_, H_, G_);
    route_k<<<dim3(1), dim3(256), 0, s>>>(GLOG, GP);
    g_launch(s, COND, er_w, er_b, ELOG, B_, GE_, H_, H_, H_, GE_);
    epsm_k<<<dim3(3), dim3(256), 0, s>>>(ELOG, GP);

    // ---------- MoE ----------
    sgemm256_k<1, 1, 1, 1, 1><<<dim3(I_ / 128, 1, GE_), dim3(512), 0, s>>>(
        FUSEDbf, e_w1, e_b1, ELOG, nullptr, H1W,
        1024, H_, 0, H_, (long)I_ * H_, 0, 0, I_,
        (long)GE_ * I_, I_, GE_, 1.f);
    sgemm256_k<1, 1, 0, 0, 0><<<dim3(H_ / 128, 1, 2 * GE_), dim3(512), 0, s>>>(
        H1W, e_w2, nullptr, nullptr, PART, nullptr,
        2048, (long)GE_ * I_, 2048, I_, (long)H_ * I_, 2048, 1, 0,
        H_, (long)B_ * H_, 0, 1.f);
    moefinal_k<<<dim3(B_ * H_ / 256), dim3(256), 0, s>>>(PART, FUSED, ELOG, e_b2, RES);

    // ---------- classifier ----------
    g_launch(s, RES, cls_w, cls_b, (float*)d_out, B_, L_, H_, H_, H_, L_);
}